// Round 9
// baseline (4606.709 us; speedup 1.0000x reference)
//
#include <hip/hip_runtime.h>
#include <hip/hip_bf16.h>
#include <cstddef>

#define CDIV(a,b) (((a)+(b)-1)/(b))

static constexpr float BN_EPS = 1e-5f;

typedef __attribute__((ext_vector_type(8))) short short8v;   // 8 bf16 (4 VGPRs)
typedef __attribute__((ext_vector_type(4))) float f32x4;

__device__ inline ushort f2bf(float x) {
  unsigned u = __float_as_uint(x);
  unsigned r = (u + 0x7fffu + ((u >> 16) & 1u)) >> 16;
  return (ushort)r;
}
__device__ inline float bf2f(ushort h) {
  return __uint_as_float(((unsigned)h) << 16);
}

// ---------------- weight fragment prep (once per launch) ----------------
// Wf layout: Wf[((mt*NKC+kc)*64 + lane)*8 + j], lane=((kr>>3)<<4)|(m&15), j=kr&7
template<int K, int M, bool TRANSW>
__global__ void wprep_k(const float* __restrict__ W, ushort* __restrict__ Wf) {
  constexpr int NKC = K / 32;
  for (int i = threadIdx.x; i < K * M; i += 256) {
    int k, m;
    if (TRANSW) { m = i / K; k = i - m * K; }
    else        { k = i / M; m = i - k * M; }
    float wv = W[i];
    int mt = m >> 4, ml = m & 15, kc = k >> 5, kr = k & 31;
    int lane = ((kr >> 3) << 4) | ml;
    int j = kr & 7;
    Wf[(size_t)((mt * NKC + kc) * 64 + lane) * 8 + j] = f2bf(wv);
  }
}

// =====================================================================
// bf16 MFMA GEMM v2 (round-7 structure + SPLITC half-table output)
// =====================================================================
template<int K, int M, int AMODE, bool FSTAT, bool OUTF32, bool SIDE, bool GATE, bool SPLITC = false>
__global__ __launch_bounds__(256)
void gemm2(const void* __restrict__ Ain, const float* __restrict__ A2,
           const ushort* __restrict__ Wf, void* __restrict__ Cout,
           ushort* __restrict__ Cb1,
           ushort* __restrict__ side,
           const float* __restrict__ aStat, const float* __restrict__ aG,
           const float* __restrict__ aB, float* __restrict__ oStat,
           const ushort* __restrict__ gi, const float* __restrict__ bih,
           const float* __restrict__ bhh, ushort* __restrict__ hnext, int N) {
  constexpr int BM = 128;
  constexpr int NKC = K / 32;
  constexpr int NMT = M / 16;
  constexpr bool BN = (AMODE >= 2);
  __shared__ __align__(16) ushort As[BM * K];
  __shared__ __align__(16) ushort WfL[M * K];
  __shared__ float bnSc[BN ? K : 1];
  __shared__ float bnSh[BN ? K : 1];
  __shared__ float redS[FSTAT ? M : 1];
  __shared__ float redQ[FSTAT ? M : 1];
  __shared__ float bihL[GATE ? 192 : 1];
  __shared__ float bhhL[GATE ? 192 : 1];
  const int tid = threadIdx.x;
  const int row0 = blockIdx.x * BM;

  for (int i = tid; i < K * M / 8; i += 256)
    ((short8v*)WfL)[i] = ((const short8v*)Wf)[i];
  if (GATE) {
    if (tid < 192) { bihL[tid] = bih[tid]; bhhL[tid] = bhh[tid]; }
  }
  if (BN) {
    float invN = 1.f / (float)N;
    for (int i = tid; i < K; i += 256) {
      float mn = aStat[i] * invN;
      float vr = fmaxf(aStat[128 + i] * invN - mn * mn, 0.f);
      float sc = aG[i] * rsqrtf(vr + BN_EPS);
      bnSc[i] = sc;
      bnSh[i] = aB[i] - mn * sc;
    }
    __syncthreads();  // bnSc/bnSh must be visible to all threads before A-staging
  }
  if (FSTAT) {
    if (tid < M) { redS[tid] = 0.f; redQ[tid] = 0.f; }
  }

  {
    const float* Af = (const float*)Ain;
    const ushort* Ab = (const ushort*)Ain;
    for (int i = tid; i < BM * K / 4; i += 256) {
      int row = (i * 4) / K, k0 = (i * 4) % K;
      int grow = row0 + row;
      ushort h4[4] = {0, 0, 0, 0};
      if (AMODE == 0) {
        if (grow < N) *(ushort4*)h4 = *(const ushort4*)&Ab[(size_t)grow * K + k0];
      } else if (AMODE == 1) {
        float vv[4] = {0.f, 0.f, 0.f, 0.f};
        if (grow < N) *(float4*)vv = *(const float4*)&Af[(size_t)grow * K + k0];
#pragma unroll
        for (int c = 0; c < 4; ++c) h4[c] = f2bf(vv[c]);
      } else {
        float vv[4] = {0.f, 0.f, 0.f, 0.f};
        if (grow < N) {
          float rw[4];
          if (AMODE == 2) *(float4*)rw = *(const float4*)&Af[(size_t)grow * K + k0];
          else            *(float4*)rw = *(const float4*)&A2[(size_t)grow * K + k0];
          ushort b4[4];
          if (AMODE == 3) *(ushort4*)b4 = *(const ushort4*)&Ab[(size_t)grow * K + k0];
#pragma unroll
          for (int c = 0; c < 4; ++c) {
            float v = fmaxf(fmaf(rw[c], bnSc[k0 + c], bnSh[k0 + c]), 0.f);
            vv[c] = (AMODE == 3) ? bf2f(b4[c]) + v : v;
            h4[c] = f2bf(vv[c]);
          }
          if (SIDE) *(ushort4*)&side[(size_t)grow * K + k0] = *(ushort4*)h4;
        }
      }
      unsigned off = ((unsigned)(row * K + k0) * 2u) ^ (((unsigned)(row & 7)) << 4);
      *(ushort4*)((char*)As + off) = *(ushort4*)h4;
    }
  }
  __syncthreads();

  const int wvi = tid >> 6, lane = tid & 63;
  const int lrow = lane & 15, lkg = lane >> 4;

  short8v af[2][NKC];
#pragma unroll
  for (int rt = 0; rt < 2; ++rt)
#pragma unroll
    for (int kc = 0; kc < NKC; ++kc) {
      int row = wvi * 32 + rt * 16 + lrow;
      unsigned off = ((unsigned)(row * K + kc * 32 + lkg * 8) * 2u) ^ (((unsigned)(row & 7)) << 4);
      af[rt][kc] = *(const short8v*)((const char*)As + off);
    }

  f32x4 acc[2][NMT];
#pragma unroll
  for (int rt = 0; rt < 2; ++rt)
#pragma unroll
    for (int mt = 0; mt < NMT; ++mt) acc[rt][mt] = f32x4{0.f, 0.f, 0.f, 0.f};

#pragma unroll
  for (int mt = 0; mt < NMT; ++mt) {
    short8v bf[NKC];
#pragma unroll
    for (int kc = 0; kc < NKC; ++kc)
      bf[kc] = *(const short8v*)&WfL[(size_t)((mt * NKC + kc) * 64 + lane) * 8];
#pragma unroll
    for (int rt = 0; rt < 2; ++rt)
#pragma unroll
      for (int kc = 0; kc < NKC; ++kc)
        acc[rt][mt] = __builtin_amdgcn_mfma_f32_16x16x32_bf16(af[rt][kc], bf[kc], acc[rt][mt], 0, 0, 0);
  }

  if (GATE) {
#pragma unroll
    for (int rt = 0; rt < 2; ++rt)
#pragma unroll
      for (int i = 0; i < 4; ++i) {
        int grow = row0 + wvi * 32 + rt * 16 + lkg * 4 + i;
        if (grow < N) {
          const ushort* gip = gi + (size_t)grow * 192;
          const ushort* hpp = (const ushort*)Ain + (size_t)grow * 64;
#pragma unroll
          for (int mtj = 0; mtj < 4; ++mtj) {
            int j = mtj * 16 + lrow;
            float ir = bf2f(gip[j]) + bihL[j];
            float iz = bf2f(gip[64 + j]) + bihL[64 + j];
            float ig = bf2f(gip[128 + j]) + bihL[128 + j];
            float hr = acc[rt][mtj][i] + bhhL[j];
            float hz = acc[rt][mtj + 4][i] + bhhL[64 + j];
            float hg = acc[rt][mtj + 8][i] + bhhL[128 + j];
            float r = 1.f / (1.f + expf(-(ir + hr)));
            float z = 1.f / (1.f + expf(-(iz + hz)));
            float ng = tanhf(ig + r * hg);
            float hn = (1.f - z) * ng + z * bf2f(hpp[j]);
            hnext[(size_t)grow * 64 + j] = f2bf(hn);
          }
        }
      }
    return;
  }

#pragma unroll
  for (int rt = 0; rt < 2; ++rt)
#pragma unroll
    for (int mt = 0; mt < NMT; ++mt) {
#pragma unroll
      for (int i = 0; i < 4; ++i) {
        int grow = row0 + wvi * 32 + rt * 16 + lkg * 4 + i;
        if (grow < N) {
          if (SPLITC) {
            int col = mt * 16 + lrow;
            ushort* tb = (mt < NMT / 2) ? (ushort*)Cout : Cb1;
            tb[(size_t)grow * (M / 2) + (col & (M / 2 - 1))] = f2bf(acc[rt][mt][i]);
          } else if (OUTF32) {
            ((float*)Cout)[(size_t)grow * M + mt * 16 + lrow] = acc[rt][mt][i];
          } else {
            ((ushort*)Cout)[(size_t)grow * M + mt * 16 + lrow] = f2bf(acc[rt][mt][i]);
          }
        }
      }
    }

  if (FSTAT) {
#pragma unroll
    for (int mt = 0; mt < NMT; ++mt) {
      float s = 0.f, q = 0.f;
#pragma unroll
      for (int rt = 0; rt < 2; ++rt)
#pragma unroll
        for (int i = 0; i < 4; ++i) {
          int grow = row0 + wvi * 32 + rt * 16 + lkg * 4 + i;
          if (grow < N) { float v = acc[rt][mt][i]; s += v; q += v * v; }
        }
      s += __shfl_xor(s, 16); s += __shfl_xor(s, 32);
      q += __shfl_xor(q, 16); q += __shfl_xor(q, 32);
      if (lkg == 0) {
        atomicAdd(&redS[mt * 16 + lrow], s);
        atomicAdd(&redQ[mt * 16 + lrow], q);
      }
    }
    __syncthreads();
    if (tid < M) {
      atomicAdd(&oStat[tid], redS[tid]);
      atomicAdd(&oStat[128 + tid], redQ[tid]);
    }
  }
}

// ---------------- fused GRU step: hnext = GRU(Ht, hprev) ----------------
// Both K=64 GEMMs with register accumulators; W fragments direct from global.
__global__ __launch_bounds__(256)
void gruf_k(const ushort* __restrict__ Ht, const ushort* __restrict__ hprev,
            const ushort* __restrict__ Wihf, const ushort* __restrict__ Whhf,
            const float* __restrict__ bih, const float* __restrict__ bhh,
            ushort* __restrict__ hnext, int N) {
  __shared__ float bihL[192], bhhL[192];
  const int tid = threadIdx.x;
  if (tid < 192) { bihL[tid] = bih[tid]; bhhL[tid] = bhh[tid]; }
  __syncthreads();
  const int wvi = tid >> 6, lane = tid & 63;
  const int lrow = lane & 15, lkg = lane >> 4;
  const int row0 = blockIdx.x * 128;
  const short8v zv = short8v{0, 0, 0, 0, 0, 0, 0, 0};
  for (int rt = 0; rt < 2; ++rt) {
    int arow = row0 + wvi * 32 + rt * 16 + lrow;
    bool aok = arow < N;
    short8v afA[2], afB[2];
#pragma unroll
    for (int kc = 0; kc < 2; ++kc) {
      afA[kc] = aok ? *(const short8v*)&Ht[(size_t)arow * 64 + kc * 32 + lkg * 8] : zv;
      afB[kc] = aok ? *(const short8v*)&hprev[(size_t)arow * 64 + kc * 32 + lkg * 8] : zv;
    }
    f32x4 gacc[12], hacc[12];
#pragma unroll
    for (int mt = 0; mt < 12; ++mt) {
      gacc[mt] = f32x4{0.f, 0.f, 0.f, 0.f};
      hacc[mt] = f32x4{0.f, 0.f, 0.f, 0.f};
#pragma unroll
      for (int kc = 0; kc < 2; ++kc) {
        short8v bwi = *(const short8v*)&Wihf[(size_t)((mt * 2 + kc) * 64 + lane) * 8];
        short8v bwh = *(const short8v*)&Whhf[(size_t)((mt * 2 + kc) * 64 + lane) * 8];
        gacc[mt] = __builtin_amdgcn_mfma_f32_16x16x32_bf16(afA[kc], bwi, gacc[mt], 0, 0, 0);
        hacc[mt] = __builtin_amdgcn_mfma_f32_16x16x32_bf16(afB[kc], bwh, hacc[mt], 0, 0, 0);
      }
    }
#pragma unroll
    for (int i = 0; i < 4; ++i) {
      int grow = row0 + wvi * 32 + rt * 16 + lkg * 4 + i;
      if (grow < N) {
        const ushort* hpp = hprev + (size_t)grow * 64;
#pragma unroll
        for (int mtj = 0; mtj < 4; ++mtj) {
          int j = mtj * 16 + lrow;
          float ir = gacc[mtj][i] + bihL[j];
          float iz = gacc[mtj + 4][i] + bihL[64 + j];
          float ig = gacc[mtj + 8][i] + bihL[128 + j];
          float hr = hacc[mtj][i] + bhhL[j];
          float hz = hacc[mtj + 4][i] + bhhL[64 + j];
          float hg = hacc[mtj + 8][i] + bhhL[128 + j];
          float r = 1.f / (1.f + expf(-(ir + hr)));
          float z = 1.f / (1.f + expf(-(iz + hz)));
          float ng = tanhf(ig + r * hg);
          float hn = (1.f - z) * ng + z * bf2f(hpp[j]);
          hnext[(size_t)grow * 64 + j] = f2bf(hn);
        }
      }
    }
  }
}

// ---------------- BN+ReLU (fp32 raw in -> bf16 normalized out) ----------------
__global__ __launch_bounds__(256) void bnbf_k(const float* __restrict__ X, ushort* __restrict__ Y,
                                              const float* __restrict__ st,
                                              const float* __restrict__ g, const float* __restrict__ be,
                                              int N, int M) {
  int i4 = blockIdx.x * 256 + threadIdx.x;
  int total = N * M / 4;
  if (i4 >= total) return;
  int c0 = (i4 * 4) % M;
  float invN = 1.f / (float)N;
  float xv[4];
  *(float4*)xv = *(const float4*)&X[(size_t)i4 * 4];
  ushort yv[4];
#pragma unroll
  for (int j = 0; j < 4; ++j) {
    int c = c0 + j;
    float mn = st[c] * invN;
    float vr = fmaxf(st[128 + c] * invN - mn * mn, 0.f);
    float sc = g[c] * rsqrtf(vr + BN_EPS);
    float v = (xv[j] - mn) * sc + be[c];
    yv[j] = f2bf(fmaxf(v, 0.f));
  }
  *(ushort4*)&Y[(size_t)i4 * 4] = *(ushort4*)yv;
}

// ---------------- batched graph prep (t = blockIdx.x & 7) ----------------
__global__ void hist_k(const int* __restrict__ dst, int* __restrict__ cnt, ushort* __restrict__ rank,
                       int N, int E) {
  int t = blockIdx.x & 7;
  int e = (blockIdx.x >> 3) * 256 + threadIdx.x;
  if (e >= E) return;
  size_t i = (size_t)t * E + e;
  rank[i] = (ushort)atomicAdd(&cnt[t * N + dst[i]], 1);
}
__global__ __launch_bounds__(256) void scan1_k(const int* __restrict__ in, int* __restrict__ incl,
                                               int* __restrict__ bsum, int n) {
  int t = blockIdx.y;
  const int* inp = in + (size_t)t * n;
  int* ip = incl + (size_t)t * n;
  int i = blockIdx.x * 256 + threadIdx.x;
  int v = (i < n) ? inp[i] : 0;
  int lane = threadIdx.x & 63;
  int sidx = threadIdx.x >> 6;
  int sv = v;
  for (int off = 1; off < 64; off <<= 1) {
    int tt = __shfl_up(sv, off, 64);
    if (lane >= off) sv += tt;
  }
  __shared__ int wsum[4];
  if (lane == 63) wsum[sidx] = sv;
  __syncthreads();
  int add = 0;
  for (int w = 0; w < sidx; ++w) add += wsum[w];
  sv += add;
  if (i < n) ip[i] = sv;
  if (threadIdx.x == 255) bsum[t * 256 + blockIdx.x] = sv;
}
__global__ __launch_bounds__(256) void scan2_k(int* __restrict__ bsum, int nb) {
  int t = blockIdx.y;
  int* bp = bsum + t * 256;
  int i = threadIdx.x;
  int v = (i < nb) ? bp[i] : 0;
  int lane = threadIdx.x & 63;
  int sidx = threadIdx.x >> 6;
  int sv = v;
  for (int off = 1; off < 64; off <<= 1) {
    int tt = __shfl_up(sv, off, 64);
    if (lane >= off) sv += tt;
  }
  __shared__ int wsum[4];
  if (lane == 63) wsum[sidx] = sv;
  __syncthreads();
  int add = 0;
  for (int w = 0; w < sidx; ++w) add += wsum[w];
  sv += add;
  if (i < nb) bp[i] = sv;
}
__global__ void scan3_k(const int* __restrict__ incl, const int* __restrict__ cnt,
                        const int* __restrict__ bsum, int* __restrict__ rowptr, int n, int E) {
  int t = blockIdx.y;
  int i = blockIdx.x * 256 + threadIdx.x;
  int* rp = rowptr + (size_t)t * (n + 1);
  if (i < n) {
    int v = incl[(size_t)t * n + i] - cnt[(size_t)t * n + i] +
            (blockIdx.x ? bsum[t * 256 + blockIdx.x - 1] : 0);
    rp[i] = v;
  }
  if (i == 0) rp[n] = E;
}
__global__ void scat_k(const int* __restrict__ src, const int* __restrict__ dst,
                       const float* __restrict__ w, const ushort* __restrict__ rank,
                       const int* __restrict__ rowptr, int2* __restrict__ epk,
                       int N1, int E) {
  int t = blockIdx.x & 7;
  int e = (blockIdx.x >> 3) * 256 + threadIdx.x;
  if (e >= E) return;
  size_t i = (size_t)t * E + e;
  int slot = rowptr[(size_t)t * N1 + dst[i]] + (int)rank[i];
  epk[(size_t)t * E + slot] = make_int2(src[i], __float_as_int(w[i]));
}
__global__ void deg_k(const int2* __restrict__ epk, const int* __restrict__ rowptr,
                      float* __restrict__ dinv, int N, int N1, int E) {
  int t = blockIdx.x & 7;
  int n = (blockIdx.x >> 3) * 256 + threadIdx.x;
  if (n >= N) return;
  const int* rp = rowptr + (size_t)t * N1;
  const int2* ep = epk + (size_t)t * E;
  float s = 1.f;  // self loop
  int b = rp[n], e = rp[n + 1];
  for (int j = b; j < e; ++j) s += __int_as_float(ep[j].y);
  dinv[(size_t)t * N + n] = rsqrtf(s);
}
__global__ void norm_k(int2* __restrict__ epk, const int* __restrict__ rowptr,
                       const float* __restrict__ dinv, int N, int N1, int E) {
  int t = blockIdx.x & 7;
  int n = (blockIdx.x >> 3) * 256 + threadIdx.x;
  if (n >= N) return;
  const int* rp = rowptr + (size_t)t * N1;
  const float* dv = dinv + (size_t)t * N;
  int2* ep = epk + (size_t)t * E;
  float dn = dv[n];
  int b = rp[n], e = rp[n + 1];
  for (int j = b; j < e; ++j) {
    int2 ed = ep[j];
    ep[j].y = __float_as_int(dv[ed.x] * __int_as_float(ed.y) * dn);
  }
}

// ---------------- GCN aggregation over split half-tables ----------------
// half = blockIdx&1 -> even/odd blocks land on disjoint XCD sets (round-robin),
// each XCD caches only its 3.2MB half-table -> L2-resident gathers.
__global__ __launch_bounds__(256) void agg2_k(const ushort* __restrict__ xw0, const ushort* __restrict__ xw1,
                                              const float* __restrict__ dinv,
                                              const int* __restrict__ rowptr, const int2* __restrict__ epk,
                                              float* __restrict__ ag, float* __restrict__ oStat, int N) {
  __shared__ float redS[64], redQ[64];
  if (threadIdx.x < 64) { redS[threadIdx.x] = 0.f; redQ[threadIdx.x] = 0.f; }
  __syncthreads();
  const int h = blockIdx.x & 1;
  const ushort* __restrict__ xwh = h ? xw1 : xw0;
  const int f = threadIdx.x & 31;          // feature within half
  const int s = threadIdx.x >> 5;          // 8 node-streams per block
  const int stride = (gridDim.x >> 1) * 8;
  float ssum = 0.f, qsum = 0.f;
  for (int n = (blockIdx.x >> 1) * 8 + s; n < N; n += stride) {
    float di = dinv[n];
    float acc0 = bf2f(xwh[(size_t)n * 32 + f]) * di * di;  // self loop
    float acc1 = 0.f;
    int b = rowptr[n], e = rowptr[n + 1];
    int j = b;
    if ((j & 1) && j < e) {
      int2 e0 = epk[j];
      acc1 += bf2f(xwh[(size_t)e0.x * 32 + f]) * __int_as_float(e0.y);
      ++j;
    }
    for (; j + 3 < e; j += 4) {
      int4 p01 = *(const int4*)&epk[j];
      int4 p23 = *(const int4*)&epk[j + 2];
      acc0 += bf2f(xwh[(size_t)p01.x * 32 + f]) * __int_as_float(p01.y);
      acc1 += bf2f(xwh[(size_t)p01.z * 32 + f]) * __int_as_float(p01.w);
      acc0 += bf2f(xwh[(size_t)p23.x * 32 + f]) * __int_as_float(p23.y);
      acc1 += bf2f(xwh[(size_t)p23.z * 32 + f]) * __int_as_float(p23.w);
    }
    for (; j < e; ++j) {
      int2 e0 = epk[j];
      acc0 += bf2f(xwh[(size_t)e0.x * 32 + f]) * __int_as_float(e0.y);
    }
    float acc = acc0 + acc1;
    ag[(size_t)n * 64 + h * 32 + f] = acc;
    ssum += acc;
    qsum += acc * acc;
  }
  atomicAdd(&redS[h * 32 + f], ssum);
  atomicAdd(&redQ[h * 32 + f], qsum);
  __syncthreads();
  if (threadIdx.x < 64) {
    atomicAdd(&oStat[threadIdx.x], redS[threadIdx.x]);
    atomicAdd(&oStat[128 + threadIdx.x], redQ[threadIdx.x]);
  }
}

// ---------------- classifier final: BN+ReLU(u fp32) @ Wc2 + bc2 ----------------
__global__ __launch_bounds__(256) void final_k(const float* __restrict__ u, const float* __restrict__ st,
                                               const float* __restrict__ g, const float* __restrict__ be,
                                               const float* __restrict__ Wc2, const float* __restrict__ bc2,
                                               float* __restrict__ out, int N) {
  __shared__ float Wl[512], sc[128], sh[128];
  for (int i = threadIdx.x; i < 512; i += 256) Wl[i] = Wc2[i];
  if (threadIdx.x < 128) {
    int c = threadIdx.x;
    float invN = 1.f / (float)N;
    float mn = st[c] * invN;
    float vr = fmaxf(st[128 + c] * invN - mn * mn, 0.f);
    float s = g[c] * rsqrtf(vr + BN_EPS);
    sc[c] = s;
    sh[c] = be[c] - mn * s;
  }
  __syncthreads();
  int idx = blockIdx.x * 256 + threadIdx.x;
  if (idx >= N * 4) return;
  int n = idx >> 2, c = idx & 3;
  const float* ur = u + (size_t)n * 128;
  float acc = bc2[c];
#pragma unroll 8
  for (int k = 0; k < 128; ++k) {
    float v = fmaxf(fmaf(ur[k], sc[k], sh[k]), 0.f);
    acc = fmaf(v, Wl[k * 4 + c], acc);
  }
  out[idx] = acc;
}

extern "C" void kernel_launch(void* const* d_in, const int* in_sizes, int n_in,
                              void* d_out, int out_size, void* d_ws, size_t ws_size,
                              hipStream_t stream) {
  const float* xs   = (const float*)d_in[0];
  const int*   esrc = (const int*)d_in[1];
  const int*   edst = (const int*)d_in[2];
  const float* ew   = (const float*)d_in[3];
  const float* W1   = (const float*)d_in[4];
  const float* g1   = (const float*)d_in[6];
  const float* be1  = (const float*)d_in[7];
  const float* W2   = (const float*)d_in[8];
  const float* g2   = (const float*)d_in[10];
  const float* be2  = (const float*)d_in[11];
  const float* gW   = (const float*)d_in[12];
  const float* gg   = (const float*)d_in[14];
  const float* gbe  = (const float*)d_in[15];
  const float* Wp   = (const float*)d_in[16];
  const float* gp   = (const float*)d_in[18];
  const float* bep  = (const float*)d_in[19];
  const float* Wih  = (const float*)d_in[20];
  const float* Whh  = (const float*)d_in[21];
  const float* bih  = (const float*)d_in[22];
  const float* bhh  = (const float*)d_in[23];
  const float* Wc1  = (const float*)d_in[24];
  const float* gc   = (const float*)d_in[26];
  const float* bec  = (const float*)d_in[27];
  const float* Wc2  = (const float*)d_in[28];
  const float* bc2  = (const float*)d_in[29];
  float* out = (float*)d_out;

  const int T = 8;
  const int N = in_sizes[0] / (T * 32);
  const int E = in_sizes[1] / T;
  const int TE = T * E, TN = T * N, N1 = N + 1;

  // ---- workspace layout (bytes) ----
  size_t off = 0;
  auto alloc = [&](size_t bytes) { size_t o = off; off += (bytes + 255) & ~(size_t)255; return o; };
  char* base = (char*)d_ws;
  size_t oH      = alloc((size_t)T * N * 64 * 2);   // H bf16 (normalized)
  size_t oEpk    = alloc((size_t)TE * 8);           // packed (src, w/norm)
  size_t oRp     = alloc((size_t)T * N1 * 4);       // rowptr
  size_t oDinv   = alloc((size_t)TN * 4);           // dinv
  size_t oStats  = alloc((size_t)49 * 256 * 4);     // stats slots
  size_t oBsum   = alloc((size_t)T * 256 * 4);      // scan block sums
  size_t oWf     = alloc((size_t)70000 * 2);        // prebuilt weight fragments
  size_t oArena  = alloc((size_t)64 * 1024 * 1024); // phase-shared arena
  if (ws_size < off) return;

  ushort* H     = (ushort*)(base + oH);
  int2*   epk   = (int2*)(base + oEpk);
  int*    rowptr= (int*)(base + oRp);
  float*  dinv  = (float*)(base + oDinv);
  float*  statsA= (float*)(base + oStats);
  int*    bsum  = (int*)(base + oBsum);
  ushort* wfA   = (ushort*)(base + oWf);
  char*   arena = base + oArena;

  // weight fragment offsets (ushort elements)
  ushort* W1f  = wfA;               // 32*128  = 4096
  ushort* W2f  = W1f + 4096;        // 128*64  = 8192
  ushort* gW0f = W2f + 8192;        // 64*64   = 4096
  ushort* gW1f = gW0f + 4096;
  ushort* gW2f = gW1f + 4096;
  ushort* Wpf  = gW2f + 4096;       // 64*64
  ushort* Wihf = Wpf + 4096;        // 64*192  = 12288
  ushort* Whhf = Wihf + 12288;
  ushort* Wc1f = Whhf + 12288;      // 64*128  = 8192  (total 61440)

  // prep-phase arena views
  int*    cnt  = (int*)arena;                      // [T*N]
  int*    incl = cnt + TN;                         // [T*N]
  ushort* rank = (ushort*)(incl + TN);             // [T*E] ushort
  // encoder-phase arena views
  float*  y1f  = (float*)arena;                    // [N,128] fp32 raw (also praw)
  float*  hbf  = y1f + (size_t)N * 128;            // [N,64]  fp32 raw
  ushort* hcur = (ushort*)(hbf + (size_t)N * 64);  // [N,64]  bf16 normalized
  ushort* xw0  = hcur + (size_t)N * 64;            // [N,32]  bf16 half-table 0
  ushort* xw1  = xw0 + (size_t)N * 32;             // [N,32]  bf16 half-table 1
  float*  ag   = (float*)(xw1 + (size_t)N * 32);   // [N,64]  fp32 raw agg
  // gru/cls-phase arena views
  ushort* hA = (ushort*)(arena + (size_t)40 * 1024 * 1024);  // [N,64]
  ushort* hB = hA + (size_t)N * 64;
  float*  uf = (float*)arena;                      // [N,128] fp32 ([0,25.6MB))

  const int nb = CDIV(N, 256);

#define SLOT(t, j) (statsA + ((size_t)(t) * 6 + (j)) * 256)

  hipMemsetAsync(statsA, 0, (size_t)49 * 256 * 4, stream);
  hipMemsetAsync(cnt, 0, (size_t)TN * 4, stream);

  // ---- weight fragment prep ----
  wprep_k<32, 128, false><<<1, 256, 0, stream>>>(W1, W1f);
  wprep_k<128, 64, false><<<1, 256, 0, stream>>>(W2, W2f);
  wprep_k<64, 64, false><<<1, 256, 0, stream>>>(gW, gW0f);
  wprep_k<64, 64, false><<<1, 256, 0, stream>>>(gW + 4096, gW1f);
  wprep_k<64, 64, false><<<1, 256, 0, stream>>>(gW + 8192, gW2f);
  wprep_k<64, 64, false><<<1, 256, 0, stream>>>(Wp, Wpf);
  wprep_k<64, 192, true><<<1, 256, 0, stream>>>(Wih, Wihf);
  wprep_k<64, 192, true><<<1, 256, 0, stream>>>(Whh, Whhf);

  // ================= batched graph prep (all T, XCD-partitioned) =================
  const int nbe = CDIV(E, 256);
  hist_k<<<8 * nbe, 256, 0, stream>>>(edst, cnt, rank, N, E);
  scan1_k<<<dim3(nb, T), 256, 0, stream>>>(cnt, incl, bsum, N);
  scan2_k<<<dim3(1, T), 256, 0, stream>>>(bsum, nb);
  scan3_k<<<dim3(nb, T), 256, 0, stream>>>(incl, cnt, bsum, rowptr, N, E);
  scat_k<<<8 * nbe, 256, 0, stream>>>(esrc, edst, ew, rank, rowptr, epk, N1, E);
  deg_k<<<8 * nb, 256, 0, stream>>>(epk, rowptr, dinv, N, N1, E);
  norm_k<<<8 * nb, 256, 0, stream>>>(epk, rowptr, dinv, N, N1, E);
  wprep_k<64, 128, false><<<1, 256, 0, stream>>>(Wc1, Wc1f);

  const int gemmGrid = CDIV(N, 128);
  const float* ncf = nullptr;
  float* nmf = nullptr;
  ushort* nus = nullptr;
  const ushort* ncus = nullptr;

  // ================= encoder over T timesteps =================
  for (int t = 0; t < T; ++t) {
    const float* xt = xs + (size_t)t * N * 32;
    const int* rpT = rowptr + (size_t)t * N1;
    const int2* epkT = epk + (size_t)t * E;
    const float* dinvT = dinv + (size_t)t * N;

    // MLP1: y1f(fp32 raw) = xt @ W1, stats0
    gemm2<32, 128, 1, true, true, false, false><<<gemmGrid, 256, 0, stream>>>(
        xt, ncf, W1f, y1f, nus, nus, ncf, ncf, ncf, SLOT(t, 0),
        ncus, ncf, ncf, nus, N);
    // MLP2: hbf(fp32 raw) = BNReLU(y1f) @ W2, stats1
    gemm2<128, 64, 2, true, true, false, false><<<gemmGrid, 256, 0, stream>>>(
        y1f, ncf, W2f, hbf, nus, nus, SLOT(t, 0), g1, be1, SLOT(t, 1),
        ncus, ncf, ncf, nus, N);
    // GCN0: A = BNReLU(hbf) [-> side hcur], out split xw0/xw1
    gemm2<64, 64, 2, false, false, true, false, true><<<gemmGrid, 256, 0, stream>>>(
        hbf, ncf, gW0f, xw0, xw1, hcur, SLOT(t, 1), g2, be2, nmf,
        ncus, ncf, ncf, nus, N);
    agg2_k<<<4096, 256, 0, stream>>>(xw0, xw1, dinvT, rpT, epkT, ag, SLOT(t, 2), N);
    // GCN1: A = hcur + ReLU(BN(ag)) [-> side hcur], out split
    gemm2<64, 64, 3, false, false, true, false, true><<<gemmGrid, 256, 0, stream>>>(
        hcur, ag, gW1f, xw0, xw1, hcur, SLOT(t, 2), gg, gbe, nmf,
        ncus, ncf, ncf, nus, N);
    agg2_k<<<4096, 256, 0, stream>>>(xw0, xw1, dinvT, rpT, epkT, ag, SLOT(t, 3), N);
    // GCN2
    gemm2<64, 64, 3, false, false, true, false, true><<<gemmGrid, 256, 0, stream>>>(
        hcur, ag, gW2f, xw0, xw1, hcur, SLOT(t, 3), gg + 64, gbe + 64, nmf,
        ncus, ncf, ncf, nus, N);
    agg2_k<<<4096, 256, 0, stream>>>(xw0, xw1, dinvT, rpT, epkT, ag, SLOT(t, 4), N);
    // POST: A = hcur + ReLU(BN(ag)), out praw(y1f) fp32 + stats5
    gemm2<64, 64, 3, true, true, false, false><<<gemmGrid, 256, 0, stream>>>(
        hcur, ag, Wpf, y1f, nus, nus, SLOT(t, 4), gg + 128, gbe + 128, SLOT(t, 5),
        ncus, ncf, ncf, nus, N);
    bnbf_k<<<CDIV(N * 16, 256), 256, 0, stream>>>(y1f, H + (size_t)t * N * 64, SLOT(t, 5), gp, bep, N, 64);
  }

  // ================= GRU over T steps (fused dual-GEMM + gate) =================
  hipMemsetAsync(hA, 0, (size_t)N * 64 * 2, stream);
  ushort* hprev = hA;
  ushort* hnext = hB;
  for (int t = 0; t < T; ++t) {
    gruf_k<<<gemmGrid, 256, 0, stream>>>(H + (size_t)t * N * 64, hprev, Wihf, Whhf,
                                         bih, bhh, hnext, N);
    ushort* tmp = hprev; hprev = hnext; hnext = tmp;
  }
  // after 8 steps hprev == hA (arena+40MB; uf occupies [0,25.6MB) - no overlap)

  // ================= classifier =================
  gemm2<64, 128, 0, true, true, false, false><<<gemmGrid, 256, 0, stream>>>(
      hprev, ncf, Wc1f, uf, nus, nus, ncf, ncf, ncf, statsA + 48 * 256,
      ncus, ncf, ncf, nus, N);
  final_k<<<CDIV(N * 4, 256), 256, 0, stream>>>(uf, statsA + 48 * 256, gc, bec, Wc2, bc2, out, N);
}

// Round 10
// 3516.155 us; speedup vs baseline: 1.3102x; 1.3102x over previous
//
#include <hip/hip_runtime.h>
#include <hip/hip_bf16.h>
#include <cstddef>

#define CDIV(a,b) (((a)+(b)-1)/(b))

static constexpr float BN_EPS = 1e-5f;

typedef __attribute__((ext_vector_type(8))) short short8v;   // 8 bf16 (4 VGPRs)
typedef __attribute__((ext_vector_type(4))) float f32x4;

__device__ inline ushort f2bf(float x) {
  unsigned u = __float_as_uint(x);
  unsigned r = (u + 0x7fffu + ((u >> 16) & 1u)) >> 16;
  return (ushort)r;
}
__device__ inline float bf2f(ushort h) {
  return __uint_as_float(((unsigned)h) << 16);
}

// ---------------- weight fragment prep (once per launch) ----------------
// Wf layout: Wf[((mt*NKC+kc)*64 + lane)*8 + j], lane=((kr>>3)<<4)|(m&15), j=kr&7
template<int K, int M, bool TRANSW>
__global__ void wprep_k(const float* __restrict__ W, ushort* __restrict__ Wf) {
  constexpr int NKC = K / 32;
  for (int i = threadIdx.x; i < K * M; i += 256) {
    int k, m;
    if (TRANSW) { m = i / K; k = i - m * K; }
    else        { k = i / M; m = i - k * M; }
    float wv = W[i];
    int mt = m >> 4, ml = m & 15, kc = k >> 5, kr = k & 31;
    int lane = ((kr >> 3) << 4) | ml;
    int j = kr & 7;
    Wf[(size_t)((mt * NKC + kc) * 64 + lane) * 8 + j] = f2bf(wv);
  }
}

// =====================================================================
// bf16 MFMA GEMM v2 (round-7/8 structure, passing at 3583us)
// =====================================================================
template<int K, int M, int AMODE, bool FSTAT, bool OUTF32, bool SIDE, bool GATE>
__global__ __launch_bounds__(256)
void gemm2(const void* __restrict__ Ain, const float* __restrict__ A2,
           const ushort* __restrict__ Wf, void* __restrict__ Cout,
           ushort* __restrict__ side,
           const float* __restrict__ aStat, const float* __restrict__ aG,
           const float* __restrict__ aB, float* __restrict__ oStat,
           const ushort* __restrict__ gi, const float* __restrict__ bih,
           const float* __restrict__ bhh, ushort* __restrict__ hnext, int N) {
  constexpr int BM = 128;
  constexpr int NKC = K / 32;
  constexpr int NMT = M / 16;
  constexpr bool BN = (AMODE >= 2);
  __shared__ __align__(16) ushort As[BM * K];
  __shared__ __align__(16) ushort WfL[M * K];
  __shared__ float bnSc[BN ? K : 1];
  __shared__ float bnSh[BN ? K : 1];
  __shared__ float redS[FSTAT ? M : 1];
  __shared__ float redQ[FSTAT ? M : 1];
  __shared__ float bihL[GATE ? 192 : 1];
  __shared__ float bhhL[GATE ? 192 : 1];
  const int tid = threadIdx.x;
  const int row0 = blockIdx.x * BM;

  for (int i = tid; i < K * M / 8; i += 256)
    ((short8v*)WfL)[i] = ((const short8v*)Wf)[i];
  if (GATE) {
    if (tid < 192) { bihL[tid] = bih[tid]; bhhL[tid] = bhh[tid]; }
  }
  if (BN) {
    float invN = 1.f / (float)N;
    for (int i = tid; i < K; i += 256) {
      float mn = aStat[i] * invN;
      float vr = fmaxf(aStat[128 + i] * invN - mn * mn, 0.f);
      float sc = aG[i] * rsqrtf(vr + BN_EPS);
      bnSc[i] = sc;
      bnSh[i] = aB[i] - mn * sc;
    }
    __syncthreads();  // bnSc/bnSh must be visible to all threads before A-staging
  }
  if (FSTAT) {
    if (tid < M) { redS[tid] = 0.f; redQ[tid] = 0.f; }
  }

  {
    const float* Af = (const float*)Ain;
    const ushort* Ab = (const ushort*)Ain;
    for (int i = tid; i < BM * K / 4; i += 256) {
      int row = (i * 4) / K, k0 = (i * 4) % K;
      int grow = row0 + row;
      ushort h4[4] = {0, 0, 0, 0};
      if (AMODE == 0) {
        if (grow < N) *(ushort4*)h4 = *(const ushort4*)&Ab[(size_t)grow * K + k0];
      } else if (AMODE == 1) {
        float vv[4] = {0.f, 0.f, 0.f, 0.f};
        if (grow < N) *(float4*)vv = *(const float4*)&Af[(size_t)grow * K + k0];
#pragma unroll
        for (int c = 0; c < 4; ++c) h4[c] = f2bf(vv[c]);
      } else {
        float vv[4] = {0.f, 0.f, 0.f, 0.f};
        if (grow < N) {
          float rw[4];
          if (AMODE == 2) *(float4*)rw = *(const float4*)&Af[(size_t)grow * K + k0];
          else            *(float4*)rw = *(const float4*)&A2[(size_t)grow * K + k0];
          ushort b4[4];
          if (AMODE == 3) *(ushort4*)b4 = *(const ushort4*)&Ab[(size_t)grow * K + k0];
#pragma unroll
          for (int c = 0; c < 4; ++c) {
            float v = fmaxf(fmaf(rw[c], bnSc[k0 + c], bnSh[k0 + c]), 0.f);
            vv[c] = (AMODE == 3) ? bf2f(b4[c]) + v : v;
            h4[c] = f2bf(vv[c]);
          }
          if (SIDE) *(ushort4*)&side[(size_t)grow * K + k0] = *(ushort4*)h4;
        }
      }
      unsigned off = ((unsigned)(row * K + k0) * 2u) ^ (((unsigned)(row & 7)) << 4);
      *(ushort4*)((char*)As + off) = *(ushort4*)h4;
    }
  }
  __syncthreads();

  const int wvi = tid >> 6, lane = tid & 63;
  const int lrow = lane & 15, lkg = lane >> 4;

  short8v af[2][NKC];
#pragma unroll
  for (int rt = 0; rt < 2; ++rt)
#pragma unroll
    for (int kc = 0; kc < NKC; ++kc) {
      int row = wvi * 32 + rt * 16 + lrow;
      unsigned off = ((unsigned)(row * K + kc * 32 + lkg * 8) * 2u) ^ (((unsigned)(row & 7)) << 4);
      af[rt][kc] = *(const short8v*)((const char*)As + off);
    }

  f32x4 acc[2][NMT];
#pragma unroll
  for (int rt = 0; rt < 2; ++rt)
#pragma unroll
    for (int mt = 0; mt < NMT; ++mt) acc[rt][mt] = f32x4{0.f, 0.f, 0.f, 0.f};

#pragma unroll
  for (int mt = 0; mt < NMT; ++mt) {
    short8v bf[NKC];
#pragma unroll
    for (int kc = 0; kc < NKC; ++kc)
      bf[kc] = *(const short8v*)&WfL[(size_t)((mt * NKC + kc) * 64 + lane) * 8];
#pragma unroll
    for (int rt = 0; rt < 2; ++rt)
#pragma unroll
      for (int kc = 0; kc < NKC; ++kc)
        acc[rt][mt] = __builtin_amdgcn_mfma_f32_16x16x32_bf16(af[rt][kc], bf[kc], acc[rt][mt], 0, 0, 0);
  }

  if (GATE) {
#pragma unroll
    for (int rt = 0; rt < 2; ++rt)
#pragma unroll
      for (int i = 0; i < 4; ++i) {
        int grow = row0 + wvi * 32 + rt * 16 + lkg * 4 + i;
        if (grow < N) {
          const ushort* gip = gi + (size_t)grow * 192;
          const ushort* hpp = (const ushort*)Ain + (size_t)grow * 64;
#pragma unroll
          for (int mtj = 0; mtj < 4; ++mtj) {
            int j = mtj * 16 + lrow;
            float ir = bf2f(gip[j]) + bihL[j];
            float iz = bf2f(gip[64 + j]) + bihL[64 + j];
            float ig = bf2f(gip[128 + j]) + bihL[128 + j];
            float hr = acc[rt][mtj][i] + bhhL[j];
            float hz = acc[rt][mtj + 4][i] + bhhL[64 + j];
            float hg = acc[rt][mtj + 8][i] + bhhL[128 + j];
            float r = 1.f / (1.f + expf(-(ir + hr)));
            float z = 1.f / (1.f + expf(-(iz + hz)));
            float ng = tanhf(ig + r * hg);
            float hn = (1.f - z) * ng + z * bf2f(hpp[j]);
            hnext[(size_t)grow * 64 + j] = f2bf(hn);
          }
        }
      }
    return;
  }

#pragma unroll
  for (int rt = 0; rt < 2; ++rt)
#pragma unroll
    for (int mt = 0; mt < NMT; ++mt) {
#pragma unroll
      for (int i = 0; i < 4; ++i) {
        int grow = row0 + wvi * 32 + rt * 16 + lkg * 4 + i;
        if (grow < N) {
          if (OUTF32) ((float*)Cout)[(size_t)grow * M + mt * 16 + lrow] = acc[rt][mt][i];
          else        ((ushort*)Cout)[(size_t)grow * M + mt * 16 + lrow] = f2bf(acc[rt][mt][i]);
        }
      }
    }

  if (FSTAT) {
#pragma unroll
    for (int mt = 0; mt < NMT; ++mt) {
      float s = 0.f, q = 0.f;
#pragma unroll
      for (int rt = 0; rt < 2; ++rt)
#pragma unroll
        for (int i = 0; i < 4; ++i) {
          int grow = row0 + wvi * 32 + rt * 16 + lkg * 4 + i;
          if (grow < N) { float v = acc[rt][mt][i]; s += v; q += v * v; }
        }
      s += __shfl_xor(s, 16); s += __shfl_xor(s, 32);
      q += __shfl_xor(q, 16); q += __shfl_xor(q, 32);
      if (lkg == 0) {
        atomicAdd(&redS[mt * 16 + lrow], s);
        atomicAdd(&redQ[mt * 16 + lrow], q);
      }
    }
    __syncthreads();
    if (tid < M) {
      atomicAdd(&oStat[tid], redS[tid]);
      atomicAdd(&oStat[128 + tid], redQ[tid]);
    }
  }
}

// ---------------- fused GRU step: hnext = GRU(Ht, hprev) ----------------
__global__ __launch_bounds__(256)
void gruf_k(const ushort* __restrict__ Ht, const ushort* __restrict__ hprev,
            const ushort* __restrict__ Wihf, const ushort* __restrict__ Whhf,
            const float* __restrict__ bih, const float* __restrict__ bhh,
            ushort* __restrict__ hnext, int N) {
  __shared__ float bihL[192], bhhL[192];
  const int tid = threadIdx.x;
  if (tid < 192) { bihL[tid] = bih[tid]; bhhL[tid] = bhh[tid]; }
  __syncthreads();
  const int wvi = tid >> 6, lane = tid & 63;
  const int lrow = lane & 15, lkg = lane >> 4;
  const int row0 = blockIdx.x * 128;
  const short8v zv = short8v{0, 0, 0, 0, 0, 0, 0, 0};
  for (int rt = 0; rt < 2; ++rt) {
    int arow = row0 + wvi * 32 + rt * 16 + lrow;
    bool aok = arow < N;
    short8v afA[2], afB[2];
#pragma unroll
    for (int kc = 0; kc < 2; ++kc) {
      afA[kc] = aok ? *(const short8v*)&Ht[(size_t)arow * 64 + kc * 32 + lkg * 8] : zv;
      afB[kc] = aok ? *(const short8v*)&hprev[(size_t)arow * 64 + kc * 32 + lkg * 8] : zv;
    }
    f32x4 gacc[12], hacc[12];
#pragma unroll
    for (int mt = 0; mt < 12; ++mt) {
      gacc[mt] = f32x4{0.f, 0.f, 0.f, 0.f};
      hacc[mt] = f32x4{0.f, 0.f, 0.f, 0.f};
#pragma unroll
      for (int kc = 0; kc < 2; ++kc) {
        short8v bwi = *(const short8v*)&Wihf[(size_t)((mt * 2 + kc) * 64 + lane) * 8];
        short8v bwh = *(const short8v*)&Whhf[(size_t)((mt * 2 + kc) * 64 + lane) * 8];
        gacc[mt] = __builtin_amdgcn_mfma_f32_16x16x32_bf16(afA[kc], bwi, gacc[mt], 0, 0, 0);
        hacc[mt] = __builtin_amdgcn_mfma_f32_16x16x32_bf16(afB[kc], bwh, hacc[mt], 0, 0, 0);
      }
    }
#pragma unroll
    for (int i = 0; i < 4; ++i) {
      int grow = row0 + wvi * 32 + rt * 16 + lkg * 4 + i;
      if (grow < N) {
        const ushort* hpp = hprev + (size_t)grow * 64;
#pragma unroll
        for (int mtj = 0; mtj < 4; ++mtj) {
          int j = mtj * 16 + lrow;
          float ir = gacc[mtj][i] + bihL[j];
          float iz = gacc[mtj + 4][i] + bihL[64 + j];
          float ig = gacc[mtj + 8][i] + bihL[128 + j];
          float hr = hacc[mtj][i] + bhhL[j];
          float hz = hacc[mtj + 4][i] + bhhL[64 + j];
          float hg = hacc[mtj + 8][i] + bhhL[128 + j];
          float r = 1.f / (1.f + expf(-(ir + hr)));
          float z = 1.f / (1.f + expf(-(iz + hz)));
          float ng = tanhf(ig + r * hg);
          float hn = (1.f - z) * ng + z * bf2f(hpp[j]);
          hnext[(size_t)grow * 64 + j] = f2bf(hn);
        }
      }
    }
  }
}

// ---------------- BN+ReLU (fp32 raw in -> bf16 normalized out) ----------------
__global__ __launch_bounds__(256) void bnbf_k(const float* __restrict__ X, ushort* __restrict__ Y,
                                              const float* __restrict__ st,
                                              const float* __restrict__ g, const float* __restrict__ be,
                                              int N, int M) {
  int i4 = blockIdx.x * 256 + threadIdx.x;
  int total = N * M / 4;
  if (i4 >= total) return;
  int c0 = (i4 * 4) % M;
  float invN = 1.f / (float)N;
  float xv[4];
  *(float4*)xv = *(const float4*)&X[(size_t)i4 * 4];
  ushort yv[4];
#pragma unroll
  for (int j = 0; j < 4; ++j) {
    int c = c0 + j;
    float mn = st[c] * invN;
    float vr = fmaxf(st[128 + c] * invN - mn * mn, 0.f);
    float sc = g[c] * rsqrtf(vr + BN_EPS);
    float v = (xv[j] - mn) * sc + be[c];
    yv[j] = f2bf(fmaxf(v, 0.f));
  }
  *(ushort4*)&Y[(size_t)i4 * 4] = *(ushort4*)yv;
}

// ---------------- batched graph prep (t = blockIdx.x & 7) ----------------
__global__ void hist_k(const int* __restrict__ dst, int* __restrict__ cnt, ushort* __restrict__ rank,
                       int N, int E) {
  int t = blockIdx.x & 7;
  int e = (blockIdx.x >> 3) * 256 + threadIdx.x;
  if (e >= E) return;
  size_t i = (size_t)t * E + e;
  rank[i] = (ushort)atomicAdd(&cnt[t * N + dst[i]], 1);
}
__global__ __launch_bounds__(256) void scan1_k(const int* __restrict__ in, int* __restrict__ incl,
                                               int* __restrict__ bsum, int n) {
  int t = blockIdx.y;
  const int* inp = in + (size_t)t * n;
  int* ip = incl + (size_t)t * n;
  int i = blockIdx.x * 256 + threadIdx.x;
  int v = (i < n) ? inp[i] : 0;
  int lane = threadIdx.x & 63;
  int sidx = threadIdx.x >> 6;
  int sv = v;
  for (int off = 1; off < 64; off <<= 1) {
    int tt = __shfl_up(sv, off, 64);
    if (lane >= off) sv += tt;
  }
  __shared__ int wsum[4];
  if (lane == 63) wsum[sidx] = sv;
  __syncthreads();
  int add = 0;
  for (int w = 0; w < sidx; ++w) add += wsum[w];
  sv += add;
  if (i < n) ip[i] = sv;
  if (threadIdx.x == 255) bsum[t * 256 + blockIdx.x] = sv;
}
__global__ __launch_bounds__(256) void scan2_k(int* __restrict__ bsum, int nb) {
  int t = blockIdx.y;
  int* bp = bsum + t * 256;
  int i = threadIdx.x;
  int v = (i < nb) ? bp[i] : 0;
  int lane = threadIdx.x & 63;
  int sidx = threadIdx.x >> 6;
  int sv = v;
  for (int off = 1; off < 64; off <<= 1) {
    int tt = __shfl_up(sv, off, 64);
    if (lane >= off) sv += tt;
  }
  __shared__ int wsum[4];
  if (lane == 63) wsum[sidx] = sv;
  __syncthreads();
  int add = 0;
  for (int w = 0; w < sidx; ++w) add += wsum[w];
  sv += add;
  if (i < nb) bp[i] = sv;
}
__global__ void scan3_k(const int* __restrict__ incl, const int* __restrict__ cnt,
                        const int* __restrict__ bsum, int* __restrict__ rowptr, int n, int E) {
  int t = blockIdx.y;
  int i = blockIdx.x * 256 + threadIdx.x;
  int* rp = rowptr + (size_t)t * (n + 1);
  if (i < n) {
    int v = incl[(size_t)t * n + i] - cnt[(size_t)t * n + i] +
            (blockIdx.x ? bsum[t * 256 + blockIdx.x - 1] : 0);
    rp[i] = v;
  }
  if (i == 0) rp[n] = E;
}
__global__ void scat_k(const int* __restrict__ src, const int* __restrict__ dst,
                       const float* __restrict__ w, const ushort* __restrict__ rank,
                       const int* __restrict__ rowptr, int2* __restrict__ epk,
                       int N1, int E) {
  int t = blockIdx.x & 7;
  int e = (blockIdx.x >> 3) * 256 + threadIdx.x;
  if (e >= E) return;
  size_t i = (size_t)t * E + e;
  int slot = rowptr[(size_t)t * N1 + dst[i]] + (int)rank[i];
  epk[(size_t)t * E + slot] = make_int2(src[i], __float_as_int(w[i]));
}
__global__ void deg_k(const int2* __restrict__ epk, const int* __restrict__ rowptr,
                      float* __restrict__ dinv, int N, int N1, int E) {
  int t = blockIdx.x & 7;
  int n = (blockIdx.x >> 3) * 256 + threadIdx.x;
  if (n >= N) return;
  const int* rp = rowptr + (size_t)t * N1;
  const int2* ep = epk + (size_t)t * E;
  float s = 1.f;  // self loop
  int b = rp[n], e = rp[n + 1];
  for (int j = b; j < e; ++j) s += __int_as_float(ep[j].y);
  dinv[(size_t)t * N + n] = rsqrtf(s);
}
__global__ void norm_k(int2* __restrict__ epk, const int* __restrict__ rowptr,
                       const float* __restrict__ dinv, int N, int N1, int E) {
  int t = blockIdx.x & 7;
  int n = (blockIdx.x >> 3) * 256 + threadIdx.x;
  if (n >= N) return;
  const int* rp = rowptr + (size_t)t * N1;
  const float* dv = dinv + (size_t)t * N;
  int2* ep = epk + (size_t)t * E;
  float dn = dv[n];
  int b = rp[n], e = rp[n + 1];
  for (int j = b; j < e; ++j) {
    int2 ed = ep[j];
    ep[j].y = __float_as_int(dv[ed.x] * __int_as_float(ed.y) * dn);
  }
}

// ---------------- GCN aggregation (round-8 wave-coherent version) ----------------
__global__ __launch_bounds__(256) void agg_k(const ushort* __restrict__ xw, const float* __restrict__ dinv,
                                             const int* __restrict__ rowptr, const int2* __restrict__ epk,
                                             float* __restrict__ ag, float* __restrict__ oStat, int N) {
  __shared__ float redS[64], redQ[64];
  if (threadIdx.x < 64) { redS[threadIdx.x] = 0.f; redQ[threadIdx.x] = 0.f; }
  __syncthreads();
  int f = threadIdx.x & 63;
  int wvl = threadIdx.x >> 6;
  int stride = gridDim.x * 4;
  float s = 0.f, q = 0.f;
  for (int n = blockIdx.x * 4 + wvl; n < N; n += stride) {
    float di = dinv[n];
    float acc0 = bf2f(xw[(size_t)n * 64 + f]) * di * di;  // self loop
    float acc1 = 0.f;
    int b = rowptr[n], e = rowptr[n + 1];
    int j = b;
    if ((j & 1) && j < e) {   // align to 16B for int4 loads
      int2 e0 = epk[j];
      acc1 += bf2f(xw[(size_t)e0.x * 64 + f]) * __int_as_float(e0.y);
      ++j;
    }
    for (; j + 3 < e; j += 4) {
      int4 p01 = *(const int4*)&epk[j];
      int4 p23 = *(const int4*)&epk[j + 2];
      acc0 += bf2f(xw[(size_t)p01.x * 64 + f]) * __int_as_float(p01.y);
      acc1 += bf2f(xw[(size_t)p01.z * 64 + f]) * __int_as_float(p01.w);
      acc0 += bf2f(xw[(size_t)p23.x * 64 + f]) * __int_as_float(p23.y);
      acc1 += bf2f(xw[(size_t)p23.z * 64 + f]) * __int_as_float(p23.w);
    }
    for (; j < e; ++j) {
      int2 e0 = epk[j];
      acc0 += bf2f(xw[(size_t)e0.x * 64 + f]) * __int_as_float(e0.y);
    }
    float acc = acc0 + acc1;
    ag[(size_t)n * 64 + f] = acc;
    s += acc;
    q += acc * acc;
  }
  atomicAdd(&redS[f], s);
  atomicAdd(&redQ[f], q);
  __syncthreads();
  if (threadIdx.x < 64) {
    atomicAdd(&oStat[threadIdx.x], redS[threadIdx.x]);
    atomicAdd(&oStat[128 + threadIdx.x], redQ[threadIdx.x]);
  }
}

// ---------------- classifier final: BN+ReLU(u fp32) @ Wc2 + bc2 ----------------
__global__ __launch_bounds__(256) void final_k(const float* __restrict__ u, const float* __restrict__ st,
                                               const float* __restrict__ g, const float* __restrict__ be,
                                               const float* __restrict__ Wc2, const float* __restrict__ bc2,
                                               float* __restrict__ out, int N) {
  __shared__ float Wl[512], sc[128], sh[128];
  for (int i = threadIdx.x; i < 512; i += 256) Wl[i] = Wc2[i];
  if (threadIdx.x < 128) {
    int c = threadIdx.x;
    float invN = 1.f / (float)N;
    float mn = st[c] * invN;
    float vr = fmaxf(st[128 + c] * invN - mn * mn, 0.f);
    float s = g[c] * rsqrtf(vr + BN_EPS);
    sc[c] = s;
    sh[c] = be[c] - mn * s;
  }
  __syncthreads();
  int idx = blockIdx.x * 256 + threadIdx.x;
  if (idx >= N * 4) return;
  int n = idx >> 2, c = idx & 3;
  const float* ur = u + (size_t)n * 128;
  float acc = bc2[c];
#pragma unroll 8
  for (int k = 0; k < 128; ++k) {
    float v = fmaxf(fmaf(ur[k], sc[k], sh[k]), 0.f);
    acc = fmaf(v, Wl[k * 4 + c], acc);
  }
  out[idx] = acc;
}

extern "C" void kernel_launch(void* const* d_in, const int* in_sizes, int n_in,
                              void* d_out, int out_size, void* d_ws, size_t ws_size,
                              hipStream_t stream) {
  const float* xs   = (const float*)d_in[0];
  const int*   esrc = (const int*)d_in[1];
  const int*   edst = (const int*)d_in[2];
  const float* ew   = (const float*)d_in[3];
  const float* W1   = (const float*)d_in[4];
  const float* g1   = (const float*)d_in[6];
  const float* be1  = (const float*)d_in[7];
  const float* W2   = (const float*)d_in[8];
  const float* g2   = (const float*)d_in[10];
  const float* be2  = (const float*)d_in[11];
  const float* gW   = (const float*)d_in[12];
  const float* gg   = (const float*)d_in[14];
  const float* gbe  = (const float*)d_in[15];
  const float* Wp   = (const float*)d_in[16];
  const float* gp   = (const float*)d_in[18];
  const float* bep  = (const float*)d_in[19];
  const float* Wih  = (const float*)d_in[20];
  const float* Whh  = (const float*)d_in[21];
  const float* bih  = (const float*)d_in[22];
  const float* bhh  = (const float*)d_in[23];
  const float* Wc1  = (const float*)d_in[24];
  const float* gc   = (const float*)d_in[26];
  const float* bec  = (const float*)d_in[27];
  const float* Wc2  = (const float*)d_in[28];
  const float* bc2  = (const float*)d_in[29];
  float* out = (float*)d_out;

  const int T = 8;
  const int N = in_sizes[0] / (T * 32);
  const int E = in_sizes[1] / T;
  const int TE = T * E, TN = T * N, N1 = N + 1;

  // ---- workspace layout (bytes) ----
  size_t off = 0;
  auto alloc = [&](size_t bytes) { size_t o = off; off += (bytes + 255) & ~(size_t)255; return o; };
  char* base = (char*)d_ws;
  size_t oH      = alloc((size_t)T * N * 64 * 2);   // H bf16 (normalized)
  size_t oEpk    = alloc((size_t)TE * 8);           // packed (src, w/norm)
  size_t oRp     = alloc((size_t)T * N1 * 4);       // rowptr
  size_t oDinv   = alloc((size_t)TN * 4);           // dinv
  size_t oStats  = alloc((size_t)49 * 256 * 4);     // stats slots
  size_t oBsum   = alloc((size_t)T * 256 * 4);      // scan block sums
  size_t oWf     = alloc((size_t)70000 * 2);        // prebuilt weight fragments
  size_t oArena  = alloc((size_t)64 * 1024 * 1024); // phase-shared arena
  if (ws_size < off) return;

  ushort* H     = (ushort*)(base + oH);
  int2*   epk   = (int2*)(base + oEpk);
  int*    rowptr= (int*)(base + oRp);
  float*  dinv  = (float*)(base + oDinv);
  float*  statsA= (float*)(base + oStats);
  int*    bsum  = (int*)(base + oBsum);
  ushort* wfA   = (ushort*)(base + oWf);
  char*   arena = base + oArena;

  // weight fragment offsets (ushort elements)
  ushort* W1f  = wfA;               // 32*128  = 4096
  ushort* W2f  = W1f + 4096;        // 128*64  = 8192
  ushort* gW0f = W2f + 8192;        // 64*64   = 4096
  ushort* gW1f = gW0f + 4096;
  ushort* gW2f = gW1f + 4096;
  ushort* Wpf  = gW2f + 4096;       // 64*64
  ushort* Wihf = Wpf + 4096;        // 64*192  = 12288
  ushort* Whhf = Wihf + 12288;
  ushort* Wc1f = Whhf + 12288;      // 64*128  = 8192  (total 61440)

  // prep-phase arena views
  int*    cnt  = (int*)arena;                      // [T*N]
  int*    incl = cnt + TN;                         // [T*N]
  ushort* rank = (ushort*)(incl + TN);             // [T*E] ushort
  // encoder-phase arena views
  float*  y1f  = (float*)arena;                    // [N,128] fp32 raw (also praw)
  float*  hbf  = y1f + (size_t)N * 128;            // [N,64]  fp32 raw
  ushort* hcur = (ushort*)(hbf + (size_t)N * 64);  // [N,64]  bf16 normalized
  ushort* xwb  = hcur + (size_t)N * 64;            // [N,64]  bf16 gather table
  float*  ag   = (float*)(xwb + (size_t)N * 64);   // [N,64]  fp32 raw agg
  // gru/cls-phase arena views
  ushort* hA = (ushort*)(arena + (size_t)40 * 1024 * 1024);  // [N,64]
  ushort* hB = hA + (size_t)N * 64;
  float*  uf = (float*)arena;                      // [N,128] fp32 ([0,25.6MB))

  const int nb = CDIV(N, 256);

#define SLOT(t, j) (statsA + ((size_t)(t) * 6 + (j)) * 256)

  hipMemsetAsync(statsA, 0, (size_t)49 * 256 * 4, stream);
  hipMemsetAsync(cnt, 0, (size_t)TN * 4, stream);

  // ---- weight fragment prep ----
  wprep_k<32, 128, false><<<1, 256, 0, stream>>>(W1, W1f);
  wprep_k<128, 64, false><<<1, 256, 0, stream>>>(W2, W2f);
  wprep_k<64, 64, false><<<1, 256, 0, stream>>>(gW, gW0f);
  wprep_k<64, 64, false><<<1, 256, 0, stream>>>(gW + 4096, gW1f);
  wprep_k<64, 64, false><<<1, 256, 0, stream>>>(gW + 8192, gW2f);
  wprep_k<64, 64, false><<<1, 256, 0, stream>>>(Wp, Wpf);
  wprep_k<64, 192, true><<<1, 256, 0, stream>>>(Wih, Wihf);
  wprep_k<64, 192, true><<<1, 256, 0, stream>>>(Whh, Whhf);

  // ================= batched graph prep (all T, XCD-partitioned) =================
  const int nbe = CDIV(E, 256);
  hist_k<<<8 * nbe, 256, 0, stream>>>(edst, cnt, rank, N, E);
  scan1_k<<<dim3(nb, T), 256, 0, stream>>>(cnt, incl, bsum, N);
  scan2_k<<<dim3(1, T), 256, 0, stream>>>(bsum, nb);
  scan3_k<<<dim3(nb, T), 256, 0, stream>>>(incl, cnt, bsum, rowptr, N, E);
  scat_k<<<8 * nbe, 256, 0, stream>>>(esrc, edst, ew, rank, rowptr, epk, N1, E);
  deg_k<<<8 * nb, 256, 0, stream>>>(epk, rowptr, dinv, N, N1, E);
  norm_k<<<8 * nb, 256, 0, stream>>>(epk, rowptr, dinv, N, N1, E);
  wprep_k<64, 128, false><<<1, 256, 0, stream>>>(Wc1, Wc1f);

  const int gemmGrid = CDIV(N, 128);
  const float* ncf = nullptr;
  float* nmf = nullptr;
  ushort* nus = nullptr;
  const ushort* ncus = nullptr;

  // ================= encoder over T timesteps =================
  for (int t = 0; t < T; ++t) {
    const float* xt = xs + (size_t)t * N * 32;
    const int* rpT = rowptr + (size_t)t * N1;
    const int2* epkT = epk + (size_t)t * E;
    const float* dinvT = dinv + (size_t)t * N;

    // MLP1: y1f(fp32 raw) = xt @ W1, stats0
    gemm2<32, 128, 1, true, true, false, false><<<gemmGrid, 256, 0, stream>>>(
        xt, ncf, W1f, y1f, nus, ncf, ncf, ncf, SLOT(t, 0),
        ncus, ncf, ncf, nus, N);
    // MLP2: hbf(fp32 raw) = BNReLU(y1f) @ W2, stats1
    gemm2<128, 64, 2, true, true, false, false><<<gemmGrid, 256, 0, stream>>>(
        y1f, ncf, W2f, hbf, nus, SLOT(t, 0), g1, be1, SLOT(t, 1),
        ncus, ncf, ncf, nus, N);
    // GCN0: A = BNReLU(hbf) [-> side hcur], out xwb bf16
    gemm2<64, 64, 2, false, false, true, false><<<gemmGrid, 256, 0, stream>>>(
        hbf, ncf, gW0f, xwb, hcur, SLOT(t, 1), g2, be2, nmf,
        ncus, ncf, ncf, nus, N);
    agg_k<<<2048, 256, 0, stream>>>(xwb, dinvT, rpT, epkT, ag, SLOT(t, 2), N);
    // GCN1: A = hcur + ReLU(BN(ag)) [-> side hcur], out xwb
    gemm2<64, 64, 3, false, false, true, false><<<gemmGrid, 256, 0, stream>>>(
        hcur, ag, gW1f, xwb, hcur, SLOT(t, 2), gg, gbe, nmf,
        ncus, ncf, ncf, nus, N);
    agg_k<<<2048, 256, 0, stream>>>(xwb, dinvT, rpT, epkT, ag, SLOT(t, 3), N);
    // GCN2
    gemm2<64, 64, 3, false, false, true, false><<<gemmGrid, 256, 0, stream>>>(
        hcur, ag, gW2f, xwb, hcur, SLOT(t, 3), gg + 64, gbe + 64, nmf,
        ncus, ncf, ncf, nus, N);
    agg_k<<<2048, 256, 0, stream>>>(xwb, dinvT, rpT, epkT, ag, SLOT(t, 4), N);
    // POST: A = hcur + ReLU(BN(ag)), out praw(y1f) fp32 + stats5
    gemm2<64, 64, 3, true, true, false, false><<<gemmGrid, 256, 0, stream>>>(
        hcur, ag, Wpf, y1f, nus, SLOT(t, 4), gg + 128, gbe + 128, SLOT(t, 5),
        ncus, ncf, ncf, nus, N);
    bnbf_k<<<CDIV(N * 16, 256), 256, 0, stream>>>(y1f, H + (size_t)t * N * 64, SLOT(t, 5), gp, bep, N, 64);
  }

  // ================= GRU over T steps (fused dual-GEMM + gate) =================
  hipMemsetAsync(hA, 0, (size_t)N * 64 * 2, stream);
  ushort* hprev = hA;
  ushort* hnext = hB;
  for (int t = 0; t < T; ++t) {
    gruf_k<<<gemmGrid, 256, 0, stream>>>(H + (size_t)t * N * 64, hprev, Wihf, Whhf,
                                         bih, bhh, hnext, N);
    ushort* tmp = hprev; hprev = hnext; hnext = tmp;
  }
  // after 8 steps hprev == hA (arena+40MB; uf occupies [0,25.6MB) - no overlap)

  // ================= classifier =================
  gemm2<64, 128, 0, true, true, false, false><<<gemmGrid, 256, 0, stream>>>(
      hprev, ncf, Wc1f, uf, nus, ncf, ncf, ncf, statsA + 48 * 256,
      ncus, ncf, ncf, nus, N);
  final_k<<<CDIV(N * 4, 256), 256, 0, stream>>>(uf, statsA + 48 * 256, gc, bec, Wc2, bc2, out, N);
}

// Round 11
// 3399.148 us; speedup vs baseline: 1.3553x; 1.0344x over previous
//
#include <hip/hip_runtime.h>
#include <hip/hip_bf16.h>
#include <cstddef>

#define CDIV(a,b) (((a)+(b)-1)/(b))

static constexpr float BN_EPS = 1e-5f;

typedef __attribute__((ext_vector_type(8))) short short8v;   // 8 bf16 (4 VGPRs)
typedef __attribute__((ext_vector_type(4))) float f32x4;

__device__ inline ushort f2bf(float x) {
  unsigned u = __float_as_uint(x);
  unsigned r = (u + 0x7fffu + ((u >> 16) & 1u)) >> 16;
  return (ushort)r;
}
__device__ inline float bf2f(ushort h) {
  return __uint_as_float(((unsigned)h) << 16);
}

// ---------------- weight fragment prep (once per launch) ----------------
// Wf layout: Wf[((mt*NKC+kc)*64 + lane)*8 + j], lane=((kr>>3)<<4)|(m&15), j=kr&7
template<int K, int M, bool TRANSW>
__global__ void wprep_k(const float* __restrict__ W, ushort* __restrict__ Wf) {
  constexpr int NKC = K / 32;
  for (int i = threadIdx.x; i < K * M; i += 256) {
    int k, m;
    if (TRANSW) { m = i / K; k = i - m * K; }
    else        { k = i / M; m = i - k * M; }
    float wv = W[i];
    int mt = m >> 4, ml = m & 15, kc = k >> 5, kr = k & 31;
    int lane = ((kr >> 3) << 4) | ml;
    int j = kr & 7;
    Wf[(size_t)((mt * NKC + kc) * 64 + lane) * 8 + j] = f2bf(wv);
  }
}

// =====================================================================
// bf16 MFMA GEMM v3: C[N,M] = Aeff[N,K] @ W  (fp32 accumulate)
// AMODE: 0 = A bf16 plain; 1 = A fp32 plain;
//        2 = Aeff = ReLU(BN(raw from Ain)); 3 = Aeff = base(bf16 Ain) + ReLU(BN(raw from A2))
// RAW16: the raw source (Ain for mode 2, A2 for mode 3) is bf16 (else fp32).
// Stats are ALWAYS taken from exact fp32 accumulators (FSTAT) - raws only
// round on storage. SIDE: write Aeff bf16 to `side` during staging.
// NOTE: bnSc/bnSh produced by a thread subset, consumed by ALL threads in
// A-staging -> __syncthreads() after their computation is REQUIRED.
// =====================================================================
template<int K, int M, int AMODE, bool RAW16, bool FSTAT, bool OUTF32, bool SIDE>
__global__ __launch_bounds__(256)
void gemm2(const void* __restrict__ Ain, const void* __restrict__ A2,
           const ushort* __restrict__ Wf, void* __restrict__ Cout,
           ushort* __restrict__ side,
           const float* __restrict__ aStat, const float* __restrict__ aG,
           const float* __restrict__ aB, float* __restrict__ oStat, int N) {
  constexpr int BM = 128;
  constexpr int NKC = K / 32;
  constexpr int NMT = M / 16;
  constexpr bool BN = (AMODE >= 2);
  __shared__ __align__(16) ushort As[BM * K];
  __shared__ __align__(16) ushort WfL[M * K];
  __shared__ float bnSc[BN ? K : 1];
  __shared__ float bnSh[BN ? K : 1];
  __shared__ float redS[FSTAT ? M : 1];
  __shared__ float redQ[FSTAT ? M : 1];
  const int tid = threadIdx.x;
  const int row0 = blockIdx.x * BM;

  for (int i = tid; i < K * M / 8; i += 256)
    ((short8v*)WfL)[i] = ((const short8v*)Wf)[i];
  if (BN) {
    float invN = 1.f / (float)N;
    for (int i = tid; i < K; i += 256) {
      float mn = aStat[i] * invN;
      float vr = fmaxf(aStat[128 + i] * invN - mn * mn, 0.f);
      float sc = aG[i] * rsqrtf(vr + BN_EPS);
      bnSc[i] = sc;
      bnSh[i] = aB[i] - mn * sc;
    }
    __syncthreads();  // bnSc/bnSh visible to all threads before A-staging
  }
  if (FSTAT) {
    if (tid < M) { redS[tid] = 0.f; redQ[tid] = 0.f; }
  }

  // ---- A -> XOR-swizzled bf16 LDS ----
  {
    const float*  Af  = (const float*)Ain;
    const ushort* Ab  = (const ushort*)Ain;
    const float*  A2f = (const float*)A2;
    const ushort* A2b = (const ushort*)A2;
    for (int i = tid; i < BM * K / 4; i += 256) {
      int row = (i * 4) / K, k0 = (i * 4) % K;
      int grow = row0 + row;
      ushort h4[4] = {0, 0, 0, 0};
      if (AMODE == 0) {
        if (grow < N) *(ushort4*)h4 = *(const ushort4*)&Ab[(size_t)grow * K + k0];
      } else if (AMODE == 1) {
        float vv[4] = {0.f, 0.f, 0.f, 0.f};
        if (grow < N) *(float4*)vv = *(const float4*)&Af[(size_t)grow * K + k0];
#pragma unroll
        for (int c = 0; c < 4; ++c) h4[c] = f2bf(vv[c]);
      } else {
        if (grow < N) {
          float rw[4];
          if (AMODE == 2) {
            if (RAW16) {
              ushort t4[4];
              *(ushort4*)t4 = *(const ushort4*)&Ab[(size_t)grow * K + k0];
#pragma unroll
              for (int c = 0; c < 4; ++c) rw[c] = bf2f(t4[c]);
            } else {
              *(float4*)rw = *(const float4*)&Af[(size_t)grow * K + k0];
            }
          } else {
            if (RAW16) {
              ushort t4[4];
              *(ushort4*)t4 = *(const ushort4*)&A2b[(size_t)grow * K + k0];
#pragma unroll
              for (int c = 0; c < 4; ++c) rw[c] = bf2f(t4[c]);
            } else {
              *(float4*)rw = *(const float4*)&A2f[(size_t)grow * K + k0];
            }
          }
          ushort b4[4];
          if (AMODE == 3) *(ushort4*)b4 = *(const ushort4*)&Ab[(size_t)grow * K + k0];
#pragma unroll
          for (int c = 0; c < 4; ++c) {
            float v = fmaxf(fmaf(rw[c], bnSc[k0 + c], bnSh[k0 + c]), 0.f);
            float vv = (AMODE == 3) ? bf2f(b4[c]) + v : v;
            h4[c] = f2bf(vv);
          }
          if (SIDE) *(ushort4*)&side[(size_t)grow * K + k0] = *(ushort4*)h4;
        }
      }
      unsigned off = ((unsigned)(row * K + k0) * 2u) ^ (((unsigned)(row & 7)) << 4);
      *(ushort4*)((char*)As + off) = *(ushort4*)h4;
    }
  }
  __syncthreads();

  const int wvi = tid >> 6, lane = tid & 63;
  const int lrow = lane & 15, lkg = lane >> 4;

  short8v af[2][NKC];
#pragma unroll
  for (int rt = 0; rt < 2; ++rt)
#pragma unroll
    for (int kc = 0; kc < NKC; ++kc) {
      int row = wvi * 32 + rt * 16 + lrow;
      unsigned off = ((unsigned)(row * K + kc * 32 + lkg * 8) * 2u) ^ (((unsigned)(row & 7)) << 4);
      af[rt][kc] = *(const short8v*)((const char*)As + off);
    }

  f32x4 acc[2][NMT];
#pragma unroll
  for (int rt = 0; rt < 2; ++rt)
#pragma unroll
    for (int mt = 0; mt < NMT; ++mt) acc[rt][mt] = f32x4{0.f, 0.f, 0.f, 0.f};

#pragma unroll
  for (int mt = 0; mt < NMT; ++mt) {
    short8v bf[NKC];
#pragma unroll
    for (int kc = 0; kc < NKC; ++kc)
      bf[kc] = *(const short8v*)&WfL[(size_t)((mt * NKC + kc) * 64 + lane) * 8];
#pragma unroll
    for (int rt = 0; rt < 2; ++rt)
#pragma unroll
      for (int kc = 0; kc < NKC; ++kc)
        acc[rt][mt] = __builtin_amdgcn_mfma_f32_16x16x32_bf16(af[rt][kc], bf[kc], acc[rt][mt], 0, 0, 0);
  }

  // ---- C write, C/D layout: col=lane&15, row=(lane>>4)*4+i ----
#pragma unroll
  for (int rt = 0; rt < 2; ++rt)
#pragma unroll
    for (int mt = 0; mt < NMT; ++mt) {
#pragma unroll
      for (int i = 0; i < 4; ++i) {
        int grow = row0 + wvi * 32 + rt * 16 + lkg * 4 + i;
        if (grow < N) {
          if (OUTF32) ((float*)Cout)[(size_t)grow * M + mt * 16 + lrow] = acc[rt][mt][i];
          else        ((ushort*)Cout)[(size_t)grow * M + mt * 16 + lrow] = f2bf(acc[rt][mt][i]);
        }
      }
    }

  if (FSTAT) {
#pragma unroll
    for (int mt = 0; mt < NMT; ++mt) {
      float s = 0.f, q = 0.f;
#pragma unroll
      for (int rt = 0; rt < 2; ++rt)
#pragma unroll
        for (int i = 0; i < 4; ++i) {
          int grow = row0 + wvi * 32 + rt * 16 + lkg * 4 + i;
          if (grow < N) { float v = acc[rt][mt][i]; s += v; q += v * v; }
        }
      s += __shfl_xor(s, 16); s += __shfl_xor(s, 32);
      q += __shfl_xor(q, 16); q += __shfl_xor(q, 32);
      if (lkg == 0) {
        atomicAdd(&redS[mt * 16 + lrow], s);
        atomicAdd(&redQ[mt * 16 + lrow], q);
      }
    }
    __syncthreads();
    if (tid < M) {
      atomicAdd(&oStat[tid], redS[tid]);
      atomicAdd(&oStat[128 + tid], redQ[tid]);
    }
  }
}

// ---------------- fused GRU step with H-BN folded into A-staging ----------------
// hnext = GRU( relu(bn(Hraw_t)), hprev )
__global__ __launch_bounds__(256)
void gruf_k(const ushort* __restrict__ Hraw, const ushort* __restrict__ hprev,
            const ushort* __restrict__ Wihf, const ushort* __restrict__ Whhf,
            const float* __restrict__ hst, const float* __restrict__ gp,
            const float* __restrict__ bep,
            const float* __restrict__ bih, const float* __restrict__ bhh,
            ushort* __restrict__ hnext, int N) {
  __shared__ float bihL[192], bhhL[192], scL[64], shL[64];
  const int tid = threadIdx.x;
  if (tid < 192) { bihL[tid] = bih[tid]; bhhL[tid] = bhh[tid]; }
  if (tid < 64) {
    float invN = 1.f / (float)N;
    float mn = hst[tid] * invN;
    float vr = fmaxf(hst[128 + tid] * invN - mn * mn, 0.f);
    float s = gp[tid] * rsqrtf(vr + BN_EPS);
    scL[tid] = s;
    shL[tid] = bep[tid] - mn * s;
  }
  __syncthreads();  // scL/shL + biases visible before staging
  const int wvi = tid >> 6, lane = tid & 63;
  const int lrow = lane & 15, lkg = lane >> 4;
  const int row0 = blockIdx.x * 128;
  const short8v zv = short8v{0, 0, 0, 0, 0, 0, 0, 0};
  for (int rt = 0; rt < 2; ++rt) {
    int arow = row0 + wvi * 32 + rt * 16 + lrow;
    bool aok = arow < N;
    short8v afA[2], afB[2];
#pragma unroll
    for (int kc = 0; kc < 2; ++kc) {
      short8v raw = aok ? *(const short8v*)&Hraw[(size_t)arow * 64 + kc * 32 + lkg * 8] : zv;
      short8v a;
#pragma unroll
      for (int j = 0; j < 8; ++j) {
        int k = kc * 32 + lkg * 8 + j;
        float v = fmaxf(fmaf(bf2f((ushort)raw[j]), scL[k], shL[k]), 0.f);
        a[j] = (short)f2bf(v);
      }
      afA[kc] = a;
      afB[kc] = aok ? *(const short8v*)&hprev[(size_t)arow * 64 + kc * 32 + lkg * 8] : zv;
    }
    f32x4 gacc[12], hacc[12];
#pragma unroll
    for (int mt = 0; mt < 12; ++mt) {
      gacc[mt] = f32x4{0.f, 0.f, 0.f, 0.f};
      hacc[mt] = f32x4{0.f, 0.f, 0.f, 0.f};
#pragma unroll
      for (int kc = 0; kc < 2; ++kc) {
        short8v bwi = *(const short8v*)&Wihf[(size_t)((mt * 2 + kc) * 64 + lane) * 8];
        short8v bwh = *(const short8v*)&Whhf[(size_t)((mt * 2 + kc) * 64 + lane) * 8];
        gacc[mt] = __builtin_amdgcn_mfma_f32_16x16x32_bf16(afA[kc], bwi, gacc[mt], 0, 0, 0);
        hacc[mt] = __builtin_amdgcn_mfma_f32_16x16x32_bf16(afB[kc], bwh, hacc[mt], 0, 0, 0);
      }
    }
#pragma unroll
    for (int i = 0; i < 4; ++i) {
      int grow = row0 + wvi * 32 + rt * 16 + lkg * 4 + i;
      if (grow < N) {
        const ushort* hpp = hprev + (size_t)grow * 64;
#pragma unroll
        for (int mtj = 0; mtj < 4; ++mtj) {
          int j = mtj * 16 + lrow;
          float ir = gacc[mtj][i] + bihL[j];
          float iz = gacc[mtj + 4][i] + bihL[64 + j];
          float ig = gacc[mtj + 8][i] + bihL[128 + j];
          float hr = hacc[mtj][i] + bhhL[j];
          float hz = hacc[mtj + 4][i] + bhhL[64 + j];
          float hg = hacc[mtj + 8][i] + bhhL[128 + j];
          float r = 1.f / (1.f + expf(-(ir + hr)));
          float z = 1.f / (1.f + expf(-(iz + hz)));
          float ng = tanhf(ig + r * hg);
          float hn = (1.f - z) * ng + z * bf2f(hpp[j]);
          hnext[(size_t)grow * 64 + j] = f2bf(hn);
        }
      }
    }
  }
}

// ---------------- batched graph prep (t = blockIdx.x & 7) ----------------
__global__ void hist_k(const int* __restrict__ dst, int* __restrict__ cnt, ushort* __restrict__ rank,
                       int N, int E) {
  int t = blockIdx.x & 7;
  int e = (blockIdx.x >> 3) * 256 + threadIdx.x;
  if (e >= E) return;
  size_t i = (size_t)t * E + e;
  rank[i] = (ushort)atomicAdd(&cnt[t * N + dst[i]], 1);
}
__global__ __launch_bounds__(256) void scan1_k(const int* __restrict__ in, int* __restrict__ incl,
                                               int* __restrict__ bsum, int n) {
  int t = blockIdx.y;
  const int* inp = in + (size_t)t * n;
  int* ip = incl + (size_t)t * n;
  int i = blockIdx.x * 256 + threadIdx.x;
  int v = (i < n) ? inp[i] : 0;
  int lane = threadIdx.x & 63;
  int sidx = threadIdx.x >> 6;
  int sv = v;
  for (int off = 1; off < 64; off <<= 1) {
    int tt = __shfl_up(sv, off, 64);
    if (lane >= off) sv += tt;
  }
  __shared__ int wsum[4];
  if (lane == 63) wsum[sidx] = sv;
  __syncthreads();
  int add = 0;
  for (int w = 0; w < sidx; ++w) add += wsum[w];
  sv += add;
  if (i < n) ip[i] = sv;
  if (threadIdx.x == 255) bsum[t * 256 + blockIdx.x] = sv;
}
__global__ __launch_bounds__(256) void scan2_k(int* __restrict__ bsum, int nb) {
  int t = blockIdx.y;
  int* bp = bsum + t * 256;
  int i = threadIdx.x;
  int v = (i < nb) ? bp[i] : 0;
  int lane = threadIdx.x & 63;
  int sidx = threadIdx.x >> 6;
  int sv = v;
  for (int off = 1; off < 64; off <<= 1) {
    int tt = __shfl_up(sv, off, 64);
    if (lane >= off) sv += tt;
  }
  __shared__ int wsum[4];
  if (lane == 63) wsum[sidx] = sv;
  __syncthreads();
  int add = 0;
  for (int w = 0; w < sidx; ++w) add += wsum[w];
  sv += add;
  if (i < nb) bp[i] = sv;
}
__global__ void scan3_k(const int* __restrict__ incl, const int* __restrict__ cnt,
                        const int* __restrict__ bsum, int* __restrict__ rowptr, int n, int E) {
  int t = blockIdx.y;
  int i = blockIdx.x * 256 + threadIdx.x;
  int* rp = rowptr + (size_t)t * (n + 1);
  if (i < n) {
    int v = incl[(size_t)t * n + i] - cnt[(size_t)t * n + i] +
            (blockIdx.x ? bsum[t * 256 + blockIdx.x - 1] : 0);
    rp[i] = v;
  }
  if (i == 0) rp[n] = E;
}
__global__ void scat_k(const int* __restrict__ src, const int* __restrict__ dst,
                       const float* __restrict__ w, const ushort* __restrict__ rank,
                       const int* __restrict__ rowptr, int2* __restrict__ epk,
                       int N1, int E) {
  int t = blockIdx.x & 7;
  int e = (blockIdx.x >> 3) * 256 + threadIdx.x;
  if (e >= E) return;
  size_t i = (size_t)t * E + e;
  int slot = rowptr[(size_t)t * N1 + dst[i]] + (int)rank[i];
  epk[(size_t)t * E + slot] = make_int2(src[i], __float_as_int(w[i]));
}
__global__ void deg_k(const int2* __restrict__ epk, const int* __restrict__ rowptr,
                      float* __restrict__ dinv, int N, int N1, int E) {
  int t = blockIdx.x & 7;
  int n = (blockIdx.x >> 3) * 256 + threadIdx.x;
  if (n >= N) return;
  const int* rp = rowptr + (size_t)t * N1;
  const int2* ep = epk + (size_t)t * E;
  float s = 1.f;  // self loop
  int b = rp[n], e = rp[n + 1];
  for (int j = b; j < e; ++j) s += __int_as_float(ep[j].y);
  dinv[(size_t)t * N + n] = rsqrtf(s);
}
__global__ void norm_k(int2* __restrict__ epk, const int* __restrict__ rowptr,
                       const float* __restrict__ dinv, int N, int N1, int E) {
  int t = blockIdx.x & 7;
  int n = (blockIdx.x >> 3) * 256 + threadIdx.x;
  if (n >= N) return;
  const int* rp = rowptr + (size_t)t * N1;
  const float* dv = dinv + (size_t)t * N;
  int2* ep = epk + (size_t)t * E;
  float dn = dv[n];
  int b = rp[n], e = rp[n + 1];
  for (int j = b; j < e; ++j) {
    int2 ed = ep[j];
    ep[j].y = __float_as_int(dv[ed.x] * __int_as_float(ed.y) * dn);
  }
}

// ---------------- GCN aggregation (wave-coherent, 8-edge unroll, bf16 out) ----------------
__global__ __launch_bounds__(256) void agg_k(const ushort* __restrict__ xw, const float* __restrict__ dinv,
                                             const int* __restrict__ rowptr, const int2* __restrict__ epk,
                                             ushort* __restrict__ ag, float* __restrict__ oStat, int N) {
  __shared__ float redS[64], redQ[64];
  if (threadIdx.x < 64) { redS[threadIdx.x] = 0.f; redQ[threadIdx.x] = 0.f; }
  __syncthreads();
  int f = threadIdx.x & 63;
  int wvl = threadIdx.x >> 6;
  int stride = gridDim.x * 4;
  float s = 0.f, q = 0.f;
  for (int n = blockIdx.x * 4 + wvl; n < N; n += stride) {
    float di = dinv[n];
    float acc0 = bf2f(xw[(size_t)n * 64 + f]) * di * di;  // self loop
    float acc1 = 0.f;
    int b = rowptr[n], e = rowptr[n + 1];
    int j = b;
    if ((j & 1) && j < e) {   // align to 16B for int4 loads
      int2 e0 = epk[j];
      acc1 += bf2f(xw[(size_t)e0.x * 64 + f]) * __int_as_float(e0.y);
      ++j;
    }
    for (; j + 7 < e; j += 8) {
      int4 p01 = *(const int4*)&epk[j];
      int4 p23 = *(const int4*)&epk[j + 2];
      int4 p45 = *(const int4*)&epk[j + 4];
      int4 p67 = *(const int4*)&epk[j + 6];
      acc0 += bf2f(xw[(size_t)p01.x * 64 + f]) * __int_as_float(p01.y);
      acc1 += bf2f(xw[(size_t)p01.z * 64 + f]) * __int_as_float(p01.w);
      acc0 += bf2f(xw[(size_t)p23.x * 64 + f]) * __int_as_float(p23.y);
      acc1 += bf2f(xw[(size_t)p23.z * 64 + f]) * __int_as_float(p23.w);
      acc0 += bf2f(xw[(size_t)p45.x * 64 + f]) * __int_as_float(p45.y);
      acc1 += bf2f(xw[(size_t)p45.z * 64 + f]) * __int_as_float(p45.w);
      acc0 += bf2f(xw[(size_t)p67.x * 64 + f]) * __int_as_float(p67.y);
      acc1 += bf2f(xw[(size_t)p67.z * 64 + f]) * __int_as_float(p67.w);
    }
    for (; j + 1 < e; j += 2) {
      int4 p01 = *(const int4*)&epk[j];
      acc0 += bf2f(xw[(size_t)p01.x * 64 + f]) * __int_as_float(p01.y);
      acc1 += bf2f(xw[(size_t)p01.z * 64 + f]) * __int_as_float(p01.w);
    }
    if (j < e) {
      int2 e0 = epk[j];
      acc0 += bf2f(xw[(size_t)e0.x * 64 + f]) * __int_as_float(e0.y);
    }
    float acc = acc0 + acc1;
    ag[(size_t)n * 64 + f] = f2bf(acc);
    s += acc;
    q += acc * acc;
  }
  atomicAdd(&redS[f], s);
  atomicAdd(&redQ[f], q);
  __syncthreads();
  if (threadIdx.x < 64) {
    atomicAdd(&oStat[threadIdx.x], redS[threadIdx.x]);
    atomicAdd(&oStat[128 + threadIdx.x], redQ[threadIdx.x]);
  }
}

// ---------------- classifier final: BN+ReLU(u fp32) @ Wc2 + bc2 ----------------
__global__ __launch_bounds__(256) void final_k(const float* __restrict__ u, const float* __restrict__ st,
                                               const float* __restrict__ g, const float* __restrict__ be,
                                               const float* __restrict__ Wc2, const float* __restrict__ bc2,
                                               float* __restrict__ out, int N) {
  __shared__ float Wl[512], sc[128], sh[128];
  for (int i = threadIdx.x; i < 512; i += 256) Wl[i] = Wc2[i];
  if (threadIdx.x < 128) {
    int c = threadIdx.x;
    float invN = 1.f / (float)N;
    float mn = st[c] * invN;
    float vr = fmaxf(st[128 + c] * invN - mn * mn, 0.f);
    float s = g[c] * rsqrtf(vr + BN_EPS);
    sc[c] = s;
    sh[c] = be[c] - mn * s;
  }
  __syncthreads();
  int idx = blockIdx.x * 256 + threadIdx.x;
  if (idx >= N * 4) return;
  int n = idx >> 2, c = idx & 3;
  const float* ur = u + (size_t)n * 128;
  float acc = bc2[c];
#pragma unroll 8
  for (int k = 0; k < 128; ++k) {
    float v = fmaxf(fmaf(ur[k], sc[k], sh[k]), 0.f);
    acc = fmaf(v, Wl[k * 4 + c], acc);
  }
  out[idx] = acc;
}

extern "C" void kernel_launch(void* const* d_in, const int* in_sizes, int n_in,
                              void* d_out, int out_size, void* d_ws, size_t ws_size,
                              hipStream_t stream) {
  const float* xs   = (const float*)d_in[0];
  const int*   esrc = (const int*)d_in[1];
  const int*   edst = (const int*)d_in[2];
  const float* ew   = (const float*)d_in[3];
  const float* W1   = (const float*)d_in[4];
  const float* g1   = (const float*)d_in[6];
  const float* be1  = (const float*)d_in[7];
  const float* W2   = (const float*)d_in[8];
  const float* g2   = (const float*)d_in[10];
  const float* be2  = (const float*)d_in[11];
  const float* gW   = (const float*)d_in[12];
  const float* gg   = (const float*)d_in[14];
  const float* gbe  = (const float*)d_in[15];
  const float* Wp   = (const float*)d_in[16];
  const float* gp   = (const float*)d_in[18];
  const float* bep  = (const float*)d_in[19];
  const float* Wih  = (const float*)d_in[20];
  const float* Whh  = (const float*)d_in[21];
  const float* bih  = (const float*)d_in[22];
  const float* bhh  = (const float*)d_in[23];
  const float* Wc1  = (const float*)d_in[24];
  const float* gc   = (const float*)d_in[26];
  const float* bec  = (const float*)d_in[27];
  const float* Wc2  = (const float*)d_in[28];
  const float* bc2  = (const float*)d_in[29];
  float* out = (float*)d_out;

  const int T = 8;
  const int N = in_sizes[0] / (T * 32);
  const int E = in_sizes[1] / T;
  const int TE = T * E, TN = T * N, N1 = N + 1;

  // ---- workspace layout (bytes) ----
  size_t off = 0;
  auto alloc = [&](size_t bytes) { size_t o = off; off += (bytes + 255) & ~(size_t)255; return o; };
  char* base = (char*)d_ws;
  size_t oH      = alloc((size_t)T * N * 64 * 2);   // Hraw bf16 (pre-BN post-MLP raws)
  size_t oEpk    = alloc((size_t)TE * 8);           // packed (src, w/norm)
  size_t oRp     = alloc((size_t)T * N1 * 4);       // rowptr
  size_t oDinv   = alloc((size_t)TN * 4);           // dinv
  size_t oStats  = alloc((size_t)49 * 256 * 4);     // stats slots
  size_t oBsum   = alloc((size_t)T * 256 * 4);      // scan block sums
  size_t oWf     = alloc((size_t)70000 * 2);        // prebuilt weight fragments
  size_t oArena  = alloc((size_t)64 * 1024 * 1024); // phase-shared arena
  if (ws_size < off) return;

  ushort* Hraw  = (ushort*)(base + oH);
  int2*   epk   = (int2*)(base + oEpk);
  int*    rowptr= (int*)(base + oRp);
  float*  dinv  = (float*)(base + oDinv);
  float*  statsA= (float*)(base + oStats);
  int*    bsum  = (int*)(base + oBsum);
  ushort* wfA   = (ushort*)(base + oWf);
  char*   arena = base + oArena;

  // weight fragment offsets (ushort elements)
  ushort* W1f  = wfA;               // 32*128  = 4096
  ushort* W2f  = W1f + 4096;        // 128*64  = 8192
  ushort* gW0f = W2f + 8192;        // 64*64   = 4096
  ushort* gW1f = gW0f + 4096;
  ushort* gW2f = gW1f + 4096;
  ushort* Wpf  = gW2f + 4096;       // 64*64
  ushort* Wihf = Wpf + 4096;        // 64*192  = 12288
  ushort* Whhf = Wihf + 12288;
  ushort* Wc1f = Whhf + 12288;      // 64*128  = 8192  (total 61440)

  // prep-phase arena views
  int*    cnt  = (int*)arena;                      // [T*N]
  int*    incl = cnt + TN;                         // [T*N]
  ushort* rank = (ushort*)(incl + TN);             // [T*E] ushort
  // encoder-phase arena views (all bf16 now; stats stay exact fp32)
  ushort* y1b   = (ushort*)arena;                  // [N,128] bf16 raw
  ushort* hbraw = y1b + (size_t)N * 128;           // [N,64]  bf16 raw
  ushort* hcur  = hbraw + (size_t)N * 64;          // [N,64]  bf16 normalized
  ushort* xwb   = hcur + (size_t)N * 64;           // [N,64]  bf16 gather table
  ushort* agb   = xwb + (size_t)N * 64;            // [N,64]  bf16 raw agg
  // gru/cls-phase arena views
  ushort* hA = (ushort*)(arena + (size_t)40 * 1024 * 1024);  // [N,64]
  ushort* hB = hA + (size_t)N * 64;
  float*  uf = (float*)arena;                      // [N,128] fp32 ([0,25.6MB))

  const int nb = CDIV(N, 256);

#define SLOT(t, j) (statsA + ((size_t)(t) * 6 + (j)) * 256)

  hipMemsetAsync(statsA, 0, (size_t)49 * 256 * 4, stream);
  hipMemsetAsync(cnt, 0, (size_t)TN * 4, stream);

  // ---- weight fragment prep ----
  wprep_k<32, 128, false><<<1, 256, 0, stream>>>(W1, W1f);
  wprep_k<128, 64, false><<<1, 256, 0, stream>>>(W2, W2f);
  wprep_k<64, 64, false><<<1, 256, 0, stream>>>(gW, gW0f);
  wprep_k<64, 64, false><<<1, 256, 0, stream>>>(gW + 4096, gW1f);
  wprep_k<64, 64, false><<<1, 256, 0, stream>>>(gW + 8192, gW2f);
  wprep_k<64, 64, false><<<1, 256, 0, stream>>>(Wp, Wpf);
  wprep_k<64, 192, true><<<1, 256, 0, stream>>>(Wih, Wihf);
  wprep_k<64, 192, true><<<1, 256, 0, stream>>>(Whh, Whhf);

  // ================= batched graph prep (all T, XCD-partitioned) =================
  const int nbe = CDIV(E, 256);
  hist_k<<<8 * nbe, 256, 0, stream>>>(edst, cnt, rank, N, E);
  scan1_k<<<dim3(nb, T), 256, 0, stream>>>(cnt, incl, bsum, N);
  scan2_k<<<dim3(1, T), 256, 0, stream>>>(bsum, nb);
  scan3_k<<<dim3(nb, T), 256, 0, stream>>>(incl, cnt, bsum, rowptr, N, E);
  scat_k<<<8 * nbe, 256, 0, stream>>>(esrc, edst, ew, rank, rowptr, epk, N1, E);
  deg_k<<<8 * nb, 256, 0, stream>>>(epk, rowptr, dinv, N, N1, E);
  norm_k<<<8 * nb, 256, 0, stream>>>(epk, rowptr, dinv, N, N1, E);
  wprep_k<64, 128, false><<<1, 256, 0, stream>>>(Wc1, Wc1f);

  const int gemmGrid = CDIV(N, 128);
  const void*  nv  = nullptr;
  const float* ncf = nullptr;
  float* nmf = nullptr;
  ushort* nus = nullptr;

  // ================= encoder over T timesteps =================
  for (int t = 0; t < T; ++t) {
    const float* xt = xs + (size_t)t * N * 32;
    const int* rpT = rowptr + (size_t)t * N1;
    const int2* epkT = epk + (size_t)t * E;
    const float* dinvT = dinv + (size_t)t * N;

    // MLP1: y1b(bf16 raw) = xt @ W1, stats0 (exact fp32 acc)
    gemm2<32, 128, 1, false, true, false, false><<<gemmGrid, 256, 0, stream>>>(
        xt, nv, W1f, y1b, nus, ncf, ncf, ncf, SLOT(t, 0), N);
    // MLP2: hbraw(bf16 raw) = BNReLU(y1b) @ W2, stats1
    gemm2<128, 64, 2, true, true, false, false><<<gemmGrid, 256, 0, stream>>>(
        y1b, nv, W2f, hbraw, nus, SLOT(t, 0), g1, be1, SLOT(t, 1), N);
    // GCN0: A = BNReLU(hbraw) [-> side hcur], out xwb bf16
    gemm2<64, 64, 2, true, false, false, true><<<gemmGrid, 256, 0, stream>>>(
        hbraw, nv, gW0f, xwb, hcur, SLOT(t, 1), g2, be2, nmf, N);
    agg_k<<<2048, 256, 0, stream>>>(xwb, dinvT, rpT, epkT, agb, SLOT(t, 2), N);
    // GCN1: A = hcur + ReLU(BN(agb)) [-> side hcur], out xwb
    gemm2<64, 64, 3, true, false, false, true><<<gemmGrid, 256, 0, stream>>>(
        hcur, agb, gW1f, xwb, hcur, SLOT(t, 2), gg, gbe, nmf, N);
    agg_k<<<2048, 256, 0, stream>>>(xwb, dinvT, rpT, epkT, agb, SLOT(t, 3), N);
    // GCN2
    gemm2<64, 64, 3, true, false, false, true><<<gemmGrid, 256, 0, stream>>>(
        hcur, agb, gW2f, xwb, hcur, SLOT(t, 3), gg + 64, gbe + 64, nmf, N);
    agg_k<<<2048, 256, 0, stream>>>(xwb, dinvT, rpT, epkT, agb, SLOT(t, 4), N);
    // POST: A = hcur + ReLU(BN(agb)), raw out -> Hraw[t] (bf16) + stats5
    gemm2<64, 64, 3, true, true, false, false><<<gemmGrid, 256, 0, stream>>>(
        hcur, agb, Wpf, Hraw + (size_t)t * N * 64, nus, SLOT(t, 4), gg + 128, gbe + 128, SLOT(t, 5), N);
  }

  // ================= GRU over T steps (fused BN + dual-GEMM + gate) =================
  hipMemsetAsync(hA, 0, (size_t)N * 64 * 2, stream);
  ushort* hprev = hA;
  ushort* hnext = hB;
  for (int t = 0; t < T; ++t) {
    gruf_k<<<gemmGrid, 256, 0, stream>>>(Hraw + (size_t)t * N * 64, hprev, Wihf, Whhf,
                                         SLOT(t, 5), gp, bep, bih, bhh, hnext, N);
    ushort* tmp = hprev; hprev = hnext; hnext = tmp;
  }
  // after 8 steps hprev == hA (arena+40MB; uf occupies [0,25.6MB) - no overlap)

  // ================= classifier =================
  gemm2<64, 128, 0, false, true, true, false><<<gemmGrid, 256, 0, stream>>>(
      hprev, nv, Wc1f, uf, nus, ncf, ncf, ncf, statsA + 48 * 256, N);
  final_k<<<CDIV(N * 4, 256), 256, 0, stream>>>(uf, statsA + 48 * 256, gc, bec, Wc2, bc2, out, N);
}

// Round 12
// 2657.661 us; speedup vs baseline: 1.7334x; 1.2790x over previous
//
#include <hip/hip_runtime.h>
#include <hip/hip_bf16.h>
#include <cstddef>

#define CDIV(a,b) (((a)+(b)-1)/(b))

static constexpr float BN_EPS = 1e-5f;

typedef __attribute__((ext_vector_type(8))) short short8v;   // 8 bf16 (4 VGPRs)
typedef __attribute__((ext_vector_type(4))) float f32x4;

__device__ inline ushort f2bf(float x) {
  unsigned u = __float_as_uint(x);
  unsigned r = (u + 0x7fffu + ((u >> 16) & 1u)) >> 16;
  return (ushort)r;
}
__device__ inline float bf2f(ushort h) {
  return __uint_as_float(((unsigned)h) << 16);
}

// ---------------- weight fragment prep (once per launch) ----------------
template<int K, int M, bool TRANSW>
__global__ void wprep_k(const float* __restrict__ W, ushort* __restrict__ Wf) {
  constexpr int NKC = K / 32;
  for (int i = threadIdx.x; i < K * M; i += 256) {
    int k, m;
    if (TRANSW) { m = i / K; k = i - m * K; }
    else        { k = i / M; m = i - k * M; }
    float wv = W[i];
    int mt = m >> 4, ml = m & 15, kc = k >> 5, kr = k & 31;
    int lane = ((kr >> 3) << 4) | ml;
    int j = kr & 7;
    Wf[(size_t)((mt * NKC + kc) * 64 + lane) * 8 + j] = f2bf(wv);
  }
}

// =====================================================================
// bf16 MFMA GEMM v4 — T-batched via blockIdx.y (independent timesteps).
// Per-ty advances: Ain/A2/Cout/side by compile-time strides; stats by 1536.
// AMODE: 0 = A bf16; 1 = A fp32; 2 = ReLU(BN(raw Ain)); 3 = Ain(bf16)+ReLU(BN(raw A2))
// RAW16: raw source is bf16 (else fp32). Stats from exact fp32 accumulators.
// NOTE: bnSc/bnSh produced by thread subset -> __syncthreads() after is REQUIRED.
// =====================================================================
template<int K, int M, int AMODE, bool RAW16, bool FSTAT, bool OUTF32, bool SIDE>
__global__ __launch_bounds__(256)
void gemm2(const void* __restrict__ Ain, const void* __restrict__ A2,
           const ushort* __restrict__ Wf, void* __restrict__ Cout,
           ushort* __restrict__ side,
           const float* __restrict__ aStat, const float* __restrict__ aG,
           const float* __restrict__ aB, float* __restrict__ oStat, int N) {
  constexpr int BM = 128;
  constexpr int NKC = K / 32;
  constexpr int NMT = M / 16;
  constexpr bool BN = (AMODE >= 2);
  constexpr int ABYTES = (AMODE == 1) ? 4 : ((AMODE == 2 && !RAW16) ? 4 : 2);
  __shared__ __align__(16) ushort As[BM * K];
  __shared__ __align__(16) ushort WfL[M * K];
  __shared__ float bnSc[BN ? K : 1];
  __shared__ float bnSh[BN ? K : 1];
  __shared__ float redS[FSTAT ? M : 1];
  __shared__ float redQ[FSTAT ? M : 1];
  const int tid = threadIdx.x;
  const int row0 = blockIdx.x * BM;
  const int ty = blockIdx.y;

  const char* AinB = (const char*)Ain + (size_t)ty * N * K * ABYTES;
  const char* A2B  = (AMODE == 3) ? ((const char*)A2 + (size_t)ty * N * K * (RAW16 ? 2 : 4)) : nullptr;
  char* CoutB = (char*)Cout + (size_t)ty * N * M * (OUTF32 ? 4 : 2);
  ushort* sideB = SIDE ? (side + (size_t)ty * N * K) : nullptr;
  if (BN) aStat += (size_t)ty * 1536;
  if (FSTAT) oStat += (size_t)ty * 1536;

  for (int i = tid; i < K * M / 8; i += 256)
    ((short8v*)WfL)[i] = ((const short8v*)Wf)[i];
  if (BN) {
    float invN = 1.f / (float)N;
    for (int i = tid; i < K; i += 256) {
      float mn = aStat[i] * invN;
      float vr = fmaxf(aStat[128 + i] * invN - mn * mn, 0.f);
      float sc = aG[i] * rsqrtf(vr + BN_EPS);
      bnSc[i] = sc;
      bnSh[i] = aB[i] - mn * sc;
    }
    __syncthreads();  // bnSc/bnSh visible to all threads before A-staging
  }
  if (FSTAT) {
    if (tid < M) { redS[tid] = 0.f; redQ[tid] = 0.f; }
  }

  // ---- A -> XOR-swizzled bf16 LDS ----
  {
    const float*  Af  = (const float*)AinB;
    const ushort* Ab  = (const ushort*)AinB;
    const float*  A2f = (const float*)A2B;
    const ushort* A2b = (const ushort*)A2B;
    for (int i = tid; i < BM * K / 4; i += 256) {
      int row = (i * 4) / K, k0 = (i * 4) % K;
      int grow = row0 + row;
      ushort h4[4] = {0, 0, 0, 0};
      if (AMODE == 0) {
        if (grow < N) *(ushort4*)h4 = *(const ushort4*)&Ab[(size_t)grow * K + k0];
      } else if (AMODE == 1) {
        float vv[4] = {0.f, 0.f, 0.f, 0.f};
        if (grow < N) *(float4*)vv = *(const float4*)&Af[(size_t)grow * K + k0];
#pragma unroll
        for (int c = 0; c < 4; ++c) h4[c] = f2bf(vv[c]);
      } else {
        if (grow < N) {
          float rw[4];
          if (AMODE == 2) {
            if (RAW16) {
              ushort t4[4];
              *(ushort4*)t4 = *(const ushort4*)&Ab[(size_t)grow * K + k0];
#pragma unroll
              for (int c = 0; c < 4; ++c) rw[c] = bf2f(t4[c]);
            } else {
              *(float4*)rw = *(const float4*)&Af[(size_t)grow * K + k0];
            }
          } else {
            if (RAW16) {
              ushort t4[4];
              *(ushort4*)t4 = *(const ushort4*)&A2b[(size_t)grow * K + k0];
#pragma unroll
              for (int c = 0; c < 4; ++c) rw[c] = bf2f(t4[c]);
            } else {
              *(float4*)rw = *(const float4*)&A2f[(size_t)grow * K + k0];
            }
          }
          ushort b4[4];
          if (AMODE == 3) *(ushort4*)b4 = *(const ushort4*)&Ab[(size_t)grow * K + k0];
#pragma unroll
          for (int c = 0; c < 4; ++c) {
            float v = fmaxf(fmaf(rw[c], bnSc[k0 + c], bnSh[k0 + c]), 0.f);
            float vv = (AMODE == 3) ? bf2f(b4[c]) + v : v;
            h4[c] = f2bf(vv);
          }
          if (SIDE) *(ushort4*)&sideB[(size_t)grow * K + k0] = *(ushort4*)h4;
        }
      }
      unsigned off = ((unsigned)(row * K + k0) * 2u) ^ (((unsigned)(row & 7)) << 4);
      *(ushort4*)((char*)As + off) = *(ushort4*)h4;
    }
  }
  __syncthreads();

  const int wvi = tid >> 6, lane = tid & 63;
  const int lrow = lane & 15, lkg = lane >> 4;

  short8v af[2][NKC];
#pragma unroll
  for (int rt = 0; rt < 2; ++rt)
#pragma unroll
    for (int kc = 0; kc < NKC; ++kc) {
      int row = wvi * 32 + rt * 16 + lrow;
      unsigned off = ((unsigned)(row * K + kc * 32 + lkg * 8) * 2u) ^ (((unsigned)(row & 7)) << 4);
      af[rt][kc] = *(const short8v*)((const char*)As + off);
    }

  f32x4 acc[2][NMT];
#pragma unroll
  for (int rt = 0; rt < 2; ++rt)
#pragma unroll
    for (int mt = 0; mt < NMT; ++mt) acc[rt][mt] = f32x4{0.f, 0.f, 0.f, 0.f};

#pragma unroll
  for (int mt = 0; mt < NMT; ++mt) {
    short8v bf[NKC];
#pragma unroll
    for (int kc = 0; kc < NKC; ++kc)
      bf[kc] = *(const short8v*)&WfL[(size_t)((mt * NKC + kc) * 64 + lane) * 8];
#pragma unroll
    for (int rt = 0; rt < 2; ++rt)
#pragma unroll
      for (int kc = 0; kc < NKC; ++kc)
        acc[rt][mt] = __builtin_amdgcn_mfma_f32_16x16x32_bf16(af[rt][kc], bf[kc], acc[rt][mt], 0, 0, 0);
  }

  // ---- C write, C/D layout: col=lane&15, row=(lane>>4)*4+i ----
#pragma unroll
  for (int rt = 0; rt < 2; ++rt)
#pragma unroll
    for (int mt = 0; mt < NMT; ++mt) {
#pragma unroll
      for (int i = 0; i < 4; ++i) {
        int grow = row0 + wvi * 32 + rt * 16 + lkg * 4 + i;
        if (grow < N) {
          if (OUTF32) ((float*)CoutB)[(size_t)grow * M + mt * 16 + lrow] = acc[rt][mt][i];
          else        ((ushort*)CoutB)[(size_t)grow * M + mt * 16 + lrow] = f2bf(acc[rt][mt][i]);
        }
      }
    }

  if (FSTAT) {
#pragma unroll
    for (int mt = 0; mt < NMT; ++mt) {
      float s = 0.f, q = 0.f;
#pragma unroll
      for (int rt = 0; rt < 2; ++rt)
#pragma unroll
        for (int i = 0; i < 4; ++i) {
          int grow = row0 + wvi * 32 + rt * 16 + lkg * 4 + i;
          if (grow < N) { float v = acc[rt][mt][i]; s += v; q += v * v; }
        }
      s += __shfl_xor(s, 16); s += __shfl_xor(s, 32);
      q += __shfl_xor(q, 16); q += __shfl_xor(q, 32);
      if (lkg == 0) {
        atomicAdd(&redS[mt * 16 + lrow], s);
        atomicAdd(&redQ[mt * 16 + lrow], q);
      }
    }
    __syncthreads();
    if (tid < M) {
      atomicAdd(&oStat[tid], redS[tid]);
      atomicAdd(&oStat[128 + tid], redQ[tid]);
    }
  }
}

// ---------------- fused GRU step with H-BN folded into A-staging ----------------
__global__ __launch_bounds__(256)
void gruf_k(const ushort* __restrict__ Hraw, const ushort* __restrict__ hprev,
            const ushort* __restrict__ Wihf, const ushort* __restrict__ Whhf,
            const float* __restrict__ hst, const float* __restrict__ gp,
            const float* __restrict__ bep,
            const float* __restrict__ bih, const float* __restrict__ bhh,
            ushort* __restrict__ hnext, int N) {
  __shared__ float bihL[192], bhhL[192], scL[64], shL[64];
  const int tid = threadIdx.x;
  if (tid < 192) { bihL[tid] = bih[tid]; bhhL[tid] = bhh[tid]; }
  if (tid < 64) {
    float invN = 1.f / (float)N;
    float mn = hst[tid] * invN;
    float vr = fmaxf(hst[128 + tid] * invN - mn * mn, 0.f);
    float s = gp[tid] * rsqrtf(vr + BN_EPS);
    scL[tid] = s;
    shL[tid] = bep[tid] - mn * s;
  }
  __syncthreads();
  const int wvi = tid >> 6, lane = tid & 63;
  const int lrow = lane & 15, lkg = lane >> 4;
  const int row0 = blockIdx.x * 128;
  const short8v zv = short8v{0, 0, 0, 0, 0, 0, 0, 0};
  for (int rt = 0; rt < 2; ++rt) {
    int arow = row0 + wvi * 32 + rt * 16 + lrow;
    bool aok = arow < N;
    short8v afA[2], afB[2];
#pragma unroll
    for (int kc = 0; kc < 2; ++kc) {
      short8v raw = aok ? *(const short8v*)&Hraw[(size_t)arow * 64 + kc * 32 + lkg * 8] : zv;
      short8v a;
#pragma unroll
      for (int j = 0; j < 8; ++j) {
        int k = kc * 32 + lkg * 8 + j;
        float v = fmaxf(fmaf(bf2f((ushort)raw[j]), scL[k], shL[k]), 0.f);
        a[j] = (short)f2bf(v);
      }
      afA[kc] = a;
      afB[kc] = aok ? *(const short8v*)&hprev[(size_t)arow * 64 + kc * 32 + lkg * 8] : zv;
    }
    f32x4 gacc[12], hacc[12];
#pragma unroll
    for (int mt = 0; mt < 12; ++mt) {
      gacc[mt] = f32x4{0.f, 0.f, 0.f, 0.f};
      hacc[mt] = f32x4{0.f, 0.f, 0.f, 0.f};
#pragma unroll
      for (int kc = 0; kc < 2; ++kc) {
        short8v bwi = *(const short8v*)&Wihf[(size_t)((mt * 2 + kc) * 64 + lane) * 8];
        short8v bwh = *(const short8v*)&Whhf[(size_t)((mt * 2 + kc) * 64 + lane) * 8];
        gacc[mt] = __builtin_amdgcn_mfma_f32_16x16x32_bf16(afA[kc], bwi, gacc[mt], 0, 0, 0);
        hacc[mt] = __builtin_amdgcn_mfma_f32_16x16x32_bf16(afB[kc], bwh, hacc[mt], 0, 0, 0);
      }
    }
#pragma unroll
    for (int i = 0; i < 4; ++i) {
      int grow = row0 + wvi * 32 + rt * 16 + lkg * 4 + i;
      if (grow < N) {
        const ushort* hpp = hprev + (size_t)grow * 64;
#pragma unroll
        for (int mtj = 0; mtj < 4; ++mtj) {
          int j = mtj * 16 + lrow;
          float ir = gacc[mtj][i] + bihL[j];
          float iz = gacc[mtj + 4][i] + bihL[64 + j];
          float ig = gacc[mtj + 8][i] + bihL[128 + j];
          float hr = hacc[mtj][i] + bhhL[j];
          float hz = hacc[mtj + 4][i] + bhhL[64 + j];
          float hg = hacc[mtj + 8][i] + bhhL[128 + j];
          float r = 1.f / (1.f + expf(-(ir + hr)));
          float z = 1.f / (1.f + expf(-(iz + hz)));
          float ng = tanhf(ig + r * hg);
          float hn = (1.f - z) * ng + z * bf2f(hpp[j]);
          hnext[(size_t)grow * 64 + j] = f2bf(hn);
        }
      }
    }
  }
}

// ---------------- batched graph prep (t = blockIdx.x & 7) ----------------
__global__ void hist_k(const int* __restrict__ dst, int* __restrict__ cnt, ushort* __restrict__ rank,
                       int N, int E) {
  int t = blockIdx.x & 7;
  int e = (blockIdx.x >> 3) * 256 + threadIdx.x;
  if (e >= E) return;
  size_t i = (size_t)t * E + e;
  rank[i] = (ushort)atomicAdd(&cnt[t * N + dst[i]], 1);
}
__global__ __launch_bounds__(256) void scan1_k(const int* __restrict__ in, int* __restrict__ incl,
                                               int* __restrict__ bsum, int n) {
  int t = blockIdx.y;
  const int* inp = in + (size_t)t * n;
  int* ip = incl + (size_t)t * n;
  int i = blockIdx.x * 256 + threadIdx.x;
  int v = (i < n) ? inp[i] : 0;
  int lane = threadIdx.x & 63;
  int sidx = threadIdx.x >> 6;
  int sv = v;
  for (int off = 1; off < 64; off <<= 1) {
    int tt = __shfl_up(sv, off, 64);
    if (lane >= off) sv += tt;
  }
  __shared__ int wsum[4];
  if (lane == 63) wsum[sidx] = sv;
  __syncthreads();
  int add = 0;
  for (int w = 0; w < sidx; ++w) add += wsum[w];
  sv += add;
  if (i < n) ip[i] = sv;
  if (threadIdx.x == 255) bsum[t * 256 + blockIdx.x] = sv;
}
__global__ __launch_bounds__(256) void scan2_k(int* __restrict__ bsum, int nb) {
  int t = blockIdx.y;
  int* bp = bsum + t * 256;
  int i = threadIdx.x;
  int v = (i < nb) ? bp[i] : 0;
  int lane = threadIdx.x & 63;
  int sidx = threadIdx.x >> 6;
  int sv = v;
  for (int off = 1; off < 64; off <<= 1) {
    int tt = __shfl_up(sv, off, 64);
    if (lane >= off) sv += tt;
  }
  __shared__ int wsum[4];
  if (lane == 63) wsum[sidx] = sv;
  __syncthreads();
  int add = 0;
  for (int w = 0; w < sidx; ++w) add += wsum[w];
  sv += add;
  if (i < nb) bp[i] = sv;
}
__global__ void scan3_k(const int* __restrict__ incl, const int* __restrict__ cnt,
                        const int* __restrict__ bsum, int* __restrict__ rowptr, int n, int E) {
  int t = blockIdx.y;
  int i = blockIdx.x * 256 + threadIdx.x;
  int* rp = rowptr + (size_t)t * (n + 1);
  if (i < n) {
    int v = incl[(size_t)t * n + i] - cnt[(size_t)t * n + i] +
            (blockIdx.x ? bsum[t * 256 + blockIdx.x - 1] : 0);
    rp[i] = v;
  }
  if (i == 0) rp[n] = E;
}
__global__ void scat_k(const int* __restrict__ src, const int* __restrict__ dst,
                       const float* __restrict__ w, const ushort* __restrict__ rank,
                       const int* __restrict__ rowptr, int2* __restrict__ epk,
                       int N1, int E) {
  int t = blockIdx.x & 7;
  int e = (blockIdx.x >> 3) * 256 + threadIdx.x;
  if (e >= E) return;
  size_t i = (size_t)t * E + e;
  int slot = rowptr[(size_t)t * N1 + dst[i]] + (int)rank[i];
  epk[(size_t)t * E + slot] = make_int2(src[i], __float_as_int(w[i]));
}
__global__ void deg_k(const int2* __restrict__ epk, const int* __restrict__ rowptr,
                      float* __restrict__ dinv, int N, int N1, int E) {
  int t = blockIdx.x & 7;
  int n = (blockIdx.x >> 3) * 256 + threadIdx.x;
  if (n >= N) return;
  const int* rp = rowptr + (size_t)t * N1;
  const int2* ep = epk + (size_t)t * E;
  float s = 1.f;  // self loop
  int b = rp[n], e = rp[n + 1];
  for (int j = b; j < e; ++j) s += __int_as_float(ep[j].y);
  dinv[(size_t)t * N + n] = rsqrtf(s);
}
__global__ void norm_k(int2* __restrict__ epk, const int* __restrict__ rowptr,
                       const float* __restrict__ dinv, int N, int N1, int E) {
  int t = blockIdx.x & 7;
  int n = (blockIdx.x >> 3) * 256 + threadIdx.x;
  if (n >= N) return;
  const int* rp = rowptr + (size_t)t * N1;
  const float* dv = dinv + (size_t)t * N;
  int2* ep = epk + (size_t)t * E;
  float dn = dv[n];
  int b = rp[n], e = rp[n + 1];
  for (int j = b; j < e; ++j) {
    int2 ed = ep[j];
    ep[j].y = __float_as_int(dv[ed.x] * __int_as_float(ed.y) * dn);
  }
}

// ---------------- GCN aggregation (wave-coherent, 8-edge unroll, T-batched) ----------------
__global__ __launch_bounds__(256) void agg_k(const ushort* __restrict__ xw, const float* __restrict__ dinv,
                                             const int* __restrict__ rowptr, const int2* __restrict__ epk,
                                             ushort* __restrict__ ag, float* __restrict__ oStat,
                                             int N, int N1, int E) {
  const int ty = blockIdx.y;
  xw    += (size_t)ty * N * 64;
  ag    += (size_t)ty * N * 64;
  dinv  += (size_t)ty * N;
  rowptr+= (size_t)ty * N1;
  epk   += (size_t)ty * E;
  oStat += (size_t)ty * 1536;
  __shared__ float redS[64], redQ[64];
  if (threadIdx.x < 64) { redS[threadIdx.x] = 0.f; redQ[threadIdx.x] = 0.f; }
  __syncthreads();
  int f = threadIdx.x & 63;
  int wvl = threadIdx.x >> 6;
  int stride = gridDim.x * 4;
  float s = 0.f, q = 0.f;
  for (int n = blockIdx.x * 4 + wvl; n < N; n += stride) {
    float di = dinv[n];
    float acc0 = bf2f(xw[(size_t)n * 64 + f]) * di * di;  // self loop
    float acc1 = 0.f;
    int b = rowptr[n], e = rowptr[n + 1];
    int j = b;
    if ((j & 1) && j < e) {
      int2 e0 = epk[j];
      acc1 += bf2f(xw[(size_t)e0.x * 64 + f]) * __int_as_float(e0.y);
      ++j;
    }
    for (; j + 7 < e; j += 8) {
      int4 p01 = *(const int4*)&epk[j];
      int4 p23 = *(const int4*)&epk[j + 2];
      int4 p45 = *(const int4*)&epk[j + 4];
      int4 p67 = *(const int4*)&epk[j + 6];
      acc0 += bf2f(xw[(size_t)p01.x * 64 + f]) * __int_as_float(p01.y);
      acc1 += bf2f(xw[(size_t)p01.z * 64 + f]) * __int_as_float(p01.w);
      acc0 += bf2f(xw[(size_t)p23.x * 64 + f]) * __int_as_float(p23.y);
      acc1 += bf2f(xw[(size_t)p23.z * 64 + f]) * __int_as_float(p23.w);
      acc0 += bf2f(xw[(size_t)p45.x * 64 + f]) * __int_as_float(p45.y);
      acc1 += bf2f(xw[(size_t)p45.z * 64 + f]) * __int_as_float(p45.w);
      acc0 += bf2f(xw[(size_t)p67.x * 64 + f]) * __int_as_float(p67.y);
      acc1 += bf2f(xw[(size_t)p67.z * 64 + f]) * __int_as_float(p67.w);
    }
    for (; j + 1 < e; j += 2) {
      int4 p01 = *(const int4*)&epk[j];
      acc0 += bf2f(xw[(size_t)p01.x * 64 + f]) * __int_as_float(p01.y);
      acc1 += bf2f(xw[(size_t)p01.z * 64 + f]) * __int_as_float(p01.w);
    }
    if (j < e) {
      int2 e0 = epk[j];
      acc0 += bf2f(xw[(size_t)e0.x * 64 + f]) * __int_as_float(e0.y);
    }
    float acc = acc0 + acc1;
    ag[(size_t)n * 64 + f] = f2bf(acc);
    s += acc;
    q += acc * acc;
  }
  atomicAdd(&redS[f], s);
  atomicAdd(&redQ[f], q);
  __syncthreads();
  if (threadIdx.x < 64) {
    atomicAdd(&oStat[threadIdx.x], redS[threadIdx.x]);
    atomicAdd(&oStat[128 + threadIdx.x], redQ[threadIdx.x]);
  }
}

// ---------------- classifier final: BN+ReLU(u fp32) @ Wc2 + bc2 ----------------
__global__ __launch_bounds__(256) void final_k(const float* __restrict__ u, const float* __restrict__ st,
                                               const float* __restrict__ g, const float* __restrict__ be,
                                               const float* __restrict__ Wc2, const float* __restrict__ bc2,
                                               float* __restrict__ out, int N) {
  __shared__ float Wl[512], sc[128], sh[128];
  for (int i = threadIdx.x; i < 512; i += 256) Wl[i] = Wc2[i];
  if (threadIdx.x < 128) {
    int c = threadIdx.x;
    float invN = 1.f / (float)N;
    float mn = st[c] * invN;
    float vr = fmaxf(st[128 + c] * invN - mn * mn, 0.f);
    float s = g[c] * rsqrtf(vr + BN_EPS);
    sc[c] = s;
    sh[c] = be[c] - mn * s;
  }
  __syncthreads();
  int idx = blockIdx.x * 256 + threadIdx.x;
  if (idx >= N * 4) return;
  int n = idx >> 2, c = idx & 3;
  const float* ur = u + (size_t)n * 128;
  float acc = bc2[c];
#pragma unroll 8
  for (int k = 0; k < 128; ++k) {
    float v = fmaxf(fmaf(ur[k], sc[k], sh[k]), 0.f);
    acc = fmaf(v, Wl[k * 4 + c], acc);
  }
  out[idx] = acc;
}

extern "C" void kernel_launch(void* const* d_in, const int* in_sizes, int n_in,
                              void* d_out, int out_size, void* d_ws, size_t ws_size,
                              hipStream_t stream) {
  const float* xs   = (const float*)d_in[0];
  const int*   esrc = (const int*)d_in[1];
  const int*   edst = (const int*)d_in[2];
  const float* ew   = (const float*)d_in[3];
  const float* W1   = (const float*)d_in[4];
  const float* g1   = (const float*)d_in[6];
  const float* be1  = (const float*)d_in[7];
  const float* W2   = (const float*)d_in[8];
  const float* g2   = (const float*)d_in[10];
  const float* be2  = (const float*)d_in[11];
  const float* gW   = (const float*)d_in[12];
  const float* gam  = (const float*)d_in[14];
  const float* gbe  = (const float*)d_in[15];
  const float* Wp   = (const float*)d_in[16];
  const float* gp   = (const float*)d_in[18];
  const float* bep  = (const float*)d_in[19];
  const float* Wih  = (const float*)d_in[20];
  const float* Whh  = (const float*)d_in[21];
  const float* bih  = (const float*)d_in[22];
  const float* bhh  = (const float*)d_in[23];
  const float* Wc1  = (const float*)d_in[24];
  const float* gc   = (const float*)d_in[26];
  const float* bec  = (const float*)d_in[27];
  const float* Wc2  = (const float*)d_in[28];
  const float* bc2  = (const float*)d_in[29];
  float* out = (float*)d_out;

  const int T = 8;
  const int TC = 4;  // timestep chunk for stage-batched encoder
  const int N = in_sizes[0] / (T * 32);
  const int E = in_sizes[1] / T;
  const int TE = T * E, TN = T * N, N1 = N + 1;

  // ---- workspace layout (bytes); total ~186MB (<= 212MB proven in round 1) ----
  size_t off = 0;
  auto alloc = [&](size_t bytes) { size_t o = off; off += (bytes + 255) & ~(size_t)255; return o; };
  char* base = (char*)d_ws;
  size_t oH      = alloc((size_t)T * N * 64 * 2);   // Hraw bf16 [T,N,64]
  size_t oEpk    = alloc((size_t)TE * 8);           // packed (src, w/norm)
  size_t oRp     = alloc((size_t)T * N1 * 4);       // rowptr
  size_t oDinv   = alloc((size_t)TN * 4);           // dinv
  size_t oStats  = alloc((size_t)49 * 256 * 4);     // stats slots
  size_t oBsum   = alloc((size_t)T * 256 * 4);      // scan block sums
  size_t oWf     = alloc((size_t)70000 * 2);        // prebuilt weight fragments
  size_t oArena  = alloc((size_t)80 * 1024 * 1024); // phase-shared arena
  if (ws_size < off) return;

  ushort* Hraw  = (ushort*)(base + oH);
  int2*   epk   = (int2*)(base + oEpk);
  int*    rowptr= (int*)(base + oRp);
  float*  dinv  = (float*)(base + oDinv);
  float*  statsA= (float*)(base + oStats);
  int*    bsum  = (int*)(base + oBsum);
  ushort* wfA   = (ushort*)(base + oWf);
  char*   arena = base + oArena;

  // weight fragment offsets (ushort elements)
  ushort* W1f  = wfA;               // 32*128
  ushort* W2f  = W1f + 4096;        // 128*64
  ushort* gW0f = W2f + 8192;        // 64*64
  ushort* gW1f = gW0f + 4096;
  ushort* gW2f = gW1f + 4096;
  ushort* Wpf  = gW2f + 4096;       // 64*64
  ushort* Wihf = Wpf + 4096;        // 64*192
  ushort* Whhf = Wihf + 12288;
  ushort* Wc1f = Whhf + 12288;      // 64*128

  // prep-phase arena views
  int*    cnt  = (int*)arena;                      // [T*N]
  int*    incl = cnt + TN;                         // [T*N]
  ushort* rank = (ushort*)(incl + TN);             // [T*E]
  // encoder-phase arena views (per chunk of TC=4 timesteps)
  // A region [0, 51.2MB): y1 (stages 1-2), then xw[0,25.6) + hcur[25.6,51.2)
  // B region [52MB, 77.6MB): hbraw (stages 2-3), then agb
  ushort* y1A  = (ushort*)arena;                              // [TC,N,128]
  ushort* xwA  = (ushort*)arena;                              // [TC,N,64]
  ushort* hcA  = xwA + (size_t)TC * N * 64;                   // [TC,N,64]
  ushort* hbB  = (ushort*)(arena + (size_t)52 * 1024 * 1024); // [TC,N,64]
  ushort* agB  = hbB;                                         // [TC,N,64] (hbraw dead)
  // gru/cls-phase arena views
  float*  uf = (float*)arena;                                 // [N,128] fp32 [0,25.6MB)
  ushort* hA = (ushort*)(arena + (size_t)26 * 1024 * 1024);   // [N,64]
  ushort* hB = (ushort*)(arena + (size_t)40 * 1024 * 1024);   // [N,64]

  const int nb = CDIV(N, 256);

#define SLOT(t, j) (statsA + ((size_t)(t) * 6 + (j)) * 256)

  hipMemsetAsync(statsA, 0, (size_t)49 * 256 * 4, stream);
  hipMemsetAsync(cnt, 0, (size_t)TN * 4, stream);

  // ---- weight fragment prep ----
  wprep_k<32, 128, false><<<1, 256, 0, stream>>>(W1, W1f);
  wprep_k<128, 64, false><<<1, 256, 0, stream>>>(W2, W2f);
  wprep_k<64, 64, false><<<1, 256, 0, stream>>>(gW, gW0f);
  wprep_k<64, 64, false><<<1, 256, 0, stream>>>(gW + 4096, gW1f);
  wprep_k<64, 64, false><<<1, 256, 0, stream>>>(gW + 8192, gW2f);
  wprep_k<64, 64, false><<<1, 256, 0, stream>>>(Wp, Wpf);
  wprep_k<64, 192, true><<<1, 256, 0, stream>>>(Wih, Wihf);
  wprep_k<64, 192, true><<<1, 256, 0, stream>>>(Whh, Whhf);

  // ================= batched graph prep (all T, XCD-partitioned) =================
  const int nbe = CDIV(E, 256);
  hist_k<<<8 * nbe, 256, 0, stream>>>(edst, cnt, rank, N, E);
  scan1_k<<<dim3(nb, T), 256, 0, stream>>>(cnt, incl, bsum, N);
  scan2_k<<<dim3(1, T), 256, 0, stream>>>(bsum, nb);
  scan3_k<<<dim3(nb, T), 256, 0, stream>>>(incl, cnt, bsum, rowptr, N, E);
  scat_k<<<8 * nbe, 256, 0, stream>>>(esrc, edst, ew, rank, rowptr, epk, N1, E);
  deg_k<<<8 * nb, 256, 0, stream>>>(epk, rowptr, dinv, N, N1, E);
  norm_k<<<8 * nb, 256, 0, stream>>>(epk, rowptr, dinv, N, N1, E);
  wprep_k<64, 128, false><<<1, 256, 0, stream>>>(Wc1, Wc1f);

  const int gemmGrid = CDIV(N, 128);
  const void*  nv  = nullptr;
  const float* ncf = nullptr;
  float* nmf = nullptr;
  ushort* nus = nullptr;

  // ================= stage-batched encoder: 2 chunks x 4 timesteps =================
  for (int c = 0; c < T / TC; ++c) {
    const int t0 = c * TC;
    const dim3 gdim(gemmGrid, TC);
    const dim3 adim(2048, TC);
    const float* xt = xs + (size_t)t0 * N * 32;
    const float* dvT = dinv + (size_t)t0 * N;
    const int* rpT = rowptr + (size_t)t0 * N1;
    const int2* epT = epk + (size_t)t0 * E;

    // MLP1: y1A[ty] = xt[ty] @ W1, stats(t0+ty, 0)
    gemm2<32, 128, 1, false, true, false, false><<<gdim, 256, 0, stream>>>(
        xt, nv, W1f, y1A, nus, ncf, ncf, ncf, SLOT(t0, 0), N);
    // MLP2: hbB[ty] = BNReLU(y1A[ty]) @ W2, stats(.,1)
    gemm2<128, 64, 2, true, true, false, false><<<gdim, 256, 0, stream>>>(
        y1A, nv, W2f, hbB, nus, SLOT(t0, 0), g1, be1, SLOT(t0, 1), N);
    // GCN0: A = BNReLU(hbB[ty]) [side -> hcA], out xwA
    gemm2<64, 64, 2, true, false, false, true><<<gdim, 256, 0, stream>>>(
        hbB, nv, gW0f, xwA, hcA, SLOT(t0, 1), g2, be2, nmf, N);
    agg_k<<<adim, 256, 0, stream>>>(xwA, dvT, rpT, epT, agB, SLOT(t0, 2), N, N1, E);
    // GCN1: A = hcA[ty] + ReLU(BN(agB[ty])) [side -> hcA], out xwA
    gemm2<64, 64, 3, true, false, false, true><<<gdim, 256, 0, stream>>>(
        hcA, agB, gW1f, xwA, hcA, SLOT(t0, 2), gam, gbe, nmf, N);
    agg_k<<<adim, 256, 0, stream>>>(xwA, dvT, rpT, epT, agB, SLOT(t0, 3), N, N1, E);
    // GCN2
    gemm2<64, 64, 3, true, false, false, true><<<gdim, 256, 0, stream>>>(
        hcA, agB, gW2f, xwA, hcA, SLOT(t0, 3), gam + 64, gbe + 64, nmf, N);
    agg_k<<<adim, 256, 0, stream>>>(xwA, dvT, rpT, epT, agB, SLOT(t0, 4), N, N1, E);
    // POST: raw -> Hraw[t0+ty] (bf16) + stats(.,5)
    gemm2<64, 64, 3, true, true, false, false><<<gdim, 256, 0, stream>>>(
        hcA, agB, Wpf, Hraw + (size_t)t0 * N * 64, nus, SLOT(t0, 4), gam + 128, gbe + 128, SLOT(t0, 5), N);
  }

  // ================= GRU over T steps (fused BN + dual-GEMM + gate) =================
  hipMemsetAsync(hA, 0, (size_t)N * 64 * 2, stream);
  ushort* hprev = hA;
  ushort* hnext = hB;
  for (int t = 0; t < T; ++t) {
    gruf_k<<<gemmGrid, 256, 0, stream>>>(Hraw + (size_t)t * N * 64, hprev, Wihf, Whhf,
                                         SLOT(t, 5), gp, bep, bih, bhh, hnext, N);
    ushort* tmp = hprev; hprev = hnext; hnext = tmp;
  }
  // after 8 steps hprev == hA (arena+26MB; uf occupies [0,25.6MB) - no overlap)

  // ================= classifier =================
  gemm2<64, 128, 0, false, true, true, false><<<dim3(gemmGrid, 1), 256, 0, stream>>>(
      hprev, nv, Wc1f, uf, nus, ncf, ncf, ncf, statsA + 48 * 256, N);
  final_k<<<CDIV(N * 4, 256), 256, 0, stream>>>(uf, statsA + 48 * 256, gc, bec, Wc2, bc2, out, N);
}

// Round 13
// 2022.669 us; speedup vs baseline: 2.2775x; 1.3139x over previous
//
#include <hip/hip_runtime.h>
#include <hip/hip_bf16.h>
#include <cstddef>

#define CDIV(a,b) (((a)+(b)-1)/(b))

static constexpr float BN_EPS = 1e-5f;

typedef __attribute__((ext_vector_type(8))) short short8v;   // 8 bf16 (4 VGPRs)
typedef __attribute__((ext_vector_type(4))) float f32x4;

__device__ inline ushort f2bf(float x) {
  unsigned u = __float_as_uint(x);
  unsigned r = (u + 0x7fffu + ((u >> 16) & 1u)) >> 16;
  return (ushort)r;
}
__device__ inline float bf2f(ushort h) {
  return __uint_as_float(((unsigned)h) << 16);
}

// ---------------- weight fragment prep (once per launch) ----------------
template<int K, int M, bool TRANSW>
__global__ void wprep_k(const float* __restrict__ W, ushort* __restrict__ Wf) {
  constexpr int NKC = K / 32;
  for (int i = threadIdx.x; i < K * M; i += 256) {
    int k, m;
    if (TRANSW) { m = i / K; k = i - m * K; }
    else        { k = i / M; m = i - k * M; }
    float wv = W[i];
    int mt = m >> 4, ml = m & 15, kc = k >> 5, kr = k & 31;
    int lane = ((kr >> 3) << 4) | ml;
    int j = kr & 7;
    Wf[(size_t)((mt * NKC + kc) * 64 + lane) * 8 + j] = f2bf(wv);
  }
}

// =====================================================================
// bf16 MFMA GEMM v4 — T-batched via blockIdx.y (independent timesteps).
// AMODE: 0 = A bf16; 1 = A fp32; 2 = ReLU(BN(raw Ain)); 3 = Ain(bf16)+ReLU(BN(raw A2))
// RAW16: raw source is bf16 (else fp32). Stats from exact fp32 accumulators.
// NOTE: bnSc/bnSh produced by thread subset -> __syncthreads() after is REQUIRED.
// =====================================================================
template<int K, int M, int AMODE, bool RAW16, bool FSTAT, bool OUTF32, bool SIDE>
__global__ __launch_bounds__(256)
void gemm2(const void* __restrict__ Ain, const void* __restrict__ A2,
           const ushort* __restrict__ Wf, void* __restrict__ Cout,
           ushort* __restrict__ side,
           const float* __restrict__ aStat, const float* __restrict__ aG,
           const float* __restrict__ aB, float* __restrict__ oStat, int N) {
  constexpr int BM = 128;
  constexpr int NKC = K / 32;
  constexpr int NMT = M / 16;
  constexpr bool BN = (AMODE >= 2);
  constexpr int ABYTES = (AMODE == 1) ? 4 : ((AMODE == 2 && !RAW16) ? 4 : 2);
  __shared__ __align__(16) ushort As[BM * K];
  __shared__ __align__(16) ushort WfL[M * K];
  __shared__ float bnSc[BN ? K : 1];
  __shared__ float bnSh[BN ? K : 1];
  __shared__ float redS[FSTAT ? M : 1];
  __shared__ float redQ[FSTAT ? M : 1];
  const int tid = threadIdx.x;
  const int row0 = blockIdx.x * BM;
  const int ty = blockIdx.y;

  const char* AinB = (const char*)Ain + (size_t)ty * N * K * ABYTES;
  const char* A2B  = (AMODE == 3) ? ((const char*)A2 + (size_t)ty * N * K * (RAW16 ? 2 : 4)) : nullptr;
  char* CoutB = (char*)Cout + (size_t)ty * N * M * (OUTF32 ? 4 : 2);
  ushort* sideB = SIDE ? (side + (size_t)ty * N * K) : nullptr;
  if (BN) aStat += (size_t)ty * 1536;
  if (FSTAT) oStat += (size_t)ty * 1536;

  for (int i = tid; i < K * M / 8; i += 256)
    ((short8v*)WfL)[i] = ((const short8v*)Wf)[i];
  if (BN) {
    float invN = 1.f / (float)N;
    for (int i = tid; i < K; i += 256) {
      float mn = aStat[i] * invN;
      float vr = fmaxf(aStat[128 + i] * invN - mn * mn, 0.f);
      float sc = aG[i] * rsqrtf(vr + BN_EPS);
      bnSc[i] = sc;
      bnSh[i] = aB[i] - mn * sc;
    }
    __syncthreads();  // bnSc/bnSh visible to all threads before A-staging
  }
  if (FSTAT) {
    if (tid < M) { redS[tid] = 0.f; redQ[tid] = 0.f; }
  }

  // ---- A -> XOR-swizzled bf16 LDS ----
  {
    const float*  Af  = (const float*)AinB;
    const ushort* Ab  = (const ushort*)AinB;
    const float*  A2f = (const float*)A2B;
    const ushort* A2b = (const ushort*)A2B;
    for (int i = tid; i < BM * K / 4; i += 256) {
      int row = (i * 4) / K, k0 = (i * 4) % K;
      int grow = row0 + row;
      ushort h4[4] = {0, 0, 0, 0};
      if (AMODE == 0) {
        if (grow < N) *(ushort4*)h4 = *(const ushort4*)&Ab[(size_t)grow * K + k0];
      } else if (AMODE == 1) {
        float vv[4] = {0.f, 0.f, 0.f, 0.f};
        if (grow < N) *(float4*)vv = *(const float4*)&Af[(size_t)grow * K + k0];
#pragma unroll
        for (int c = 0; c < 4; ++c) h4[c] = f2bf(vv[c]);
      } else {
        if (grow < N) {
          float rw[4];
          if (AMODE == 2) {
            if (RAW16) {
              ushort t4[4];
              *(ushort4*)t4 = *(const ushort4*)&Ab[(size_t)grow * K + k0];
#pragma unroll
              for (int c = 0; c < 4; ++c) rw[c] = bf2f(t4[c]);
            } else {
              *(float4*)rw = *(const float4*)&Af[(size_t)grow * K + k0];
            }
          } else {
            if (RAW16) {
              ushort t4[4];
              *(ushort4*)t4 = *(const ushort4*)&A2b[(size_t)grow * K + k0];
#pragma unroll
              for (int c = 0; c < 4; ++c) rw[c] = bf2f(t4[c]);
            } else {
              *(float4*)rw = *(const float4*)&A2f[(size_t)grow * K + k0];
            }
          }
          ushort b4[4];
          if (AMODE == 3) *(ushort4*)b4 = *(const ushort4*)&Ab[(size_t)grow * K + k0];
#pragma unroll
          for (int c = 0; c < 4; ++c) {
            float v = fmaxf(fmaf(rw[c], bnSc[k0 + c], bnSh[k0 + c]), 0.f);
            float vv = (AMODE == 3) ? bf2f(b4[c]) + v : v;
            h4[c] = f2bf(vv);
          }
          if (SIDE) *(ushort4*)&sideB[(size_t)grow * K + k0] = *(ushort4*)h4;
        }
      }
      unsigned off = ((unsigned)(row * K + k0) * 2u) ^ (((unsigned)(row & 7)) << 4);
      *(ushort4*)((char*)As + off) = *(ushort4*)h4;
    }
  }
  __syncthreads();

  const int wvi = tid >> 6, lane = tid & 63;
  const int lrow = lane & 15, lkg = lane >> 4;

  short8v af[2][NKC];
#pragma unroll
  for (int rt = 0; rt < 2; ++rt)
#pragma unroll
    for (int kc = 0; kc < NKC; ++kc) {
      int row = wvi * 32 + rt * 16 + lrow;
      unsigned off = ((unsigned)(row * K + kc * 32 + lkg * 8) * 2u) ^ (((unsigned)(row & 7)) << 4);
      af[rt][kc] = *(const short8v*)((const char*)As + off);
    }

  f32x4 acc[2][NMT];
#pragma unroll
  for (int rt = 0; rt < 2; ++rt)
#pragma unroll
    for (int mt = 0; mt < NMT; ++mt) acc[rt][mt] = f32x4{0.f, 0.f, 0.f, 0.f};

#pragma unroll
  for (int mt = 0; mt < NMT; ++mt) {
    short8v bf[NKC];
#pragma unroll
    for (int kc = 0; kc < NKC; ++kc)
      bf[kc] = *(const short8v*)&WfL[(size_t)((mt * NKC + kc) * 64 + lane) * 8];
#pragma unroll
    for (int rt = 0; rt < 2; ++rt)
#pragma unroll
      for (int kc = 0; kc < NKC; ++kc)
        acc[rt][mt] = __builtin_amdgcn_mfma_f32_16x16x32_bf16(af[rt][kc], bf[kc], acc[rt][mt], 0, 0, 0);
  }

  // ---- C write, C/D layout: col=lane&15, row=(lane>>4)*4+i ----
#pragma unroll
  for (int rt = 0; rt < 2; ++rt)
#pragma unroll
    for (int mt = 0; mt < NMT; ++mt) {
#pragma unroll
      for (int i = 0; i < 4; ++i) {
        int grow = row0 + wvi * 32 + rt * 16 + lkg * 4 + i;
        if (grow < N) {
          if (OUTF32) ((float*)CoutB)[(size_t)grow * M + mt * 16 + lrow] = acc[rt][mt][i];
          else        ((ushort*)CoutB)[(size_t)grow * M + mt * 16 + lrow] = f2bf(acc[rt][mt][i]);
        }
      }
    }

  if (FSTAT) {
#pragma unroll
    for (int mt = 0; mt < NMT; ++mt) {
      float s = 0.f, q = 0.f;
#pragma unroll
      for (int rt = 0; rt < 2; ++rt)
#pragma unroll
        for (int i = 0; i < 4; ++i) {
          int grow = row0 + wvi * 32 + rt * 16 + lkg * 4 + i;
          if (grow < N) { float v = acc[rt][mt][i]; s += v; q += v * v; }
        }
      s += __shfl_xor(s, 16); s += __shfl_xor(s, 32);
      q += __shfl_xor(q, 16); q += __shfl_xor(q, 32);
      if (lkg == 0) {
        atomicAdd(&redS[mt * 16 + lrow], s);
        atomicAdd(&redQ[mt * 16 + lrow], q);
      }
    }
    __syncthreads();
    if (tid < M) {
      atomicAdd(&oStat[tid], redS[tid]);
      atomicAdd(&oStat[128 + tid], redQ[tid]);
    }
  }
}

// ---------------- fused GRU step with H-BN folded into A-staging ----------------
__global__ __launch_bounds__(256)
void gruf_k(const ushort* __restrict__ Hraw, const ushort* __restrict__ hprev,
            const ushort* __restrict__ Wihf, const ushort* __restrict__ Whhf,
            const float* __restrict__ hst, const float* __restrict__ gp,
            const float* __restrict__ bep,
            const float* __restrict__ bih, const float* __restrict__ bhh,
            ushort* __restrict__ hnext, int N) {
  __shared__ float bihL[192], bhhL[192], scL[64], shL[64];
  const int tid = threadIdx.x;
  if (tid < 192) { bihL[tid] = bih[tid]; bhhL[tid] = bhh[tid]; }
  if (tid < 64) {
    float invN = 1.f / (float)N;
    float mn = hst[tid] * invN;
    float vr = fmaxf(hst[128 + tid] * invN - mn * mn, 0.f);
    float s = gp[tid] * rsqrtf(vr + BN_EPS);
    scL[tid] = s;
    shL[tid] = bep[tid] - mn * s;
  }
  __syncthreads();
  const int wvi = tid >> 6, lane = tid & 63;
  const int lrow = lane & 15, lkg = lane >> 4;
  const int row0 = blockIdx.x * 128;
  const short8v zv = short8v{0, 0, 0, 0, 0, 0, 0, 0};
  for (int rt = 0; rt < 2; ++rt) {
    int arow = row0 + wvi * 32 + rt * 16 + lrow;
    bool aok = arow < N;
    short8v afA[2], afB[2];
#pragma unroll
    for (int kc = 0; kc < 2; ++kc) {
      short8v raw = aok ? *(const short8v*)&Hraw[(size_t)arow * 64 + kc * 32 + lkg * 8] : zv;
      short8v a;
#pragma unroll
      for (int j = 0; j < 8; ++j) {
        int k = kc * 32 + lkg * 8 + j;
        float v = fmaxf(fmaf(bf2f((ushort)raw[j]), scL[k], shL[k]), 0.f);
        a[j] = (short)f2bf(v);
      }
      afA[kc] = a;
      afB[kc] = aok ? *(const short8v*)&hprev[(size_t)arow * 64 + kc * 32 + lkg * 8] : zv;
    }
    f32x4 gacc[12], hacc[12];
#pragma unroll
    for (int mt = 0; mt < 12; ++mt) {
      gacc[mt] = f32x4{0.f, 0.f, 0.f, 0.f};
      hacc[mt] = f32x4{0.f, 0.f, 0.f, 0.f};
#pragma unroll
      for (int kc = 0; kc < 2; ++kc) {
        short8v bwi = *(const short8v*)&Wihf[(size_t)((mt * 2 + kc) * 64 + lane) * 8];
        short8v bwh = *(const short8v*)&Whhf[(size_t)((mt * 2 + kc) * 64 + lane) * 8];
        gacc[mt] = __builtin_amdgcn_mfma_f32_16x16x32_bf16(afA[kc], bwi, gacc[mt], 0, 0, 0);
        hacc[mt] = __builtin_amdgcn_mfma_f32_16x16x32_bf16(afB[kc], bwh, hacc[mt], 0, 0, 0);
      }
    }
#pragma unroll
    for (int i = 0; i < 4; ++i) {
      int grow = row0 + wvi * 32 + rt * 16 + lkg * 4 + i;
      if (grow < N) {
        const ushort* hpp = hprev + (size_t)grow * 64;
#pragma unroll
        for (int mtj = 0; mtj < 4; ++mtj) {
          int j = mtj * 16 + lrow;
          float ir = gacc[mtj][i] + bihL[j];
          float iz = gacc[mtj + 4][i] + bihL[64 + j];
          float ig = gacc[mtj + 8][i] + bihL[128 + j];
          float hr = hacc[mtj][i] + bhhL[j];
          float hz = hacc[mtj + 4][i] + bhhL[64 + j];
          float hg = hacc[mtj + 8][i] + bhhL[128 + j];
          float r = 1.f / (1.f + expf(-(ir + hr)));
          float z = 1.f / (1.f + expf(-(iz + hz)));
          float ng = tanhf(ig + r * hg);
          float hn = (1.f - z) * ng + z * bf2f(hpp[j]);
          hnext[(size_t)grow * 64 + j] = f2bf(hn);
        }
      }
    }
  }
}

// ---------------- batched graph prep (t = blockIdx.x & 7) ----------------
__global__ void hist_k(const int* __restrict__ dst, int* __restrict__ cnt, ushort* __restrict__ rank,
                       int N, int E) {
  int t = blockIdx.x & 7;
  int e = (blockIdx.x >> 3) * 256 + threadIdx.x;
  if (e >= E) return;
  size_t i = (size_t)t * E + e;
  rank[i] = (ushort)atomicAdd(&cnt[t * N + dst[i]], 1);
}
__global__ __launch_bounds__(256) void scan1_k(const int* __restrict__ in, int* __restrict__ incl,
                                               int* __restrict__ bsum, int n) {
  int t = blockIdx.y;
  const int* inp = in + (size_t)t * n;
  int* ip = incl + (size_t)t * n;
  int i = blockIdx.x * 256 + threadIdx.x;
  int v = (i < n) ? inp[i] : 0;
  int lane = threadIdx.x & 63;
  int sidx = threadIdx.x >> 6;
  int sv = v;
  for (int off = 1; off < 64; off <<= 1) {
    int tt = __shfl_up(sv, off, 64);
    if (lane >= off) sv += tt;
  }
  __shared__ int wsum[4];
  if (lane == 63) wsum[sidx] = sv;
  __syncthreads();
  int add = 0;
  for (int w = 0; w < sidx; ++w) add += wsum[w];
  sv += add;
  if (i < n) ip[i] = sv;
  if (threadIdx.x == 255) bsum[t * 256 + blockIdx.x] = sv;
}
__global__ __launch_bounds__(256) void scan2_k(int* __restrict__ bsum, int nb) {
  int t = blockIdx.y;
  int* bp = bsum + t * 256;
  int i = threadIdx.x;
  int v = (i < nb) ? bp[i] : 0;
  int lane = threadIdx.x & 63;
  int sidx = threadIdx.x >> 6;
  int sv = v;
  for (int off = 1; off < 64; off <<= 1) {
    int tt = __shfl_up(sv, off, 64);
    if (lane >= off) sv += tt;
  }
  __shared__ int wsum[4];
  if (lane == 63) wsum[sidx] = sv;
  __syncthreads();
  int add = 0;
  for (int w = 0; w < sidx; ++w) add += wsum[w];
  sv += add;
  if (i < nb) bp[i] = sv;
}
__global__ void scan3_k(const int* __restrict__ incl, const int* __restrict__ cnt,
                        const int* __restrict__ bsum, int* __restrict__ rowptr, int n, int E) {
  int t = blockIdx.y;
  int i = blockIdx.x * 256 + threadIdx.x;
  int* rp = rowptr + (size_t)t * (n + 1);
  if (i < n) {
    int v = incl[(size_t)t * n + i] - cnt[(size_t)t * n + i] +
            (blockIdx.x ? bsum[t * 256 + blockIdx.x - 1] : 0);
    rp[i] = v;
  }
  if (i == 0) rp[n] = E;
}
__global__ void scat_k(const int* __restrict__ src, const int* __restrict__ dst,
                       const float* __restrict__ w, const ushort* __restrict__ rank,
                       const int* __restrict__ rowptr, int2* __restrict__ epk,
                       int N1, int E) {
  int t = blockIdx.x & 7;
  int e = (blockIdx.x >> 3) * 256 + threadIdx.x;
  if (e >= E) return;
  size_t i = (size_t)t * E + e;
  int slot = rowptr[(size_t)t * N1 + dst[i]] + (int)rank[i];
  epk[(size_t)t * E + slot] = make_int2(src[i], __float_as_int(w[i]));
}
__global__ void deg_k(const int2* __restrict__ epk, const int* __restrict__ rowptr,
                      float* __restrict__ dinv, int N, int N1, int E) {
  int t = blockIdx.x & 7;
  int n = (blockIdx.x >> 3) * 256 + threadIdx.x;
  if (n >= N) return;
  const int* rp = rowptr + (size_t)t * N1;
  const int2* ep = epk + (size_t)t * E;
  float s = 1.f;  // self loop
  int b = rp[n], e = rp[n + 1];
  for (int j = b; j < e; ++j) s += __int_as_float(ep[j].y);
  dinv[(size_t)t * N + n] = rsqrtf(s);
}
__global__ void norm_k(int2* __restrict__ epk, const int* __restrict__ rowptr,
                       const float* __restrict__ dinv, int N, int N1, int E) {
  int t = blockIdx.x & 7;
  int n = (blockIdx.x >> 3) * 256 + threadIdx.x;
  if (n >= N) return;
  const int* rp = rowptr + (size_t)t * N1;
  const float* dv = dinv + (size_t)t * N;
  int2* ep = epk + (size_t)t * E;
  float dn = dv[n];
  int b = rp[n], e = rp[n + 1];
  for (int j = b; j < e; ++j) {
    int2 ed = ep[j];
    ep[j].y = __float_as_int(dv[ed.x] * __int_as_float(ed.y) * dn);
  }
}

// ---------------- GCN aggregation (wave-coherent, XCD-affine by timestep) ----------------
// 1D grid; ty = blockIdx.x & 3 -> under round-robin block->XCD dispatch, timestep
// t's blocks land on XCDs {t, t+4} whose combined 8MB L2 holds t's 6.4MB table.
// Wave structure unchanged: 64 lanes = 64 features of ONE node.
__global__ __launch_bounds__(256) void agg_k(const ushort* __restrict__ xw, const float* __restrict__ dinv,
                                             const int* __restrict__ rowptr, const int2* __restrict__ epk,
                                             ushort* __restrict__ ag, float* __restrict__ oStat,
                                             int N, int N1, int E) {
  const int ty = blockIdx.x & 3;
  const int blk = blockIdx.x >> 2;
  const int nblk = gridDim.x >> 2;
  xw    += (size_t)ty * N * 64;
  ag    += (size_t)ty * N * 64;
  dinv  += (size_t)ty * N;
  rowptr+= (size_t)ty * N1;
  epk   += (size_t)ty * E;
  oStat += (size_t)ty * 1536;
  __shared__ float redS[64], redQ[64];
  if (threadIdx.x < 64) { redS[threadIdx.x] = 0.f; redQ[threadIdx.x] = 0.f; }
  __syncthreads();
  int f = threadIdx.x & 63;
  int wvl = threadIdx.x >> 6;
  int stride = nblk * 4;
  float s = 0.f, q = 0.f;
  for (int n = blk * 4 + wvl; n < N; n += stride) {
    float di = dinv[n];
    float acc0 = bf2f(xw[(size_t)n * 64 + f]) * di * di;  // self loop
    float acc1 = 0.f;
    int b = rowptr[n], e = rowptr[n + 1];
    int j = b;
    if ((j & 1) && j < e) {
      int2 e0 = epk[j];
      acc1 += bf2f(xw[(size_t)e0.x * 64 + f]) * __int_as_float(e0.y);
      ++j;
    }
    for (; j + 7 < e; j += 8) {
      int4 p01 = *(const int4*)&epk[j];
      int4 p23 = *(const int4*)&epk[j + 2];
      int4 p45 = *(const int4*)&epk[j + 4];
      int4 p67 = *(const int4*)&epk[j + 6];
      acc0 += bf2f(xw[(size_t)p01.x * 64 + f]) * __int_as_float(p01.y);
      acc1 += bf2f(xw[(size_t)p01.z * 64 + f]) * __int_as_float(p01.w);
      acc0 += bf2f(xw[(size_t)p23.x * 64 + f]) * __int_as_float(p23.y);
      acc1 += bf2f(xw[(size_t)p23.z * 64 + f]) * __int_as_float(p23.w);
      acc0 += bf2f(xw[(size_t)p45.x * 64 + f]) * __int_as_float(p45.y);
      acc1 += bf2f(xw[(size_t)p45.z * 64 + f]) * __int_as_float(p45.w);
      acc0 += bf2f(xw[(size_t)p67.x * 64 + f]) * __int_as_float(p67.y);
      acc1 += bf2f(xw[(size_t)p67.z * 64 + f]) * __int_as_float(p67.w);
    }
    for (; j + 1 < e; j += 2) {
      int4 p01 = *(const int4*)&epk[j];
      acc0 += bf2f(xw[(size_t)p01.x * 64 + f]) * __int_as_float(p01.y);
      acc1 += bf2f(xw[(size_t)p01.z * 64 + f]) * __int_as_float(p01.w);
    }
    if (j < e) {
      int2 e0 = epk[j];
      acc0 += bf2f(xw[(size_t)e0.x * 64 + f]) * __int_as_float(e0.y);
    }
    float acc = acc0 + acc1;
    ag[(size_t)n * 64 + f] = f2bf(acc);
    s += acc;
    q += acc * acc;
  }
  atomicAdd(&redS[f], s);
  atomicAdd(&redQ[f], q);
  __syncthreads();
  if (threadIdx.x < 64) {
    atomicAdd(&oStat[threadIdx.x], redS[threadIdx.x]);
    atomicAdd(&oStat[128 + threadIdx.x], redQ[threadIdx.x]);
  }
}

// ---------------- classifier final: BN+ReLU(u fp32) @ Wc2 + bc2 ----------------
__global__ __launch_bounds__(256) void final_k(const float* __restrict__ u, const float* __restrict__ st,
                                               const float* __restrict__ g, const float* __restrict__ be,
                                               const float* __restrict__ Wc2, const float* __restrict__ bc2,
                                               float* __restrict__ out, int N) {
  __shared__ float Wl[512], sc[128], sh[128];
  for (int i = threadIdx.x; i < 512; i += 256) Wl[i] = Wc2[i];
  if (threadIdx.x < 128) {
    int c = threadIdx.x;
    float invN = 1.f / (float)N;
    float mn = st[c] * invN;
    float vr = fmaxf(st[128 + c] * invN - mn * mn, 0.f);
    float s = g[c] * rsqrtf(vr + BN_EPS);
    sc[c] = s;
    sh[c] = be[c] - mn * s;
  }
  __syncthreads();
  int idx = blockIdx.x * 256 + threadIdx.x;
  if (idx >= N * 4) return;
  int n = idx >> 2, c = idx & 3;
  const float* ur = u + (size_t)n * 128;
  float acc = bc2[c];
#pragma unroll 8
  for (int k = 0; k < 128; ++k) {
    float v = fmaxf(fmaf(ur[k], sc[k], sh[k]), 0.f);
    acc = fmaf(v, Wl[k * 4 + c], acc);
  }
  out[idx] = acc;
}

extern "C" void kernel_launch(void* const* d_in, const int* in_sizes, int n_in,
                              void* d_out, int out_size, void* d_ws, size_t ws_size,
                              hipStream_t stream) {
  const float* xs   = (const float*)d_in[0];
  const int*   esrc = (const int*)d_in[1];
  const int*   edst = (const int*)d_in[2];
  const float* ew   = (const float*)d_in[3];
  const float* W1   = (const float*)d_in[4];
  const float* g1   = (const float*)d_in[6];
  const float* be1  = (const float*)d_in[7];
  const float* W2   = (const float*)d_in[8];
  const float* g2   = (const float*)d_in[10];
  const float* be2  = (const float*)d_in[11];
  const float* gW   = (const float*)d_in[12];
  const float* gam  = (const float*)d_in[14];
  const float* gbe  = (const float*)d_in[15];
  const float* Wp   = (const float*)d_in[16];
  const float* gp   = (const float*)d_in[18];
  const float* bep  = (const float*)d_in[19];
  const float* Wih  = (const float*)d_in[20];
  const float* Whh  = (const float*)d_in[21];
  const float* bih  = (const float*)d_in[22];
  const float* bhh  = (const float*)d_in[23];
  const float* Wc1  = (const float*)d_in[24];
  const float* gc   = (const float*)d_in[26];
  const float* bec  = (const float*)d_in[27];
  const float* Wc2  = (const float*)d_in[28];
  const float* bc2  = (const float*)d_in[29];
  float* out = (float*)d_out;

  const int T = 8;
  const int TC = 4;  // timestep chunk for stage-batched encoder
  const int N = in_sizes[0] / (T * 32);
  const int E = in_sizes[1] / T;
  const int TE = T * E, TN = T * N, N1 = N + 1;

  // ---- workspace layout (bytes) ----
  size_t off = 0;
  auto alloc = [&](size_t bytes) { size_t o = off; off += (bytes + 255) & ~(size_t)255; return o; };
  char* base = (char*)d_ws;
  size_t oH      = alloc((size_t)T * N * 64 * 2);   // Hraw bf16 [T,N,64]
  size_t oEpk    = alloc((size_t)TE * 8);           // packed (src, w/norm)
  size_t oRp     = alloc((size_t)T * N1 * 4);       // rowptr
  size_t oDinv   = alloc((size_t)TN * 4);           // dinv
  size_t oStats  = alloc((size_t)49 * 256 * 4);     // stats slots
  size_t oBsum   = alloc((size_t)T * 256 * 4);      // scan block sums
  size_t oWf     = alloc((size_t)70000 * 2);        // prebuilt weight fragments
  size_t oArena  = alloc((size_t)80 * 1024 * 1024); // phase-shared arena
  if (ws_size < off) return;

  ushort* Hraw  = (ushort*)(base + oH);
  int2*   epk   = (int2*)(base + oEpk);
  int*    rowptr= (int*)(base + oRp);
  float*  dinv  = (float*)(base + oDinv);
  float*  statsA= (float*)(base + oStats);
  int*    bsum  = (int*)(base + oBsum);
  ushort* wfA   = (ushort*)(base + oWf);
  char*   arena = base + oArena;

  // weight fragment offsets (ushort elements)
  ushort* W1f  = wfA;
  ushort* W2f  = W1f + 4096;
  ushort* gW0f = W2f + 8192;
  ushort* gW1f = gW0f + 4096;
  ushort* gW2f = gW1f + 4096;
  ushort* Wpf  = gW2f + 4096;
  ushort* Wihf = Wpf + 4096;
  ushort* Whhf = Wihf + 12288;
  ushort* Wc1f = Whhf + 12288;

  // prep-phase arena views
  int*    cnt  = (int*)arena;                      // [T*N]
  int*    incl = cnt + TN;                         // [T*N]
  ushort* rank = (ushort*)(incl + TN);             // [T*E]
  // encoder-phase arena views (per chunk of TC=4 timesteps)
  ushort* y1A  = (ushort*)arena;                              // [TC,N,128]
  ushort* xwA  = (ushort*)arena;                              // [TC,N,64]
  ushort* hcA  = xwA + (size_t)TC * N * 64;                   // [TC,N,64]
  ushort* hbB  = (ushort*)(arena + (size_t)52 * 1024 * 1024); // [TC,N,64]
  ushort* agB  = hbB;                                         // [TC,N,64]
  // gru/cls-phase arena views
  float*  uf = (float*)arena;                                 // [N,128] fp32
  ushort* hA = (ushort*)(arena + (size_t)26 * 1024 * 1024);   // [N,64]
  ushort* hB = (ushort*)(arena + (size_t)40 * 1024 * 1024);   // [N,64]

  const int nb = CDIV(N, 256);

#define SLOT(t, j) (statsA + ((size_t)(t) * 6 + (j)) * 256)

  hipMemsetAsync(statsA, 0, (size_t)49 * 256 * 4, stream);
  hipMemsetAsync(cnt, 0, (size_t)TN * 4, stream);

  // ---- weight fragment prep ----
  wprep_k<32, 128, false><<<1, 256, 0, stream>>>(W1, W1f);
  wprep_k<128, 64, false><<<1, 256, 0, stream>>>(W2, W2f);
  wprep_k<64, 64, false><<<1, 256, 0, stream>>>(gW, gW0f);
  wprep_k<64, 64, false><<<1, 256, 0, stream>>>(gW + 4096, gW1f);
  wprep_k<64, 64, false><<<1, 256, 0, stream>>>(gW + 8192, gW2f);
  wprep_k<64, 64, false><<<1, 256, 0, stream>>>(Wp, Wpf);
  wprep_k<64, 192, true><<<1, 256, 0, stream>>>(Wih, Wihf);
  wprep_k<64, 192, true><<<1, 256, 0, stream>>>(Whh, Whhf);

  // ================= batched graph prep (all T, XCD-partitioned) =================
  const int nbe = CDIV(E, 256);
  hist_k<<<8 * nbe, 256, 0, stream>>>(edst, cnt, rank, N, E);
  scan1_k<<<dim3(nb, T), 256, 0, stream>>>(cnt, incl, bsum, N);
  scan2_k<<<dim3(1, T), 256, 0, stream>>>(bsum, nb);
  scan3_k<<<dim3(nb, T), 256, 0, stream>>>(incl, cnt, bsum, rowptr, N, E);
  scat_k<<<8 * nbe, 256, 0, stream>>>(esrc, edst, ew, rank, rowptr, epk, N1, E);
  deg_k<<<8 * nb, 256, 0, stream>>>(epk, rowptr, dinv, N, N1, E);
  norm_k<<<8 * nb, 256, 0, stream>>>(epk, rowptr, dinv, N, N1, E);
  wprep_k<64, 128, false><<<1, 256, 0, stream>>>(Wc1, Wc1f);

  const int gemmGrid = CDIV(N, 128);
  const void*  nv  = nullptr;
  const float* ncf = nullptr;
  float* nmf = nullptr;
  ushort* nus = nullptr;

  // ================= stage-batched encoder: 2 chunks x 4 timesteps =================
  for (int c = 0; c < T / TC; ++c) {
    const int t0 = c * TC;
    const dim3 gdim(gemmGrid, TC);
    const int aggGrid = 8192;  // 1D; ty = blk&3 for XCD affinity
    const float* xt = xs + (size_t)t0 * N * 32;
    const float* dvT = dinv + (size_t)t0 * N;
    const int* rpT = rowptr + (size_t)t0 * N1;
    const int2* epT = epk + (size_t)t0 * E;

    // MLP1: y1A[ty] = xt[ty] @ W1, stats(t0+ty, 0)
    gemm2<32, 128, 1, false, true, false, false><<<gdim, 256, 0, stream>>>(
        xt, nv, W1f, y1A, nus, ncf, ncf, ncf, SLOT(t0, 0), N);
    // MLP2: hbB[ty] = BNReLU(y1A[ty]) @ W2, stats(.,1)
    gemm2<128, 64, 2, true, true, false, false><<<gdim, 256, 0, stream>>>(
        y1A, nv, W2f, hbB, nus, SLOT(t0, 0), g1, be1, SLOT(t0, 1), N);
    // GCN0: A = BNReLU(hbB[ty]) [side -> hcA], out xwA
    gemm2<64, 64, 2, true, false, false, true><<<gdim, 256, 0, stream>>>(
        hbB, nv, gW0f, xwA, hcA, SLOT(t0, 1), g2, be2, nmf, N);
    agg_k<<<aggGrid, 256, 0, stream>>>(xwA, dvT, rpT, epT, agB, SLOT(t0, 2), N, N1, E);
    // GCN1: A = hcA[ty] + ReLU(BN(agB[ty])) [side -> hcA], out xwA
    gemm2<64, 64, 3, true, false, false, true><<<gdim, 256, 0, stream>>>(
        hcA, agB, gW1f, xwA, hcA, SLOT(t0, 2), gam, gbe, nmf, N);
    agg_k<<<aggGrid, 256, 0, stream>>>(xwA, dvT, rpT, epT, agB, SLOT(t0, 3), N, N1, E);
    // GCN2
    gemm2<64, 64, 3, true, false, false, true><<<gdim, 256, 0, stream>>>(
        hcA, agB, gW2f, xwA, hcA, SLOT(t0, 3), gam + 64, gbe + 64, nmf, N);
    agg_k<<<aggGrid, 256, 0, stream>>>(xwA, dvT, rpT, epT, agB, SLOT(t0, 4), N, N1, E);
    // POST: raw -> Hraw[t0+ty] (bf16) + stats(.,5)
    gemm2<64, 64, 3, true, true, false, false><<<gdim, 256, 0, stream>>>(
        hcA, agB, Wpf, Hraw + (size_t)t0 * N * 64, nus, SLOT(t0, 4), gam + 128, gbe + 128, SLOT(t0, 5), N);
  }

  // ================= GRU over T steps (fused BN + dual-GEMM + gate) =================
  hipMemsetAsync(hA, 0, (size_t)N * 64 * 2, stream);
  ushort* hprev = hA;
  ushort* hnext = hB;
  for (int t = 0; t < T; ++t) {
    gruf_k<<<gemmGrid, 256, 0, stream>>>(Hraw + (size_t)t * N * 64, hprev, Wihf, Whhf,
                                         SLOT(t, 5), gp, bep, bih, bhh, hnext, N);
    ushort* tmp = hprev; hprev = hnext; hnext = tmp;
  }
  // after 8 steps hprev == hA

  // ================= classifier =================
  gemm2<64, 128, 0, false, true, true, false><<<dim3(gemmGrid, 1), 256, 0, stream>>>(
      hprev, nv, Wc1f, uf, nus, ncf, ncf, ncf, statsA + 48 * 256, N);
  final_k<<<CDIV(N * 4, 256), 256, 0, stream>>>(uf, statsA + 48 * 256, gc, bec, Wc2, bc2, out, N);
}

// Round 14
// 2019.528 us; speedup vs baseline: 2.2811x; 1.0016x over previous
//
#include <hip/hip_runtime.h>
#include <hip/hip_bf16.h>
#include <cstddef>

#define CDIV(a,b) (((a)+(b)-1)/(b))

static constexpr float BN_EPS = 1e-5f;

typedef __attribute__((ext_vector_type(8))) short short8v;   // 8 bf16 (4 VGPRs)
typedef __attribute__((ext_vector_type(4))) float f32x4;

__device__ inline ushort f2bf(float x) {
  unsigned u = __float_as_uint(x);
  unsigned r = (u + 0x7fffu + ((u >> 16) & 1u)) >> 16;
  return (ushort)r;
}
__device__ inline float bf2f(ushort h) {
  return __uint_as_float(((unsigned)h) << 16);
}

// ---------------- weight fragment prep (once per launch) ----------------
// Fragment layout works as EITHER MFMA operand (A/B layouts are symmetric):
// Wf[((mt*NKC+kc)*64 + lane)*8 + j], lane=((kr>>3)<<4)|(m&15), j=kr&7
template<int K, int M, bool TRANSW>
__global__ void wprep_k(const float* __restrict__ W, ushort* __restrict__ Wf) {
  constexpr int NKC = K / 32;
  for (int i = threadIdx.x; i < K * M; i += 256) {
    int k, m;
    if (TRANSW) { m = i / K; k = i - m * K; }
    else        { k = i / M; m = i - k * M; }
    float wv = W[i];
    int mt = m >> 4, ml = m & 15, kc = k >> 5, kr = k & 31;
    int lane = ((kr >> 3) << 4) | ml;
    int j = kr & 7;
    Wf[(size_t)((mt * NKC + kc) * 64 + lane) * 8 + j] = f2bf(wv);
  }
}

// =====================================================================
// bf16 MFMA GEMM v5 — T-batched; SWAPPED operands (A=weights, B=acts):
// D[m=feature][n=act row] -> each thread owns 4 consecutive features of one
// act row -> vectorized ushort4/float4 C-writes.
// AMODE: 0 = A bf16; 1 = A fp32; 2 = ReLU(BN(raw Ain)); 3 = Ain(bf16)+ReLU(BN(raw A2))
// RAW16: raw source is bf16 (else fp32). Stats from exact fp32 accumulators
// (OOB rows are staged as zeros -> contribute exactly 0 to sum/sumsq).
// NOTE: bnSc/bnSh produced by thread subset -> __syncthreads() after is REQUIRED.
// =====================================================================
template<int K, int M, int AMODE, bool RAW16, bool FSTAT, bool OUTF32, bool SIDE>
__global__ __launch_bounds__(256)
void gemm2(const void* __restrict__ Ain, const void* __restrict__ A2,
           const ushort* __restrict__ Wf, void* __restrict__ Cout,
           ushort* __restrict__ side,
           const float* __restrict__ aStat, const float* __restrict__ aG,
           const float* __restrict__ aB, float* __restrict__ oStat, int N) {
  constexpr int BM = 128;
  constexpr int NKC = K / 32;
  constexpr int NMT = M / 16;
  constexpr bool BN = (AMODE >= 2);
  constexpr int ABYTES = (AMODE == 1) ? 4 : ((AMODE == 2 && !RAW16) ? 4 : 2);
  __shared__ __align__(16) ushort As[BM * K];
  __shared__ __align__(16) ushort WfL[M * K];
  __shared__ float bnSc[BN ? K : 1];
  __shared__ float bnSh[BN ? K : 1];
  __shared__ float redS[FSTAT ? M : 1];
  __shared__ float redQ[FSTAT ? M : 1];
  const int tid = threadIdx.x;
  const int row0 = blockIdx.x * BM;
  const int ty = blockIdx.y;

  const char* AinB = (const char*)Ain + (size_t)ty * N * K * ABYTES;
  const char* A2B  = (AMODE == 3) ? ((const char*)A2 + (size_t)ty * N * K * (RAW16 ? 2 : 4)) : nullptr;
  char* CoutB = (char*)Cout + (size_t)ty * N * M * (OUTF32 ? 4 : 2);
  ushort* sideB = SIDE ? (side + (size_t)ty * N * K) : nullptr;
  if (BN) aStat += (size_t)ty * 1536;
  if (FSTAT) oStat += (size_t)ty * 1536;

  for (int i = tid; i < K * M / 8; i += 256)
    ((short8v*)WfL)[i] = ((const short8v*)Wf)[i];
  if (BN) {
    float invN = 1.f / (float)N;
    for (int i = tid; i < K; i += 256) {
      float mn = aStat[i] * invN;
      float vr = fmaxf(aStat[128 + i] * invN - mn * mn, 0.f);
      float sc = aG[i] * rsqrtf(vr + BN_EPS);
      bnSc[i] = sc;
      bnSh[i] = aB[i] - mn * sc;
    }
    __syncthreads();  // bnSc/bnSh visible to all threads before A-staging
  }
  if (FSTAT) {
    if (tid < M) { redS[tid] = 0.f; redQ[tid] = 0.f; }
  }

  // ---- A -> XOR-swizzled bf16 LDS (OOB rows staged as zeros) ----
  {
    const float*  Af  = (const float*)AinB;
    const ushort* Ab  = (const ushort*)AinB;
    const float*  A2f = (const float*)A2B;
    const ushort* A2b = (const ushort*)A2B;
    for (int i = tid; i < BM * K / 4; i += 256) {
      int row = (i * 4) / K, k0 = (i * 4) % K;
      int grow = row0 + row;
      ushort h4[4] = {0, 0, 0, 0};
      if (AMODE == 0) {
        if (grow < N) *(ushort4*)h4 = *(const ushort4*)&Ab[(size_t)grow * K + k0];
      } else if (AMODE == 1) {
        float vv[4] = {0.f, 0.f, 0.f, 0.f};
        if (grow < N) *(float4*)vv = *(const float4*)&Af[(size_t)grow * K + k0];
#pragma unroll
        for (int c = 0; c < 4; ++c) h4[c] = f2bf(vv[c]);
      } else {
        if (grow < N) {
          float rw[4];
          if (AMODE == 2) {
            if (RAW16) {
              ushort t4[4];
              *(ushort4*)t4 = *(const ushort4*)&Ab[(size_t)grow * K + k0];
#pragma unroll
              for (int c = 0; c < 4; ++c) rw[c] = bf2f(t4[c]);
            } else {
              *(float4*)rw = *(const float4*)&Af[(size_t)grow * K + k0];
            }
          } else {
            if (RAW16) {
              ushort t4[4];
              *(ushort4*)t4 = *(const ushort4*)&A2b[(size_t)grow * K + k0];
#pragma unroll
              for (int c = 0; c < 4; ++c) rw[c] = bf2f(t4[c]);
            } else {
              *(float4*)rw = *(const float4*)&A2f[(size_t)grow * K + k0];
            }
          }
          ushort b4[4];
          if (AMODE == 3) *(ushort4*)b4 = *(const ushort4*)&Ab[(size_t)grow * K + k0];
#pragma unroll
          for (int c = 0; c < 4; ++c) {
            float v = fmaxf(fmaf(rw[c], bnSc[k0 + c], bnSh[k0 + c]), 0.f);
            float vv = (AMODE == 3) ? bf2f(b4[c]) + v : v;
            h4[c] = f2bf(vv);
          }
          if (SIDE) *(ushort4*)&sideB[(size_t)grow * K + k0] = *(ushort4*)h4;
        }
      }
      unsigned off = ((unsigned)(row * K + k0) * 2u) ^ (((unsigned)(row & 7)) << 4);
      *(ushort4*)((char*)As + off) = *(ushort4*)h4;
    }
  }
  __syncthreads();

  const int wvi = tid >> 6, lane = tid & 63;
  const int lrow = lane & 15, lkg = lane >> 4;

  short8v af[2][NKC];
#pragma unroll
  for (int rt = 0; rt < 2; ++rt)
#pragma unroll
    for (int kc = 0; kc < NKC; ++kc) {
      int row = wvi * 32 + rt * 16 + lrow;
      unsigned off = ((unsigned)(row * K + kc * 32 + lkg * 8) * 2u) ^ (((unsigned)(row & 7)) << 4);
      af[rt][kc] = *(const short8v*)((const char*)As + off);
    }

  f32x4 acc[2][NMT];
#pragma unroll
  for (int rt = 0; rt < 2; ++rt)
#pragma unroll
    for (int mt = 0; mt < NMT; ++mt) acc[rt][mt] = f32x4{0.f, 0.f, 0.f, 0.f};

#pragma unroll
  for (int mt = 0; mt < NMT; ++mt) {
    short8v bf[NKC];
#pragma unroll
    for (int kc = 0; kc < NKC; ++kc)
      bf[kc] = *(const short8v*)&WfL[(size_t)((mt * NKC + kc) * 64 + lane) * 8];
#pragma unroll
    for (int rt = 0; rt < 2; ++rt)
#pragma unroll
      for (int kc = 0; kc < NKC; ++kc)
        acc[rt][mt] = __builtin_amdgcn_mfma_f32_16x16x32_bf16(bf[kc], af[rt][kc], acc[rt][mt], 0, 0, 0);
  }

  // ---- C write (swapped layout): thread owns act row (lrow), 4 feats mt*16+lkg*4+i ----
#pragma unroll
  for (int rt = 0; rt < 2; ++rt) {
    int grow = row0 + wvi * 32 + rt * 16 + lrow;
    if (grow < N) {
#pragma unroll
      for (int mt = 0; mt < NMT; ++mt) {
        int fb = mt * 16 + lkg * 4;
        if (OUTF32) {
          *(f32x4*)&((float*)CoutB)[(size_t)grow * M + fb] = acc[rt][mt];
        } else {
          ushort h4[4];
#pragma unroll
          for (int i = 0; i < 4; ++i) h4[i] = f2bf(acc[rt][mt][i]);
          *(ushort4*)&((ushort*)CoutB)[(size_t)grow * M + fb] = *(ushort4*)h4;
        }
      }
    }
  }

  // ---- fused column stats (OOB rows are zeros -> contribute 0) ----
  if (FSTAT) {
#pragma unroll
    for (int mt = 0; mt < NMT; ++mt) {
#pragma unroll
      for (int i = 0; i < 4; ++i) {
        float v0 = acc[0][mt][i], v1 = acc[1][mt][i];
        float s = v0 + v1;
        float q = v0 * v0 + v1 * v1;
        s += __shfl_xor(s, 1);  q += __shfl_xor(q, 1);
        s += __shfl_xor(s, 2);  q += __shfl_xor(q, 2);
        s += __shfl_xor(s, 4);  q += __shfl_xor(q, 4);
        s += __shfl_xor(s, 8);  q += __shfl_xor(q, 8);
        if (lrow == 0) {
          atomicAdd(&redS[mt * 16 + lkg * 4 + i], s);
          atomicAdd(&redQ[mt * 16 + lkg * 4 + i], q);
        }
      }
    }
    __syncthreads();
    if (tid < M) {
      atomicAdd(&oStat[tid], redS[tid]);
      atomicAdd(&oStat[128 + tid], redQ[tid]);
    }
  }
}

// ---------------- fused GRU step (swapped operands, vectorized gate I/O) ----------------
__global__ __launch_bounds__(256)
void gruf_k(const ushort* __restrict__ Hraw, const ushort* __restrict__ hprev,
            const ushort* __restrict__ Wihf, const ushort* __restrict__ Whhf,
            const float* __restrict__ hst, const float* __restrict__ gp,
            const float* __restrict__ bep,
            const float* __restrict__ bih, const float* __restrict__ bhh,
            ushort* __restrict__ hnext, int N) {
  __shared__ float bihL[192], bhhL[192], scL[64], shL[64];
  const int tid = threadIdx.x;
  if (tid < 192) { bihL[tid] = bih[tid]; bhhL[tid] = bhh[tid]; }
  if (tid < 64) {
    float invN = 1.f / (float)N;
    float mn = hst[tid] * invN;
    float vr = fmaxf(hst[128 + tid] * invN - mn * mn, 0.f);
    float s = gp[tid] * rsqrtf(vr + BN_EPS);
    scL[tid] = s;
    shL[tid] = bep[tid] - mn * s;
  }
  __syncthreads();
  const int wvi = tid >> 6, lane = tid & 63;
  const int lrow = lane & 15, lkg = lane >> 4;
  const int row0 = blockIdx.x * 128;
  const short8v zv = short8v{0, 0, 0, 0, 0, 0, 0, 0};
  for (int rt = 0; rt < 2; ++rt) {
    int arow = row0 + wvi * 32 + rt * 16 + lrow;
    bool aok = arow < N;
    short8v afA[2], afB[2];
#pragma unroll
    for (int kc = 0; kc < 2; ++kc) {
      short8v raw = aok ? *(const short8v*)&Hraw[(size_t)arow * 64 + kc * 32 + lkg * 8] : zv;
      short8v a;
#pragma unroll
      for (int j = 0; j < 8; ++j) {
        int k = kc * 32 + lkg * 8 + j;
        float v = fmaxf(fmaf(bf2f((ushort)raw[j]), scL[k], shL[k]), 0.f);
        a[j] = (short)f2bf(v);
      }
      afA[kc] = a;
      afB[kc] = aok ? *(const short8v*)&hprev[(size_t)arow * 64 + kc * 32 + lkg * 8] : zv;
    }
    f32x4 gacc[12], hacc[12];
#pragma unroll
    for (int mt = 0; mt < 12; ++mt) {
      gacc[mt] = f32x4{0.f, 0.f, 0.f, 0.f};
      hacc[mt] = f32x4{0.f, 0.f, 0.f, 0.f};
#pragma unroll
      for (int kc = 0; kc < 2; ++kc) {
        short8v bwi = *(const short8v*)&Wihf[(size_t)((mt * 2 + kc) * 64 + lane) * 8];
        short8v bwh = *(const short8v*)&Whhf[(size_t)((mt * 2 + kc) * 64 + lane) * 8];
        gacc[mt] = __builtin_amdgcn_mfma_f32_16x16x32_bf16(bwi, afA[kc], gacc[mt], 0, 0, 0);
        hacc[mt] = __builtin_amdgcn_mfma_f32_16x16x32_bf16(bwh, afB[kc], hacc[mt], 0, 0, 0);
      }
    }
    // gate epilogue: thread owns act row `arow`, features mtj*16+lkg*4+i (gacc reg i)
    if (aok) {
      const ushort* hpp = hprev + (size_t)arow * 64;
#pragma unroll
      for (int mtj = 0; mtj < 4; ++mtj) {
        int fb = mtj * 16 + lkg * 4;
        ushort hp4[4];
        *(ushort4*)hp4 = *(const ushort4*)&hpp[fb];
        ushort o4[4];
#pragma unroll
        for (int i = 0; i < 4; ++i) {
          int j = fb + i;
          float ir = gacc[mtj][i] + bihL[j];
          float iz = gacc[mtj + 4][i] + bihL[64 + j];
          float ig = gacc[mtj + 8][i] + bihL[128 + j];
          float hr = hacc[mtj][i] + bhhL[j];
          float hz = hacc[mtj + 4][i] + bhhL[64 + j];
          float hg = hacc[mtj + 8][i] + bhhL[128 + j];
          float r = 1.f / (1.f + expf(-(ir + hr)));
          float z = 1.f / (1.f + expf(-(iz + hz)));
          float ng = tanhf(ig + r * hg);
          o4[i] = f2bf((1.f - z) * ng + z * bf2f(hp4[i]));
        }
        *(ushort4*)&hnext[(size_t)arow * 64 + fb] = *(ushort4*)o4;
      }
    }
  }
}

// ---------------- batched graph prep (t = blockIdx.x & 7) ----------------
__global__ void hist_k(const int* __restrict__ dst, int* __restrict__ cnt, ushort* __restrict__ rank,
                       int N, int E) {
  int t = blockIdx.x & 7;
  int e = (blockIdx.x >> 3) * 256 + threadIdx.x;
  if (e >= E) return;
  size_t i = (size_t)t * E + e;
  rank[i] = (ushort)atomicAdd(&cnt[t * N + dst[i]], 1);
}
__global__ __launch_bounds__(256) void scan1_k(const int* __restrict__ in, int* __restrict__ incl,
                                               int* __restrict__ bsum, int n) {
  int t = blockIdx.y;
  const int* inp = in + (size_t)t * n;
  int* ip = incl + (size_t)t * n;
  int i = blockIdx.x * 256 + threadIdx.x;
  int v = (i < n) ? inp[i] : 0;
  int lane = threadIdx.x & 63;
  int sidx = threadIdx.x >> 6;
  int sv = v;
  for (int off = 1; off < 64; off <<= 1) {
    int tt = __shfl_up(sv, off, 64);
    if (lane >= off) sv += tt;
  }
  __shared__ int wsum[4];
  if (lane == 63) wsum[sidx] = sv;
  __syncthreads();
  int add = 0;
  for (int w = 0; w < sidx; ++w) add += wsum[w];
  sv += add;
  if (i < n) ip[i] = sv;
  if (threadIdx.x == 255) bsum[t * 256 + blockIdx.x] = sv;
}
__global__ __launch_bounds__(256) void scan2_k(int* __restrict__ bsum, int nb) {
  int t = blockIdx.y;
  int* bp = bsum + t * 256;
  int i = threadIdx.x;
  int v = (i < nb) ? bp[i] : 0;
  int lane = threadIdx.x & 63;
  int sidx = threadIdx.x >> 6;
  int sv = v;
  for (int off = 1; off < 64; off <<= 1) {
    int tt = __shfl_up(sv, off, 64);
    if (lane >= off) sv += tt;
  }
  __shared__ int wsum[4];
  if (lane == 63) wsum[sidx] = sv;
  __syncthreads();
  int add = 0;
  for (int w = 0; w < sidx; ++w) add += wsum[w];
  sv += add;
  if (i < nb) bp[i] = sv;
}
__global__ void scan3_k(const int* __restrict__ incl, const int* __restrict__ cnt,
                        const int* __restrict__ bsum, int* __restrict__ rowptr, int n, int E) {
  int t = blockIdx.y;
  int i = blockIdx.x * 256 + threadIdx.x;
  int* rp = rowptr + (size_t)t * (n + 1);
  if (i < n) {
    int v = incl[(size_t)t * n + i] - cnt[(size_t)t * n + i] +
            (blockIdx.x ? bsum[t * 256 + blockIdx.x - 1] : 0);
    rp[i] = v;
  }
  if (i == 0) rp[n] = E;
}
__global__ void scat_k(const int* __restrict__ src, const int* __restrict__ dst,
                       const float* __restrict__ w, const ushort* __restrict__ rank,
                       const int* __restrict__ rowptr, int2* __restrict__ epk,
                       int N1, int E) {
  int t = blockIdx.x & 7;
  int e = (blockIdx.x >> 3) * 256 + threadIdx.x;
  if (e >= E) return;
  size_t i = (size_t)t * E + e;
  int slot = rowptr[(size_t)t * N1 + dst[i]] + (int)rank[i];
  epk[(size_t)t * E + slot] = make_int2(src[i], __float_as_int(w[i]));
}
__global__ void deg_k(const int2* __restrict__ epk, const int* __restrict__ rowptr,
                      float* __restrict__ dinv, int N, int N1, int E) {
  int t = blockIdx.x & 7;
  int n = (blockIdx.x >> 3) * 256 + threadIdx.x;
  if (n >= N) return;
  const int* rp = rowptr + (size_t)t * N1;
  const int2* ep = epk + (size_t)t * E;
  float s = 1.f;  // self loop
  int b = rp[n], e = rp[n + 1];
  for (int j = b; j < e; ++j) s += __int_as_float(ep[j].y);
  dinv[(size_t)t * N + n] = rsqrtf(s);
}
__global__ void norm_k(int2* __restrict__ epk, const int* __restrict__ rowptr,
                       const float* __restrict__ dinv, int N, int N1, int E) {
  int t = blockIdx.x & 7;
  int n = (blockIdx.x >> 3) * 256 + threadIdx.x;
  if (n >= N) return;
  const int* rp = rowptr + (size_t)t * N1;
  const float* dv = dinv + (size_t)t * N;
  int2* ep = epk + (size_t)t * E;
  float dn = dv[n];
  int b = rp[n], e = rp[n + 1];
  for (int j = b; j < e; ++j) {
    int2 ed = ep[j];
    ep[j].y = __float_as_int(dv[ed.x] * __int_as_float(ed.y) * dn);
  }
}

// ---------------- GCN aggregation (wave-coherent, XCD-affine by timestep) ----------------
__global__ __launch_bounds__(256) void agg_k(const ushort* __restrict__ xw, const float* __restrict__ dinv,
                                             const int* __restrict__ rowptr, const int2* __restrict__ epk,
                                             ushort* __restrict__ ag, float* __restrict__ oStat,
                                             int N, int N1, int E) {
  const int ty = blockIdx.x & 3;
  const int blk = blockIdx.x >> 2;
  const int nblk = gridDim.x >> 2;
  xw    += (size_t)ty * N * 64;
  ag    += (size_t)ty * N * 64;
  dinv  += (size_t)ty * N;
  rowptr+= (size_t)ty * N1;
  epk   += (size_t)ty * E;
  oStat += (size_t)ty * 1536;
  __shared__ float redS[64], redQ[64];
  if (threadIdx.x < 64) { redS[threadIdx.x] = 0.f; redQ[threadIdx.x] = 0.f; }
  __syncthreads();
  int f = threadIdx.x & 63;
  int wvl = threadIdx.x >> 6;
  int stride = nblk * 4;
  float s = 0.f, q = 0.f;
  for (int n = blk * 4 + wvl; n < N; n += stride) {
    float di = dinv[n];
    float acc0 = bf2f(xw[(size_t)n * 64 + f]) * di * di;  // self loop
    float acc1 = 0.f;
    int b = rowptr[n], e = rowptr[n + 1];
    int j = b;
    if ((j & 1) && j < e) {
      int2 e0 = epk[j];
      acc1 += bf2f(xw[(size_t)e0.x * 64 + f]) * __int_as_float(e0.y);
      ++j;
    }
    for (; j + 7 < e; j += 8) {
      int4 p01 = *(const int4*)&epk[j];
      int4 p23 = *(const int4*)&epk[j + 2];
      int4 p45 = *(const int4*)&epk[j + 4];
      int4 p67 = *(const int4*)&epk[j + 6];
      acc0 += bf2f(xw[(size_t)p01.x * 64 + f]) * __int_as_float(p01.y);
      acc1 += bf2f(xw[(size_t)p01.z * 64 + f]) * __int_as_float(p01.w);
      acc0 += bf2f(xw[(size_t)p23.x * 64 + f]) * __int_as_float(p23.y);
      acc1 += bf2f(xw[(size_t)p23.z * 64 + f]) * __int_as_float(p23.w);
      acc0 += bf2f(xw[(size_t)p45.x * 64 + f]) * __int_as_float(p45.y);
      acc1 += bf2f(xw[(size_t)p45.z * 64 + f]) * __int_as_float(p45.w);
      acc0 += bf2f(xw[(size_t)p67.x * 64 + f]) * __int_as_float(p67.y);
      acc1 += bf2f(xw[(size_t)p67.z * 64 + f]) * __int_as_float(p67.w);
    }
    for (; j + 1 < e; j += 2) {
      int4 p01 = *(const int4*)&epk[j];
      acc0 += bf2f(xw[(size_t)p01.x * 64 + f]) * __int_as_float(p01.y);
      acc1 += bf2f(xw[(size_t)p01.z * 64 + f]) * __int_as_float(p01.w);
    }
    if (j < e) {
      int2 e0 = epk[j];
      acc0 += bf2f(xw[(size_t)e0.x * 64 + f]) * __int_as_float(e0.y);
    }
    float acc = acc0 + acc1;
    ag[(size_t)n * 64 + f] = f2bf(acc);
    s += acc;
    q += acc * acc;
  }
  atomicAdd(&redS[f], s);
  atomicAdd(&redQ[f], q);
  __syncthreads();
  if (threadIdx.x < 64) {
    atomicAdd(&oStat[threadIdx.x], redS[threadIdx.x]);
    atomicAdd(&oStat[128 + threadIdx.x], redQ[threadIdx.x]);
  }
}

// ---------------- classifier final: BN+ReLU(u fp32) @ Wc2 + bc2 ----------------
__global__ __launch_bounds__(256) void final_k(const float* __restrict__ u, const float* __restrict__ st,
                                               const float* __restrict__ g, const float* __restrict__ be,
                                               const float* __restrict__ Wc2, const float* __restrict__ bc2,
                                               float* __restrict__ out, int N) {
  __shared__ float Wl[512], sc[128], sh[128];
  for (int i = threadIdx.x; i < 512; i += 256) Wl[i] = Wc2[i];
  if (threadIdx.x < 128) {
    int c = threadIdx.x;
    float invN = 1.f / (float)N;
    float mn = st[c] * invN;
    float vr = fmaxf(st[128 + c] * invN - mn * mn, 0.f);
    float s = g[c] * rsqrtf(vr + BN_EPS);
    sc[c] = s;
    sh[c] = be[c] - mn * s;
  }
  __syncthreads();
  int idx = blockIdx.x * 256 + threadIdx.x;
  if (idx >= N * 4) return;
  int n = idx >> 2, c = idx & 3;
  const float* ur = u + (size_t)n * 128;
  float acc = bc2[c];
#pragma unroll 8
  for (int k = 0; k < 128; ++k) {
    float v = fmaxf(fmaf(ur[k], sc[k], sh[k]), 0.f);
    acc = fmaf(v, Wl[k * 4 + c], acc);
  }
  out[idx] = acc;
}

extern "C" void kernel_launch(void* const* d_in, const int* in_sizes, int n_in,
                              void* d_out, int out_size, void* d_ws, size_t ws_size,
                              hipStream_t stream) {
  const float* xs   = (const float*)d_in[0];
  const int*   esrc = (const int*)d_in[1];
  const int*   edst = (const int*)d_in[2];
  const float* ew   = (const float*)d_in[3];
  const float* W1   = (const float*)d_in[4];
  const float* g1   = (const float*)d_in[6];
  const float* be1  = (const float*)d_in[7];
  const float* W2   = (const float*)d_in[8];
  const float* g2   = (const float*)d_in[10];
  const float* be2  = (const float*)d_in[11];
  const float* gW   = (const float*)d_in[12];
  const float* gam  = (const float*)d_in[14];
  const float* gbe  = (const float*)d_in[15];
  const float* Wp   = (const float*)d_in[16];
  const float* gp   = (const float*)d_in[18];
  const float* bep  = (const float*)d_in[19];
  const float* Wih  = (const float*)d_in[20];
  const float* Whh  = (const float*)d_in[21];
  const float* bih  = (const float*)d_in[22];
  const float* bhh  = (const float*)d_in[23];
  const float* Wc1  = (const float*)d_in[24];
  const float* gc   = (const float*)d_in[26];
  const float* bec  = (const float*)d_in[27];
  const float* Wc2  = (const float*)d_in[28];
  const float* bc2  = (const float*)d_in[29];
  float* out = (float*)d_out;

  const int T = 8;
  const int TC = 4;  // timestep chunk for stage-batched encoder
  const int N = in_sizes[0] / (T * 32);
  const int E = in_sizes[1] / T;
  const int TE = T * E, TN = T * N, N1 = N + 1;

  // ---- workspace layout (bytes) ----
  size_t off = 0;
  auto alloc = [&](size_t bytes) { size_t o = off; off += (bytes + 255) & ~(size_t)255; return o; };
  char* base = (char*)d_ws;
  size_t oH      = alloc((size_t)T * N * 64 * 2);   // Hraw bf16 [T,N,64]
  size_t oEpk    = alloc((size_t)TE * 8);           // packed (src, w/norm)
  size_t oRp     = alloc((size_t)T * N1 * 4);       // rowptr
  size_t oDinv   = alloc((size_t)TN * 4);           // dinv
  size_t oStats  = alloc((size_t)49 * 256 * 4);     // stats slots
  size_t oBsum   = alloc((size_t)T * 256 * 4);      // scan block sums
  size_t oWf     = alloc((size_t)70000 * 2);        // prebuilt weight fragments
  size_t oArena  = alloc((size_t)80 * 1024 * 1024); // phase-shared arena
  if (ws_size < off) return;

  ushort* Hraw  = (ushort*)(base + oH);
  int2*   epk   = (int2*)(base + oEpk);
  int*    rowptr= (int*)(base + oRp);
  float*  dinv  = (float*)(base + oDinv);
  float*  statsA= (float*)(base + oStats);
  int*    bsum  = (int*)(base + oBsum);
  ushort* wfA   = (ushort*)(base + oWf);
  char*   arena = base + oArena;

  // weight fragment offsets (ushort elements)
  ushort* W1f  = wfA;
  ushort* W2f  = W1f + 4096;
  ushort* gW0f = W2f + 8192;
  ushort* gW1f = gW0f + 4096;
  ushort* gW2f = gW1f + 4096;
  ushort* Wpf  = gW2f + 4096;
  ushort* Wihf = Wpf + 4096;
  ushort* Whhf = Wihf + 12288;
  ushort* Wc1f = Whhf + 12288;

  // prep-phase arena views
  int*    cnt  = (int*)arena;                      // [T*N]
  int*    incl = cnt + TN;                         // [T*N]
  ushort* rank = (ushort*)(incl + TN);             // [T*E]
  // encoder-phase arena views (per chunk of TC=4 timesteps)
  ushort* y1A  = (ushort*)arena;                              // [TC,N,128]
  ushort* xwA  = (ushort*)arena;                              // [TC,N,64]
  ushort* hcA  = xwA + (size_t)TC * N * 64;                   // [TC,N,64]
  ushort* hbB  = (ushort*)(arena + (size_t)52 * 1024 * 1024); // [TC,N,64]
  ushort* agB  = hbB;                                         // [TC,N,64]
  // gru/cls-phase arena views
  float*  uf = (float*)arena;                                 // [N,128] fp32
  ushort* hA = (ushort*)(arena + (size_t)26 * 1024 * 1024);   // [N,64]
  ushort* hB = (ushort*)(arena + (size_t)40 * 1024 * 1024);   // [N,64]

  const int nb = CDIV(N, 256);

#define SLOT(t, j) (statsA + ((size_t)(t) * 6 + (j)) * 256)

  hipMemsetAsync(statsA, 0, (size_t)49 * 256 * 4, stream);
  hipMemsetAsync(cnt, 0, (size_t)TN * 4, stream);

  // ---- weight fragment prep ----
  wprep_k<32, 128, false><<<1, 256, 0, stream>>>(W1, W1f);
  wprep_k<128, 64, false><<<1, 256, 0, stream>>>(W2, W2f);
  wprep_k<64, 64, false><<<1, 256, 0, stream>>>(gW, gW0f);
  wprep_k<64, 64, false><<<1, 256, 0, stream>>>(gW + 4096, gW1f);
  wprep_k<64, 64, false><<<1, 256, 0, stream>>>(gW + 8192, gW2f);
  wprep_k<64, 64, false><<<1, 256, 0, stream>>>(Wp, Wpf);
  wprep_k<64, 192, true><<<1, 256, 0, stream>>>(Wih, Wihf);
  wprep_k<64, 192, true><<<1, 256, 0, stream>>>(Whh, Whhf);

  // ================= batched graph prep (all T, XCD-partitioned) =================
  const int nbe = CDIV(E, 256);
  hist_k<<<8 * nbe, 256, 0, stream>>>(edst, cnt, rank, N, E);
  scan1_k<<<dim3(nb, T), 256, 0, stream>>>(cnt, incl, bsum, N);
  scan2_k<<<dim3(1, T), 256, 0, stream>>>(bsum, nb);
  scan3_k<<<dim3(nb, T), 256, 0, stream>>>(incl, cnt, bsum, rowptr, N, E);
  scat_k<<<8 * nbe, 256, 0, stream>>>(esrc, edst, ew, rank, rowptr, epk, N1, E);
  deg_k<<<8 * nb, 256, 0, stream>>>(epk, rowptr, dinv, N, N1, E);
  norm_k<<<8 * nb, 256, 0, stream>>>(epk, rowptr, dinv, N, N1, E);
  wprep_k<64, 128, false><<<1, 256, 0, stream>>>(Wc1, Wc1f);

  const int gemmGrid = CDIV(N, 128);
  const void*  nv  = nullptr;
  const float* ncf = nullptr;
  float* nmf = nullptr;
  ushort* nus = nullptr;

  // ================= stage-batched encoder: 2 chunks x 4 timesteps =================
  for (int c = 0; c < T / TC; ++c) {
    const int t0 = c * TC;
    const dim3 gdim(gemmGrid, TC);
    const int aggGrid = 8192;  // 1D; ty = blk&3 for XCD affinity
    const float* xt = xs + (size_t)t0 * N * 32;
    const float* dvT = dinv + (size_t)t0 * N;
    const int* rpT = rowptr + (size_t)t0 * N1;
    const int2* epT = epk + (size_t)t0 * E;

    // MLP1: y1A[ty] = xt[ty] @ W1, stats(t0+ty, 0)
    gemm2<32, 128, 1, false, true, false, false><<<gdim, 256, 0, stream>>>(
        xt, nv, W1f, y1A, nus, ncf, ncf, ncf, SLOT(t0, 0), N);
    // MLP2: hbB[ty] = BNReLU(y1A[ty]) @ W2, stats(.,1)
    gemm2<128, 64, 2, true, true, false, false><<<gdim, 256, 0, stream>>>(
        y1A, nv, W2f, hbB, nus, SLOT(t0, 0), g1, be1, SLOT(t0, 1), N);
    // GCN0: A = BNReLU(hbB[ty]) [side -> hcA], out xwA
    gemm2<64, 64, 2, true, false, false, true><<<gdim, 256, 0, stream>>>(
        hbB, nv, gW0f, xwA, hcA, SLOT(t0, 1), g2, be2, nmf, N);
    agg_k<<<aggGrid, 256, 0, stream>>>(xwA, dvT, rpT, epT, agB, SLOT(t0, 2), N, N1, E);
    // GCN1: A = hcA[ty] + ReLU(BN(agB[ty])) [side -> hcA], out xwA
    gemm2<64, 64, 3, true, false, false, true><<<gdim, 256, 0, stream>>>(
        hcA, agB, gW1f, xwA, hcA, SLOT(t0, 2), gam, gbe, nmf, N);
    agg_k<<<aggGrid, 256, 0, stream>>>(xwA, dvT, rpT, epT, agB, SLOT(t0, 3), N, N1, E);
    // GCN2
    gemm2<64, 64, 3, true, false, false, true><<<gdim, 256, 0, stream>>>(
        hcA, agB, gW2f, xwA, hcA, SLOT(t0, 3), gam + 64, gbe + 64, nmf, N);
    agg_k<<<aggGrid, 256, 0, stream>>>(xwA, dvT, rpT, epT, agB, SLOT(t0, 4), N, N1, E);
    // POST: raw -> Hraw[t0+ty] (bf16) + stats(.,5)
    gemm2<64, 64, 3, true, true, false, false><<<gdim, 256, 0, stream>>>(
        hcA, agB, Wpf, Hraw + (size_t)t0 * N * 64, nus, SLOT(t0, 4), gam + 128, gbe + 128, SLOT(t0, 5), N);
  }

  // ================= GRU over T steps (fused BN + dual-GEMM + gate) =================
  hipMemsetAsync(hA, 0, (size_t)N * 64 * 2, stream);
  ushort* hprev = hA;
  ushort* hnext = hB;
  for (int t = 0; t < T; ++t) {
    gruf_k<<<gemmGrid, 256, 0, stream>>>(Hraw + (size_t)t * N * 64, hprev, Wihf, Whhf,
                                         SLOT(t, 5), gp, bep, bih, bhh, hnext, N);
    ushort* tmp = hprev; hprev = hnext; hnext = tmp;
  }
  // after 8 steps hprev == hA

  // ================= classifier =================
  gemm2<64, 128, 0, false, true, true, false><<<dim3(gemmGrid, 1), 256, 0, stream>>>(
      hprev, nv, Wc1f, uf, nus, ncf, ncf, ncf, statsA + 48 * 256, N);
  final_k<<<CDIV(N * 4, 256), 256, 0, stream>>>(uf, statsA + 48 * 256, gc, bec, Wc2, bc2, out, N);
}